// Round 2
// baseline (11199.682 us; speedup 1.0000x reference)
//
#include <hip/hip_runtime.h>

// ---------------------------------------------------------------------------
// TemporalExtractor: multi-scale gated conv -> LN -> 2x GQA -> mean/std pool
// -> proj -> LN -> relu.   fp32 baseline, round 2.
//
// Round-1 post-mortem: abort/core-dump == GPU memory fault. Root cause:
// assumed ws_size >= 403 MB (4 full B*T*H fp32 buffers). Fix: batch-chunked
// pipeline — chunk = largest pow2 c such that 4*c*T*H*4B + pool fits ws_size.
// Everything before the pool concat is per-batch-element independent.
//
// Shapes: B=32 T=1024 F=64 H=768 (3x CH=256), G=4 heads D=192, out (B,768).
// ---------------------------------------------------------------------------

constexpr int Bb = 32, Tt = 1024, Ff = 64, Hh = 768, CH = 256, Gg = 4, Dd = 192;
constexpr float EPS = 1e-5f;

__device__ __forceinline__ float2 block_reduce2(float a, float b, float* tmp) {
  // blockDim.x == 256 (4 waves). Returns (sum_a, sum_b) broadcast to all.
  int lane = threadIdx.x & 63, wid = threadIdx.x >> 6;
#pragma unroll
  for (int off = 32; off > 0; off >>= 1) {
    a += __shfl_down(a, off);
    b += __shfl_down(b, off);
  }
  if (lane == 0) { tmp[wid] = a; tmp[4 + wid] = b; }
  __syncthreads();
  if (threadIdx.x == 0) {
    tmp[0] = tmp[0] + tmp[1] + tmp[2] + tmp[3];
    tmp[4] = tmp[4] + tmp[5] + tmp[6] + tmp[7];
  }
  __syncthreads();
  float2 r; r.x = tmp[0]; r.y = tmp[4];
  return r;
}

// ---------------------------------------------------------------------------
// 1) Gated conv branch: out[b,t,coff+c] = relu(convf) * sigmoid(convg)
//    grid (T/32, chunk), block 256 (thread = output channel c), 32 t's each.
// ---------------------------------------------------------------------------
__global__ __launch_bounds__(256) void conv_gated_kernel(
    const float* __restrict__ x, const float* __restrict__ wf,
    const float* __restrict__ bf, const float* __restrict__ wg,
    const float* __restrict__ bg, float* __restrict__ out, int K, int coff) {
  const int t0 = blockIdx.x * 32;
  const int b = blockIdx.y;
  const int pad = (K - 1) / 2;
  const int span = 32 + 2 * pad;  // <= 38
  __shared__ float xs[38][64];

  for (int e = threadIdx.x; e < span * Ff; e += 256) {
    int tt = e >> 6, f = e & 63;
    int tg = t0 - pad + tt;
    xs[tt][f] = (tg >= 0 && tg < Tt) ? x[((size_t)b * Tt + tg) * Ff + f] : 0.f;
  }
  __syncthreads();

  const int c = threadIdx.x;
  float accf[32], accg[32];
  const float bf0 = bf[c], bg0 = bg[c];
#pragma unroll
  for (int t = 0; t < 32; t++) { accf[t] = bf0; accg[t] = bg0; }

  for (int kk = 0; kk < K; kk++) {
#pragma unroll 4
    for (int f = 0; f < Ff; f++) {
      float wfv = wf[(kk * Ff + f) * CH + c];
      float wgv = wg[(kk * Ff + f) * CH + c];
#pragma unroll
      for (int t = 0; t < 32; t++) {
        float xv = xs[t + kk][f];
        accf[t] = fmaf(xv, wfv, accf[t]);
        accg[t] = fmaf(xv, wgv, accg[t]);
      }
    }
  }
#pragma unroll
  for (int t = 0; t < 32; t++) {
    float a = accf[t] > 0.f ? accf[t] : 0.f;
    float s = 1.f / (1.f + __expf(-accg[t]));
    out[((size_t)b * Tt + t0 + t) * Hh + coff + c] = a * s;
  }
}

// ---------------------------------------------------------------------------
// 2) LayerNorm over last dim 768: one block per row, 256 threads (3 ea.)
// ---------------------------------------------------------------------------
__global__ __launch_bounds__(256) void ln_kernel(
    const float* __restrict__ in, float* __restrict__ out,
    const float* __restrict__ g, const float* __restrict__ bt) {
  __shared__ float red[8];
  const size_t row = blockIdx.x;
  float v[3], s = 0.f, ss = 0.f;
#pragma unroll
  for (int j = 0; j < 3; j++) {
    int c = threadIdx.x + j * 256;
    float t = in[row * Hh + c];
    v[j] = t; s += t; ss += t * t;
  }
  float2 r = block_reduce2(s, ss, red);
  float mu = r.x * (1.f / Hh);
  float var = r.y * (1.f / Hh) - mu * mu;
  float rs = rsqrtf(var + EPS);
#pragma unroll
  for (int j = 0; j < 3; j++) {
    int c = threadIdx.x + j * 256;
    out[row * Hh + c] = (v[j] - mu) * rs * g[c] + bt[c];
  }
}

// residual variant: h = LN(h + y + bp)  (in-place on h)
__global__ __launch_bounds__(256) void res_ln_kernel(
    float* __restrict__ h, const float* __restrict__ y,
    const float* __restrict__ bp, const float* __restrict__ g,
    const float* __restrict__ bt) {
  __shared__ float red[8];
  const size_t row = blockIdx.x;
  float v[3], s = 0.f, ss = 0.f;
#pragma unroll
  for (int j = 0; j < 3; j++) {
    int c = threadIdx.x + j * 256;
    float t = h[row * Hh + c] + y[row * Hh + c] + bp[c];
    v[j] = t; s += t; ss += t * t;
  }
  float2 r = block_reduce2(s, ss, red);
  float mu = r.x * (1.f / Hh);
  float var = r.y * (1.f / Hh) - mu * mu;
  float rs = rsqrtf(var + EPS);
#pragma unroll
  for (int j = 0; j < 3; j++) {
    int c = threadIdx.x + j * 256;
    h[row * Hh + c] = (v[j] - mu) * rs * g[c] + bt[c];
  }
}

// ---------------------------------------------------------------------------
// 3) GEMM fp32: C[M,N] = A[M,K] @ W[K,N]; 64x64 block tile, BK=16,
//    256 threads, 4x4 micro-tile. M,N,K multiples of 64/16 here.
// ---------------------------------------------------------------------------
__global__ __launch_bounds__(256) void gemm_fp32(
    const float* __restrict__ A, const float* __restrict__ W,
    float* __restrict__ C, int M, int N, int K) {
  __shared__ float As[16][68];  // [k][m], stride 68: 16B-aligned, <=2-way banks
  __shared__ float Ws[16][64];  // [k][n]
  const int n0 = blockIdx.x * 64, m0 = blockIdx.y * 64;
  const int tx = threadIdx.x & 15, ty = threadIdx.x >> 4;
  float acc[4][4] = {};

  for (int k0 = 0; k0 < K; k0 += 16) {
    {
      int m = threadIdx.x >> 2, kg = (threadIdx.x & 3) * 4;
      const float4 av = *(const float4*)&A[(size_t)(m0 + m) * K + k0 + kg];
      As[kg + 0][m] = av.x; As[kg + 1][m] = av.y;
      As[kg + 2][m] = av.z; As[kg + 3][m] = av.w;
      int kk = threadIdx.x >> 4, jg = (threadIdx.x & 15) * 4;
      *(float4*)&Ws[kk][jg] = *(const float4*)&W[(size_t)(k0 + kk) * N + n0 + jg];
    }
    __syncthreads();
#pragma unroll
    for (int kk = 0; kk < 16; kk++) {
      float4 av = *(const float4*)&As[kk][ty * 4];
      float4 wv = *(const float4*)&Ws[kk][tx * 4];
      float a[4] = {av.x, av.y, av.z, av.w};
      float w[4] = {wv.x, wv.y, wv.z, wv.w};
#pragma unroll
      for (int i = 0; i < 4; i++)
#pragma unroll
        for (int j = 0; j < 4; j++) acc[i][j] = fmaf(a[i], w[j], acc[i][j]);
    }
    __syncthreads();
  }
#pragma unroll
  for (int i = 0; i < 4; i++) {
    float4 v = make_float4(acc[i][0], acc[i][1], acc[i][2], acc[i][3]);
    *(float4*)&C[(size_t)(m0 + ty * 4 + i) * N + n0 + tx * 4] = v;
  }
}

// ---------------------------------------------------------------------------
// 4) Flash-style GQA attention, fp32. grid (T/32, G, chunk), block 256.
//    Q tile 32 rows; K/V tiles 32 rows streamed through one LDS buffer.
//    Writes O in place of the Q tile (only this block reads that region).
// ---------------------------------------------------------------------------
__global__ __launch_bounds__(256) void attn_kernel(
    float* __restrict__ q, const float* __restrict__ kbuf,
    const float* __restrict__ vbuf) {
  const float scale = 0.0721687836f;  // 192^-0.5
  const int q0 = blockIdx.x * 32;
  const int g = blockIdx.y;
  const int b = blockIdx.z;
  __shared__ float Qs[32][196];   // stride 196: float4-aligned, <=2-way banks
  __shared__ float KVs[32][196];
  __shared__ float Ss[32][33];
  __shared__ float mrow[32], lrow[32], arow[32];

  const size_t baseQ = ((size_t)b * Tt) * Hh + (size_t)g * Dd;
  for (int e = threadIdx.x; e < 32 * 48; e += 256) {
    int r = e / 48, d4 = e % 48;
    *(float4*)&Qs[r][d4 * 4] =
        *(const float4*)&q[baseQ + (size_t)(q0 + r) * Hh + d4 * 4];
  }
  if (threadIdx.x < 32) { mrow[threadIdx.x] = -1e30f; lrow[threadIdx.x] = 0.f; }

  float O[24];
#pragma unroll
  for (int i = 0; i < 24; i++) O[i] = 0.f;
  const int qr = threadIdx.x >> 3;   // PV: q row
  const int dg = threadIdx.x & 7;    // PV: d block (24 floats at dg*24)
  const int tyq = threadIdx.x >> 4;  // S: q rows tyq, tyq+16
  const int txk = threadIdx.x & 15;  // S: k rows txk, txk+16

  for (int kt = 0; kt < Tt; kt += 32) {
    __syncthreads();  // prev PV done -> KVs reusable
    for (int e = threadIdx.x; e < 32 * 48; e += 256) {
      int r = e / 48, d4 = e % 48;
      *(float4*)&KVs[r][d4 * 4] =
          *(const float4*)&kbuf[((size_t)(b * Tt + kt + r)) * Hh + g * Dd + d4 * 4];
    }
    __syncthreads();
    float s00 = 0.f, s01 = 0.f, s10 = 0.f, s11 = 0.f;
#pragma unroll 8
    for (int d4 = 0; d4 < 48; d4++) {
      float4 a0 = *(const float4*)&Qs[tyq][d4 * 4];
      float4 a1 = *(const float4*)&Qs[tyq + 16][d4 * 4];
      float4 k0 = *(const float4*)&KVs[txk][d4 * 4];
      float4 k1 = *(const float4*)&KVs[txk + 16][d4 * 4];
      s00 += a0.x * k0.x + a0.y * k0.y + a0.z * k0.z + a0.w * k0.w;
      s01 += a0.x * k1.x + a0.y * k1.y + a0.z * k1.z + a0.w * k1.w;
      s10 += a1.x * k0.x + a1.y * k0.y + a1.z * k0.z + a1.w * k0.w;
      s11 += a1.x * k1.x + a1.y * k1.y + a1.z * k1.z + a1.w * k1.w;
    }
    Ss[tyq][txk] = s00 * scale;
    Ss[tyq][txk + 16] = s01 * scale;
    Ss[tyq + 16][txk] = s10 * scale;
    Ss[tyq + 16][txk + 16] = s11 * scale;
    __syncthreads();
    if (threadIdx.x < 32) {  // online softmax per q-row
      int r = threadIdx.x;
      float mold = mrow[r], mx = mold;
#pragma unroll
      for (int j = 0; j < 32; j++) mx = fmaxf(mx, Ss[r][j]);
      float alpha = __expf(mold - mx);
      float sum = 0.f;
#pragma unroll
      for (int j = 0; j < 32; j++) {
        float p = __expf(Ss[r][j] - mx);
        Ss[r][j] = p; sum += p;
      }
      mrow[r] = mx;
      lrow[r] = lrow[r] * alpha + sum;
      arow[r] = alpha;
    }
    __syncthreads();
    {   // rescale O; load V over K
      float alpha = arow[qr];
#pragma unroll
      for (int i = 0; i < 24; i++) O[i] *= alpha;
      for (int e = threadIdx.x; e < 32 * 48; e += 256) {
        int r = e / 48, d4 = e % 48;
        *(float4*)&KVs[r][d4 * 4] =
            *(const float4*)&vbuf[((size_t)(b * Tt + kt + r)) * Hh + g * Dd + d4 * 4];
      }
    }
    __syncthreads();
#pragma unroll 4
    for (int j = 0; j < 32; j++) {  // O += P.V
      float p = Ss[qr][j];
#pragma unroll
      for (int i4 = 0; i4 < 6; i4++) {
        float4 v = *(const float4*)&KVs[j][dg * 24 + i4 * 4];
        O[i4 * 4 + 0] = fmaf(p, v.x, O[i4 * 4 + 0]);
        O[i4 * 4 + 1] = fmaf(p, v.y, O[i4 * 4 + 1]);
        O[i4 * 4 + 2] = fmaf(p, v.z, O[i4 * 4 + 2]);
        O[i4 * 4 + 3] = fmaf(p, v.w, O[i4 * 4 + 3]);
      }
    }
  }
  float linv = 1.f / lrow[qr];
#pragma unroll
  for (int i = 0; i < 24; i++) O[i] *= linv;
  __syncthreads();
#pragma unroll
  for (int i = 0; i < 24; i++) Qs[qr][dg * 24 + i] = O[i];
  __syncthreads();
  for (int e = threadIdx.x; e < 32 * 48; e += 256) {
    int r = e / 48, d4 = e % 48;
    *(float4*)&q[baseQ + (size_t)(q0 + r) * Hh + d4 * 4] =
        *(const float4*)&Qs[r][d4 * 4];
  }
}

// ---------------------------------------------------------------------------
// 5) Pool: mean + population std over T.  pool[b,c]=m, pool[b,768+c]=s.
//    h is chunk-local; pool pointer is pre-offset by caller.
// ---------------------------------------------------------------------------
__global__ __launch_bounds__(256) void pool_kernel(const float* __restrict__ h,
                                                   float* __restrict__ pool) {
  int idx = blockIdx.x * 256 + threadIdx.x;  // chunk*768
  int b = idx / Hh, c = idx % Hh;
  float s = 0.f, ss = 0.f;
  for (int t = 0; t < Tt; t++) {
    float v = h[((size_t)b * Tt + t) * Hh + c];
    s += v; ss += v * v;
  }
  float mu = s * (1.f / Tt);
  float var = ss * (1.f / Tt) - mu * mu;
  pool[(size_t)b * 1536 + c] = mu;
  pool[(size_t)b * 1536 + 768 + c] = sqrtf(fmaxf(var, 0.f));
}

// ---------------------------------------------------------------------------
// 6) Final: z = pool @ proj_w + proj_b; out = relu(LN(z)). one block per b.
// ---------------------------------------------------------------------------
__global__ __launch_bounds__(256) void final_kernel(
    const float* __restrict__ pool, const float* __restrict__ pw,
    const float* __restrict__ pb, const float* __restrict__ g,
    const float* __restrict__ bt, float* __restrict__ out) {
  __shared__ float ms[1536];
  __shared__ float red[8];
  const int b = blockIdx.x;
  for (int e = threadIdx.x; e < 1536; e += 256) ms[e] = pool[(size_t)b * 1536 + e];
  __syncthreads();
  const int n0 = threadIdx.x, n1 = threadIdx.x + 256, n2 = threadIdx.x + 512;
  float a0 = pb[n0], a1 = pb[n1], a2 = pb[n2];
  for (int k = 0; k < 1536; k++) {
    float m = ms[k];
    const float* row = &pw[(size_t)k * Hh];
    a0 = fmaf(m, row[n0], a0);
    a1 = fmaf(m, row[n1], a1);
    a2 = fmaf(m, row[n2], a2);
  }
  float s = a0 + a1 + a2, ss = a0 * a0 + a1 * a1 + a2 * a2;
  float2 r = block_reduce2(s, ss, red);
  float mu = r.x * (1.f / Hh);
  float var = r.y * (1.f / Hh) - mu * mu;
  float rs = rsqrtf(var + EPS);
  float o0 = (a0 - mu) * rs * g[n0] + bt[n0];
  float o1 = (a1 - mu) * rs * g[n1] + bt[n1];
  float o2 = (a2 - mu) * rs * g[n2] + bt[n2];
  out[(size_t)b * Hh + n0] = o0 > 0.f ? o0 : 0.f;
  out[(size_t)b * Hh + n1] = o1 > 0.f ? o1 : 0.f;
  out[(size_t)b * Hh + n2] = o2 > 0.f ? o2 : 0.f;
}

// ---------------------------------------------------------------------------
extern "C" void kernel_launch(void* const* d_in, const int* in_sizes, int n_in,
                              void* d_out, int out_size, void* d_ws,
                              size_t ws_size, hipStream_t stream) {
  (void)in_sizes; (void)n_in; (void)out_size;
  const float* x = (const float*)d_in[0];
  const float* cw[3][4];  // [branch][wf,bf,wg,bg]
  for (int j = 0; j < 3; j++)
    for (int p = 0; p < 4; p++) cw[j][p] = (const float*)d_in[1 + j * 4 + p];
  const float* conv_ln_g = (const float*)d_in[13];
  const float* conv_ln_b = (const float*)d_in[14];
  const float* wq = (const float*)d_in[15];
  const float* wk = (const float*)d_in[16];
  const float* wv = (const float*)d_in[17];
  const float* wp = (const float*)d_in[18];
  const float* bp = (const float*)d_in[19];
  const float* lng = (const float*)d_in[20];
  const float* lnb = (const float*)d_in[21];
  const float* proj_w = (const float*)d_in[22];
  const float* proj_b = (const float*)d_in[23];
  const float* proj_ln_g = (const float*)d_in[24];
  const float* proj_ln_b = (const float*)d_in[25];
  float* out = (float*)d_out;

  // --- batch-chunked workspace layout -------------------------------------
  // per-b per-buffer: T*H floats = 3 MB. Buffers: h|q|k|v (chunk-sized) +
  // persistent pool (32*1536 floats). chunk = largest pow2 that fits ws_size.
  const size_t perb = (size_t)Tt * Hh;              // floats per b per buffer
  const size_t poolsz = (size_t)Bb * 2 * Hh;        // 49152 floats
  int chunk = Bb;
  while (chunk > 1 &&
         (4ull * perb * chunk + poolsz) * sizeof(float) > ws_size)
    chunk >>= 1;

  float* wsf = (float*)d_ws;
  const size_t crow = perb * (size_t)chunk;
  float* h = wsf;
  float* qb = wsf + crow;
  float* kb = wsf + 2 * crow;
  float* vb = wsf + 3 * crow;
  float* pool = wsf + 4 * crow;

  const int Ks[3] = {3, 5, 7};

  for (int b0 = 0; b0 < Bb; b0 += chunk) {
    const float* xb = x + (size_t)b0 * Tt * Ff;
    const int M = chunk * Tt;

    // conv front end (concat into qb), then LN -> h
    for (int j = 0; j < 3; j++) {
      conv_gated_kernel<<<dim3(Tt / 32, chunk), 256, 0, stream>>>(
          xb, cw[j][0], cw[j][1], cw[j][2], cw[j][3], qb, Ks[j], j * CH);
    }
    ln_kernel<<<M, 256, 0, stream>>>(qb, h, conv_ln_g, conv_ln_b);

    // two GQA blocks
    for (int i = 0; i < 2; i++) {
      const size_t wo = (size_t)i * Hh * Hh;
      gemm_fp32<<<dim3(Hh / 64, M / 64), 256, 0, stream>>>(h, wq + wo, qb, M, Hh, Hh);
      gemm_fp32<<<dim3(Hh / 64, M / 64), 256, 0, stream>>>(h, wk + wo, kb, M, Hh, Hh);
      gemm_fp32<<<dim3(Hh / 64, M / 64), 256, 0, stream>>>(h, wv + wo, vb, M, Hh, Hh);
      attn_kernel<<<dim3(Tt / 32, Gg, chunk), 256, 0, stream>>>(qb, kb, vb);
      gemm_fp32<<<dim3(Hh / 64, M / 64), 256, 0, stream>>>(qb, wp + wo, kb, M, Hh, Hh);
      res_ln_kernel<<<M, 256, 0, stream>>>(h, kb, bp + (size_t)i * Hh,
                                           lng + (size_t)i * Hh,
                                           lnb + (size_t)i * Hh);
    }

    // pool for this chunk (pool ptr offset by b0 rows)
    pool_kernel<<<(chunk * Hh) / 256, 256, 0, stream>>>(
        h, pool + (size_t)b0 * 2 * Hh);
  }

  // final projection over all 32 b
  final_kernel<<<Bb, 256, 0, stream>>>(pool, proj_w, proj_b, proj_ln_g,
                                       proj_ln_b, out);
}

// Round 3
// 7973.504 us; speedup vs baseline: 1.4046x; 1.4046x over previous
//
#include <hip/hip_runtime.h>
#include <hip/hip_bf16.h>

// ---------------------------------------------------------------------------
// TemporalExtractor round 3: GEMMs -> bf16 MFMA (m97 recipe).
//   - weights transposed+cast to bf16 [N][K] once per launch (9.4 MB)
//   - LN kernels emit fp32 h (residual/pool) + bf16 h (GEMM A input)
//   - attention outputs bf16 directly (only ever consumed by out-proj GEMM)
//   - gemm_bf16: 128x128 tile, BK=32, global_load_lds(16B), 16x16x32 MFMA
// Attention compute stays fp32 this round (next target).
// ---------------------------------------------------------------------------

constexpr int Bb = 32, Tt = 1024, Ff = 64, Hh = 768, CH = 256, Gg = 4, Dd = 192;
constexpr float EPS = 1e-5f;

typedef __attribute__((ext_vector_type(8))) short short8;   // 8 bf16 = 4 VGPRs
typedef __attribute__((ext_vector_type(4))) float floatx4;  // MFMA acc

__device__ __forceinline__ void async_copy16(const void* g, void* l) {
  __builtin_amdgcn_global_load_lds(
      (const __attribute__((address_space(1))) unsigned int*)g,
      (__attribute__((address_space(3))) unsigned int*)l, 16, 0, 0);
}

__device__ __forceinline__ float2 block_reduce2(float a, float b, float* tmp) {
  int lane = threadIdx.x & 63, wid = threadIdx.x >> 6;
#pragma unroll
  for (int off = 32; off > 0; off >>= 1) {
    a += __shfl_down(a, off);
    b += __shfl_down(b, off);
  }
  if (lane == 0) { tmp[wid] = a; tmp[4 + wid] = b; }
  __syncthreads();
  if (threadIdx.x == 0) {
    tmp[0] = tmp[0] + tmp[1] + tmp[2] + tmp[3];
    tmp[4] = tmp[4] + tmp[5] + tmp[6] + tmp[7];
  }
  __syncthreads();
  float2 r; r.x = tmp[0]; r.y = tmp[4];
  return r;
}

// ---------------------------------------------------------------------------
// 0) Weight transpose+cast: src fp32 [K=768][N=768] -> wt bf16 [z][N][K]
//    z = mat*2 + block (q0,q1,k0,k1,v0,v1,p0,p1). grid (24,24,8), 256 thr.
// ---------------------------------------------------------------------------
__global__ __launch_bounds__(256) void wt_cast_kernel(
    const float* __restrict__ wq, const float* __restrict__ wk,
    const float* __restrict__ wv, const float* __restrict__ wp,
    __hip_bfloat16* __restrict__ wt) {
  const int z = blockIdx.z;
  const float* src = (z < 2 ? wq : z < 4 ? wk : z < 6 ? wv : wp) +
                     (size_t)(z & 1) * Hh * Hh;
  __shared__ float tile[32][33];
  const int n0 = blockIdx.x * 32, k0 = blockIdx.y * 32;
  const int tx = threadIdx.x & 31, ty = threadIdx.x >> 5;  // ty 0..7
#pragma unroll
  for (int r = 0; r < 4; r++)
    tile[ty + 8 * r][tx] = src[(size_t)(k0 + ty + 8 * r) * Hh + n0 + tx];
  __syncthreads();
#pragma unroll
  for (int r = 0; r < 4; r++)
    wt[((size_t)z * Hh + n0 + ty + 8 * r) * Hh + k0 + tx] =
        __float2bfloat16(tile[tx][ty + 8 * r]);
}

// ---------------------------------------------------------------------------
// 1) Gated conv branch (unchanged)
// ---------------------------------------------------------------------------
__global__ __launch_bounds__(256) void conv_gated_kernel(
    const float* __restrict__ x, const float* __restrict__ wf,
    const float* __restrict__ bf, const float* __restrict__ wg,
    const float* __restrict__ bg, float* __restrict__ out, int K, int coff) {
  const int t0 = blockIdx.x * 32;
  const int b = blockIdx.y;
  const int pad = (K - 1) / 2;
  const int span = 32 + 2 * pad;  // <= 38
  __shared__ float xs[38][64];

  for (int e = threadIdx.x; e < span * Ff; e += 256) {
    int tt = e >> 6, f = e & 63;
    int tg = t0 - pad + tt;
    xs[tt][f] = (tg >= 0 && tg < Tt) ? x[((size_t)b * Tt + tg) * Ff + f] : 0.f;
  }
  __syncthreads();

  const int c = threadIdx.x;
  float accf[32], accg[32];
  const float bf0 = bf[c], bg0 = bg[c];
#pragma unroll
  for (int t = 0; t < 32; t++) { accf[t] = bf0; accg[t] = bg0; }

  for (int kk = 0; kk < K; kk++) {
#pragma unroll 4
    for (int f = 0; f < Ff; f++) {
      float wfv = wf[(kk * Ff + f) * CH + c];
      float wgv = wg[(kk * Ff + f) * CH + c];
#pragma unroll
      for (int t = 0; t < 32; t++) {
        float xv = xs[t + kk][f];
        accf[t] = fmaf(xv, wfv, accf[t]);
        accg[t] = fmaf(xv, wgv, accg[t]);
      }
    }
  }
#pragma unroll
  for (int t = 0; t < 32; t++) {
    float a = accf[t] > 0.f ? accf[t] : 0.f;
    float s = 1.f / (1.f + __expf(-accg[t]));
    out[((size_t)b * Tt + t0 + t) * Hh + coff + c] = a * s;
  }
}

// ---------------------------------------------------------------------------
// 2) LayerNorm: out fp32 + out16 bf16
// ---------------------------------------------------------------------------
__global__ __launch_bounds__(256) void ln_kernel(
    const float* __restrict__ in, float* __restrict__ out,
    __hip_bfloat16* __restrict__ out16, const float* __restrict__ g,
    const float* __restrict__ bt) {
  __shared__ float red[8];
  const size_t row = blockIdx.x;
  float v[3], s = 0.f, ss = 0.f;
#pragma unroll
  for (int j = 0; j < 3; j++) {
    int c = threadIdx.x + j * 256;
    float t = in[row * Hh + c];
    v[j] = t; s += t; ss += t * t;
  }
  float2 r = block_reduce2(s, ss, red);
  float mu = r.x * (1.f / Hh);
  float var = r.y * (1.f / Hh) - mu * mu;
  float rs = rsqrtf(var + EPS);
#pragma unroll
  for (int j = 0; j < 3; j++) {
    int c = threadIdx.x + j * 256;
    float o = (v[j] - mu) * rs * g[c] + bt[c];
    out[row * Hh + c] = o;
    out16[row * Hh + c] = __float2bfloat16(o);
  }
}

// residual variant: h = LN(h + y + bp), also emit bf16
__global__ __launch_bounds__(256) void res_ln_kernel(
    float* __restrict__ h, __hip_bfloat16* __restrict__ h16,
    const float* __restrict__ y, const float* __restrict__ bp,
    const float* __restrict__ g, const float* __restrict__ bt) {
  __shared__ float red[8];
  const size_t row = blockIdx.x;
  float v[3], s = 0.f, ss = 0.f;
#pragma unroll
  for (int j = 0; j < 3; j++) {
    int c = threadIdx.x + j * 256;
    float t = h[row * Hh + c] + y[row * Hh + c] + bp[c];
    v[j] = t; s += t; ss += t * t;
  }
  float2 r = block_reduce2(s, ss, red);
  float mu = r.x * (1.f / Hh);
  float var = r.y * (1.f / Hh) - mu * mu;
  float rs = rsqrtf(var + EPS);
#pragma unroll
  for (int j = 0; j < 3; j++) {
    int c = threadIdx.x + j * 256;
    float o = (v[j] - mu) * rs * g[c] + bt[c];
    h[row * Hh + c] = o;
    h16[row * Hh + c] = __float2bfloat16(o);
  }
}

// ---------------------------------------------------------------------------
// 3) bf16 MFMA GEMM: C[M,768] fp32 = A[M,768]bf16 @ Bt[768,768]bf16^T
//    (Bt stored [N][K]). 128x128 tile, BK=32, 256 thr = 4 waves, each wave a
//    64x64 quadrant = 4x4 MFMA tiles of 16x16x32. global_load_lds staging.
// ---------------------------------------------------------------------------
__global__ __launch_bounds__(256) void gemm_bf16(
    const short* __restrict__ A, const short* __restrict__ Bt,
    float* __restrict__ C) {
  constexpr int K = 768, N = 768;
  __shared__ __align__(16) short Asl[128 * 32];  // [m][k], 64B rows
  __shared__ __align__(16) short Bsl[128 * 32];  // [n][k]
  const int n0 = blockIdx.x * 128, m0 = blockIdx.y * 128;
  const int lane = threadIdx.x & 63;
  const int w = threadIdx.x >> 6, wm = w >> 1, wn = w & 1;
  const int lm = lane & 15, quad = lane >> 4;

  floatx4 acc[4][4];
#pragma unroll
  for (int i = 0; i < 4; i++)
#pragma unroll
    for (int j = 0; j < 4; j++) acc[i][j] = (floatx4)0.f;

  for (int k0 = 0; k0 < K; k0 += 32) {
    __syncthreads();  // previous iter's LDS reads done
#pragma unroll
    for (int half = 0; half < 2; half++) {
      int s = half * 256 + threadIdx.x;   // 512 slots of 16B per tile
      int m = s >> 2, ks = (s & 3) * 8;
      async_copy16(&A[(size_t)(m0 + m) * K + k0 + ks], &Asl[s * 8]);
      async_copy16(&Bt[(size_t)(n0 + m) * K + k0 + ks], &Bsl[s * 8]);
    }
    __syncthreads();  // drains vmcnt before barrier (compiler-emitted)

    short8 a[4], b[4];
#pragma unroll
    for (int i = 0; i < 4; i++)
      a[i] = *(const short8*)&Asl[(wm * 64 + i * 16 + lm) * 32 + quad * 8];
#pragma unroll
    for (int j = 0; j < 4; j++)
      b[j] = *(const short8*)&Bsl[(wn * 64 + j * 16 + lm) * 32 + quad * 8];
#pragma unroll
    for (int i = 0; i < 4; i++)
#pragma unroll
      for (int j = 0; j < 4; j++)
        acc[i][j] = __builtin_amdgcn_mfma_f32_16x16x32_bf16(a[i], b[j],
                                                            acc[i][j], 0, 0, 0);
  }

  // C/D layout: col = lane&15, row = quad*4 + reg   (m89-verified)
  const int rbase = quad * 4;
#pragma unroll
  for (int i = 0; i < 4; i++)
#pragma unroll
    for (int j = 0; j < 4; j++) {
      int mrow = m0 + wm * 64 + i * 16 + rbase;
      int ncol = n0 + wn * 64 + j * 16 + lm;
#pragma unroll
      for (int r = 0; r < 4; r++)
        C[(size_t)(mrow + r) * N + ncol] = acc[i][j][r];
    }
}

// ---------------------------------------------------------------------------
// 4) Flash-style GQA attention, fp32 compute; output written as bf16.
//    grid (T/32, G, chunk), block 256.
// ---------------------------------------------------------------------------
__global__ __launch_bounds__(256) void attn_kernel(
    const float* __restrict__ q, const float* __restrict__ kbuf,
    const float* __restrict__ vbuf, __hip_bfloat16* __restrict__ o16) {
  const float scale = 0.0721687836f;  // 192^-0.5
  const int q0 = blockIdx.x * 32;
  const int g = blockIdx.y;
  const int b = blockIdx.z;
  __shared__ float Qs[32][196];
  __shared__ float KVs[32][196];
  __shared__ float Ss[32][33];
  __shared__ float mrow[32], lrow[32], arow[32];

  const size_t baseQ = ((size_t)b * Tt) * Hh + (size_t)g * Dd;
  for (int e = threadIdx.x; e < 32 * 48; e += 256) {
    int r = e / 48, d4 = e % 48;
    *(float4*)&Qs[r][d4 * 4] =
        *(const float4*)&q[baseQ + (size_t)(q0 + r) * Hh + d4 * 4];
  }
  if (threadIdx.x < 32) { mrow[threadIdx.x] = -1e30f; lrow[threadIdx.x] = 0.f; }

  float O[24];
#pragma unroll
  for (int i = 0; i < 24; i++) O[i] = 0.f;
  const int qr = threadIdx.x >> 3;   // PV: q row
  const int dg = threadIdx.x & 7;    // PV: d block (24 floats at dg*24)
  const int tyq = threadIdx.x >> 4;  // S: q rows tyq, tyq+16
  const int txk = threadIdx.x & 15;  // S: k rows txk, txk+16

  for (int kt = 0; kt < Tt; kt += 32) {
    __syncthreads();
    for (int e = threadIdx.x; e < 32 * 48; e += 256) {
      int r = e / 48, d4 = e % 48;
      *(float4*)&KVs[r][d4 * 4] =
          *(const float4*)&kbuf[((size_t)(b * Tt + kt + r)) * Hh + g * Dd + d4 * 4];
    }
    __syncthreads();
    float s00 = 0.f, s01 = 0.f, s10 = 0.f, s11 = 0.f;
#pragma unroll 8
    for (int d4 = 0; d4 < 48; d4++) {
      float4 a0 = *(const float4*)&Qs[tyq][d4 * 4];
      float4 a1 = *(const float4*)&Qs[tyq + 16][d4 * 4];
      float4 k0 = *(const float4*)&KVs[txk][d4 * 4];
      float4 k1 = *(const float4*)&KVs[txk + 16][d4 * 4];
      s00 += a0.x * k0.x + a0.y * k0.y + a0.z * k0.z + a0.w * k0.w;
      s01 += a0.x * k1.x + a0.y * k1.y + a0.z * k1.z + a0.w * k1.w;
      s10 += a1.x * k0.x + a1.y * k0.y + a1.z * k0.z + a1.w * k0.w;
      s11 += a1.x * k1.x + a1.y * k1.y + a1.z * k1.z + a1.w * k1.w;
    }
    Ss[tyq][txk] = s00 * scale;
    Ss[tyq][txk + 16] = s01 * scale;
    Ss[tyq + 16][txk] = s10 * scale;
    Ss[tyq + 16][txk + 16] = s11 * scale;
    __syncthreads();
    if (threadIdx.x < 32) {
      int r = threadIdx.x;
      float mold = mrow[r], mx = mold;
#pragma unroll
      for (int j = 0; j < 32; j++) mx = fmaxf(mx, Ss[r][j]);
      float alpha = __expf(mold - mx);
      float sum = 0.f;
#pragma unroll
      for (int j = 0; j < 32; j++) {
        float p = __expf(Ss[r][j] - mx);
        Ss[r][j] = p; sum += p;
      }
      mrow[r] = mx;
      lrow[r] = lrow[r] * alpha + sum;
      arow[r] = alpha;
    }
    __syncthreads();
    {
      float alpha = arow[qr];
#pragma unroll
      for (int i = 0; i < 24; i++) O[i] *= alpha;
      for (int e = threadIdx.x; e < 32 * 48; e += 256) {
        int r = e / 48, d4 = e % 48;
        *(float4*)&KVs[r][d4 * 4] =
            *(const float4*)&vbuf[((size_t)(b * Tt + kt + r)) * Hh + g * Dd + d4 * 4];
      }
    }
    __syncthreads();
#pragma unroll 4
    for (int j = 0; j < 32; j++) {
      float p = Ss[qr][j];
#pragma unroll
      for (int i4 = 0; i4 < 6; i4++) {
        float4 v = *(const float4*)&KVs[j][dg * 24 + i4 * 4];
        O[i4 * 4 + 0] = fmaf(p, v.x, O[i4 * 4 + 0]);
        O[i4 * 4 + 1] = fmaf(p, v.y, O[i4 * 4 + 1]);
        O[i4 * 4 + 2] = fmaf(p, v.z, O[i4 * 4 + 2]);
        O[i4 * 4 + 3] = fmaf(p, v.w, O[i4 * 4 + 3]);
      }
    }
  }
  float linv = 1.f / lrow[qr];
#pragma unroll
  for (int i = 0; i < 24; i++) O[i] *= linv;
  __syncthreads();
#pragma unroll
  for (int i = 0; i < 24; i++) Qs[qr][dg * 24 + i] = O[i];
  __syncthreads();
  for (int e = threadIdx.x; e < 32 * Dd; e += 256) {
    int r = e / Dd, d = e % Dd;
    o16[baseQ + (size_t)(q0 + r) * Hh + d] = __float2bfloat16(Qs[r][d]);
  }
}

// ---------------------------------------------------------------------------
// 5) Pool: mean + population std over T (unchanged)
// ---------------------------------------------------------------------------
__global__ __launch_bounds__(256) void pool_kernel(const float* __restrict__ h,
                                                   float* __restrict__ pool) {
  int idx = blockIdx.x * 256 + threadIdx.x;
  int b = idx / Hh, c = idx % Hh;
  float s = 0.f, ss = 0.f;
  for (int t = 0; t < Tt; t++) {
    float v = h[((size_t)b * Tt + t) * Hh + c];
    s += v; ss += v * v;
  }
  float mu = s * (1.f / Tt);
  float var = ss * (1.f / Tt) - mu * mu;
  pool[(size_t)b * 1536 + c] = mu;
  pool[(size_t)b * 1536 + 768 + c] = sqrtf(fmaxf(var, 0.f));
}

// ---------------------------------------------------------------------------
// 6) Final: z = pool @ proj_w + proj_b; out = relu(LN(z)) (unchanged)
// ---------------------------------------------------------------------------
__global__ __launch_bounds__(256) void final_kernel(
    const float* __restrict__ pool, const float* __restrict__ pw,
    const float* __restrict__ pb, const float* __restrict__ g,
    const float* __restrict__ bt, float* __restrict__ out) {
  __shared__ float ms[1536];
  __shared__ float red[8];
  const int b = blockIdx.x;
  for (int e = threadIdx.x; e < 1536; e += 256) ms[e] = pool[(size_t)b * 1536 + e];
  __syncthreads();
  const int n0 = threadIdx.x, n1 = threadIdx.x + 256, n2 = threadIdx.x + 512;
  float a0 = pb[n0], a1 = pb[n1], a2 = pb[n2];
  for (int k = 0; k < 1536; k++) {
    float m = ms[k];
    const float* row = &pw[(size_t)k * Hh];
    a0 = fmaf(m, row[n0], a0);
    a1 = fmaf(m, row[n1], a1);
    a2 = fmaf(m, row[n2], a2);
  }
  float s = a0 + a1 + a2, ss = a0 * a0 + a1 * a1 + a2 * a2;
  float2 r = block_reduce2(s, ss, red);
  float mu = r.x * (1.f / Hh);
  float var = r.y * (1.f / Hh) - mu * mu;
  float rs = rsqrtf(var + EPS);
  float o0 = (a0 - mu) * rs * g[n0] + bt[n0];
  float o1 = (a1 - mu) * rs * g[n1] + bt[n1];
  float o2 = (a2 - mu) * rs * g[n2] + bt[n2];
  out[(size_t)b * Hh + n0] = o0 > 0.f ? o0 : 0.f;
  out[(size_t)b * Hh + n1] = o1 > 0.f ? o1 : 0.f;
  out[(size_t)b * Hh + n2] = o2 > 0.f ? o2 : 0.f;
}

// ---------------------------------------------------------------------------
extern "C" void kernel_launch(void* const* d_in, const int* in_sizes, int n_in,
                              void* d_out, int out_size, void* d_ws,
                              size_t ws_size, hipStream_t stream) {
  (void)in_sizes; (void)n_in; (void)out_size;
  const float* x = (const float*)d_in[0];
  const float* cw[3][4];
  for (int j = 0; j < 3; j++)
    for (int p = 0; p < 4; p++) cw[j][p] = (const float*)d_in[1 + j * 4 + p];
  const float* conv_ln_g = (const float*)d_in[13];
  const float* conv_ln_b = (const float*)d_in[14];
  const float* wq = (const float*)d_in[15];
  const float* wk = (const float*)d_in[16];
  const float* wv = (const float*)d_in[17];
  const float* wp = (const float*)d_in[18];
  const float* bp = (const float*)d_in[19];
  const float* lng = (const float*)d_in[20];
  const float* lnb = (const float*)d_in[21];
  const float* proj_w = (const float*)d_in[22];
  const float* proj_b = (const float*)d_in[23];
  const float* proj_ln_g = (const float*)d_in[24];
  const float* proj_ln_b = (const float*)d_in[25];
  float* out = (float*)d_out;

  // --- workspace: 4 fp32 + 2 bf16 chunk buffers + wt(9.4MB) + pool ---------
  const size_t perb = (size_t)Tt * Hh;          // floats per b per buffer
  const size_t fixedB = 8ull * Hh * Hh * 2 + (size_t)Bb * 2 * Hh * 4;  // wt+pool
  int chunk = Bb;
  while (chunk > 1 && 20ull * perb * chunk + fixedB > ws_size) chunk >>= 1;

  const size_t crow = perb * (size_t)chunk;
  char* p = (char*)d_ws;
  float* h  = (float*)p;            p += crow * 4;
  float* qb = (float*)p;            p += crow * 4;
  float* kb = (float*)p;            p += crow * 4;
  float* vb = (float*)p;            p += crow * 4;
  __hip_bfloat16* h16  = (__hip_bfloat16*)p;  p += crow * 2;
  __hip_bfloat16* qb16 = (__hip_bfloat16*)p;  p += crow * 2;
  __hip_bfloat16* wt   = (__hip_bfloat16*)p;  p += 8ull * Hh * Hh * 2;
  float* pool = (float*)p;

  // one-time (per launch) weight transpose+cast
  wt_cast_kernel<<<dim3(24, 24, 8), 256, 0, stream>>>(wq, wk, wv, wp, wt);

  const int Ks[3] = {3, 5, 7};
  const short* wts = (const short*)wt;  // [z][N][K] bf16 bits

  for (int b0 = 0; b0 < Bb; b0 += chunk) {
    const float* xb = x + (size_t)b0 * Tt * Ff;
    const int M = chunk * Tt;
    const dim3 ggrid(Hh / 128, M / 128);

    for (int j = 0; j < 3; j++) {
      conv_gated_kernel<<<dim3(Tt / 32, chunk), 256, 0, stream>>>(
          xb, cw[j][0], cw[j][1], cw[j][2], cw[j][3], qb, Ks[j], j * CH);
    }
    ln_kernel<<<M, 256, 0, stream>>>(qb, h, h16, conv_ln_g, conv_ln_b);

    for (int i = 0; i < 2; i++) {
      const short* wtq = wts + (size_t)(0 * 2 + i) * Hh * Hh;
      const short* wtk = wts + (size_t)(1 * 2 + i) * Hh * Hh;
      const short* wtv = wts + (size_t)(2 * 2 + i) * Hh * Hh;
      const short* wtp = wts + (size_t)(3 * 2 + i) * Hh * Hh;
      gemm_bf16<<<ggrid, 256, 0, stream>>>((const short*)h16, wtq, qb);
      gemm_bf16<<<ggrid, 256, 0, stream>>>((const short*)h16, wtk, kb);
      gemm_bf16<<<ggrid, 256, 0, stream>>>((const short*)h16, wtv, vb);
      attn_kernel<<<dim3(Tt / 32, Gg, chunk), 256, 0, stream>>>(qb, kb, vb,
                                                                qb16);
      gemm_bf16<<<ggrid, 256, 0, stream>>>((const short*)qb16, wtp, kb);
      res_ln_kernel<<<M, 256, 0, stream>>>(h, h16, kb, bp + (size_t)i * Hh,
                                           lng + (size_t)i * Hh,
                                           lnb + (size_t)i * Hh);
    }

    pool_kernel<<<(chunk * Hh) / 256, 256, 0, stream>>>(
        h, pool + (size_t)b0 * 2 * Hh);
  }

  final_kernel<<<Bb, 256, 0, stream>>>(pool, proj_w, proj_b, proj_ln_g,
                                       proj_ln_b, out);
}

// Round 4
// 2336.673 us; speedup vs baseline: 4.7930x; 3.4123x over previous
//
#include <hip/hip_runtime.h>
#include <hip/hip_bf16.h>

// ---------------------------------------------------------------------------
// TemporalExtractor round 4: MFMA flash attention.
//   - QKV GEMMs write bf16 (only attn consumes them); V-GEMM writes V^T
//     global layout [b][g][d][T] so attn PV fragments are contiguous.
//   - attn: 128-q-row blocks, 4 waves x 32 rows, 16x16x32 bf16 MFMA for
//     QK^T and PV, online softmax in C-layout, P via wave-private LDS.
//   - out-proj GEMM keeps fp32 output (residual precision).
// ---------------------------------------------------------------------------

constexpr int Bb = 32, Tt = 1024, Ff = 64, Hh = 768, CH = 256, Gg = 4, Dd = 192;
constexpr float EPS = 1e-5f;

typedef __attribute__((ext_vector_type(8))) short short8;   // 8 bf16 = 4 VGPRs
typedef __attribute__((ext_vector_type(4))) float floatx4;  // MFMA acc

__device__ __forceinline__ void async_copy16(const void* g, void* l) {
  __builtin_amdgcn_global_load_lds(
      (const __attribute__((address_space(1))) unsigned int*)g,
      (__attribute__((address_space(3))) unsigned int*)l, 16, 0, 0);
}

__device__ __forceinline__ short bf16s(float f) {
  __hip_bfloat16 h = __float2bfloat16(f);
  return *(short*)&h;
}

__device__ __forceinline__ float2 block_reduce2(float a, float b, float* tmp) {
  int lane = threadIdx.x & 63, wid = threadIdx.x >> 6;
#pragma unroll
  for (int off = 32; off > 0; off >>= 1) {
    a += __shfl_down(a, off);
    b += __shfl_down(b, off);
  }
  if (lane == 0) { tmp[wid] = a; tmp[4 + wid] = b; }
  __syncthreads();
  if (threadIdx.x == 0) {
    tmp[0] = tmp[0] + tmp[1] + tmp[2] + tmp[3];
    tmp[4] = tmp[4] + tmp[5] + tmp[6] + tmp[7];
  }
  __syncthreads();
  float2 r; r.x = tmp[0]; r.y = tmp[4];
  return r;
}

// ---------------------------------------------------------------------------
// 0) Weight transpose+cast: src fp32 [K=768][N=768] -> wt bf16 [z][N][K]
// ---------------------------------------------------------------------------
__global__ __launch_bounds__(256) void wt_cast_kernel(
    const float* __restrict__ wq, const float* __restrict__ wk,
    const float* __restrict__ wv, const float* __restrict__ wp,
    __hip_bfloat16* __restrict__ wt) {
  const int z = blockIdx.z;
  const float* src = (z < 2 ? wq : z < 4 ? wk : z < 6 ? wv : wp) +
                     (size_t)(z & 1) * Hh * Hh;
  __shared__ float tile[32][33];
  const int n0 = blockIdx.x * 32, k0 = blockIdx.y * 32;
  const int tx = threadIdx.x & 31, ty = threadIdx.x >> 5;
#pragma unroll
  for (int r = 0; r < 4; r++)
    tile[ty + 8 * r][tx] = src[(size_t)(k0 + ty + 8 * r) * Hh + n0 + tx];
  __syncthreads();
#pragma unroll
  for (int r = 0; r < 4; r++)
    wt[((size_t)z * Hh + n0 + ty + 8 * r) * Hh + k0 + tx] =
        __float2bfloat16(tile[tx][ty + 8 * r]);
}

// ---------------------------------------------------------------------------
// 1) Gated conv branch (unchanged)
// ---------------------------------------------------------------------------
__global__ __launch_bounds__(256) void conv_gated_kernel(
    const float* __restrict__ x, const float* __restrict__ wf,
    const float* __restrict__ bf, const float* __restrict__ wg,
    const float* __restrict__ bg, float* __restrict__ out, int K, int coff) {
  const int t0 = blockIdx.x * 32;
  const int b = blockIdx.y;
  const int pad = (K - 1) / 2;
  const int span = 32 + 2 * pad;  // <= 38
  __shared__ float xs[38][64];

  for (int e = threadIdx.x; e < span * Ff; e += 256) {
    int tt = e >> 6, f = e & 63;
    int tg = t0 - pad + tt;
    xs[tt][f] = (tg >= 0 && tg < Tt) ? x[((size_t)b * Tt + tg) * Ff + f] : 0.f;
  }
  __syncthreads();

  const int c = threadIdx.x;
  float accf[32], accg[32];
  const float bf0 = bf[c], bg0 = bg[c];
#pragma unroll
  for (int t = 0; t < 32; t++) { accf[t] = bf0; accg[t] = bg0; }

  for (int kk = 0; kk < K; kk++) {
#pragma unroll 4
    for (int f = 0; f < Ff; f++) {
      float wfv = wf[(kk * Ff + f) * CH + c];
      float wgv = wg[(kk * Ff + f) * CH + c];
#pragma unroll
      for (int t = 0; t < 32; t++) {
        float xv = xs[t + kk][f];
        accf[t] = fmaf(xv, wfv, accf[t]);
        accg[t] = fmaf(xv, wgv, accg[t]);
      }
    }
  }
#pragma unroll
  for (int t = 0; t < 32; t++) {
    float a = accf[t] > 0.f ? accf[t] : 0.f;
    float s = 1.f / (1.f + __expf(-accg[t]));
    out[((size_t)b * Tt + t0 + t) * Hh + coff + c] = a * s;
  }
}

// ---------------------------------------------------------------------------
// 2) LayerNorm (fp32 + bf16 outputs)
// ---------------------------------------------------------------------------
__global__ __launch_bounds__(256) void ln_kernel(
    const float* __restrict__ in, float* __restrict__ out,
    __hip_bfloat16* __restrict__ out16, const float* __restrict__ g,
    const float* __restrict__ bt) {
  __shared__ float red[8];
  const size_t row = blockIdx.x;
  float v[3], s = 0.f, ss = 0.f;
#pragma unroll
  for (int j = 0; j < 3; j++) {
    int c = threadIdx.x + j * 256;
    float t = in[row * Hh + c];
    v[j] = t; s += t; ss += t * t;
  }
  float2 r = block_reduce2(s, ss, red);
  float mu = r.x * (1.f / Hh);
  float var = r.y * (1.f / Hh) - mu * mu;
  float rs = rsqrtf(var + EPS);
#pragma unroll
  for (int j = 0; j < 3; j++) {
    int c = threadIdx.x + j * 256;
    float o = (v[j] - mu) * rs * g[c] + bt[c];
    out[row * Hh + c] = o;
    out16[row * Hh + c] = __float2bfloat16(o);
  }
}

__global__ __launch_bounds__(256) void res_ln_kernel(
    float* __restrict__ h, __hip_bfloat16* __restrict__ h16,
    const float* __restrict__ y, const float* __restrict__ bp,
    const float* __restrict__ g, const float* __restrict__ bt) {
  __shared__ float red[8];
  const size_t row = blockIdx.x;
  float v[3], s = 0.f, ss = 0.f;
#pragma unroll
  for (int j = 0; j < 3; j++) {
    int c = threadIdx.x + j * 256;
    float t = h[row * Hh + c] + y[row * Hh + c] + bp[c];
    v[j] = t; s += t; ss += t * t;
  }
  float2 r = block_reduce2(s, ss, red);
  float mu = r.x * (1.f / Hh);
  float var = r.y * (1.f / Hh) - mu * mu;
  float rs = rsqrtf(var + EPS);
#pragma unroll
  for (int j = 0; j < 3; j++) {
    int c = threadIdx.x + j * 256;
    float o = (v[j] - mu) * rs * g[c] + bt[c];
    h[row * Hh + c] = o;
    h16[row * Hh + c] = __float2bfloat16(o);
  }
}

// ---------------------------------------------------------------------------
// 3) bf16 MFMA GEMM, 128x128 tile, BK=32. MODE: 0 = fp32 out [tok][768],
//    1 = bf16 out [tok][768], 2 = bf16 V^T out [(b*4+g)*192+d][1024].
// ---------------------------------------------------------------------------
template <int MODE>
__global__ __launch_bounds__(256) void gemm_bf16(
    const short* __restrict__ A, const short* __restrict__ Bt,
    void* __restrict__ Cv) {
  constexpr int K = 768, N = 768;
  __shared__ __align__(16) short Asl[128 * 32];  // [m][k]
  __shared__ __align__(16) short Bsl[128 * 32];  // [n][k]
  const int n0 = blockIdx.x * 128, m0 = blockIdx.y * 128;
  const int lane = threadIdx.x & 63;
  const int w = threadIdx.x >> 6, wm = w >> 1, wn = w & 1;
  const int lm = lane & 15, quad = lane >> 4;

  floatx4 acc[4][4];
#pragma unroll
  for (int i = 0; i < 4; i++)
#pragma unroll
    for (int j = 0; j < 4; j++) acc[i][j] = (floatx4)0.f;

  for (int k0 = 0; k0 < K; k0 += 32) {
    __syncthreads();
#pragma unroll
    for (int half = 0; half < 2; half++) {
      int s = half * 256 + threadIdx.x;  // 512 slots of 16B per tile
      int m = s >> 2, ks = (s & 3) * 8;
      async_copy16(&A[(size_t)(m0 + m) * K + k0 + ks], &Asl[s * 8]);
      async_copy16(&Bt[(size_t)(n0 + m) * K + k0 + ks], &Bsl[s * 8]);
    }
    __syncthreads();

    short8 a[4], b[4];
#pragma unroll
    for (int i = 0; i < 4; i++)
      a[i] = *(const short8*)&Asl[(wm * 64 + i * 16 + lm) * 32 + quad * 8];
#pragma unroll
    for (int j = 0; j < 4; j++)
      b[j] = *(const short8*)&Bsl[(wn * 64 + j * 16 + lm) * 32 + quad * 8];
#pragma unroll
    for (int i = 0; i < 4; i++)
#pragma unroll
      for (int j = 0; j < 4; j++)
        acc[i][j] = __builtin_amdgcn_mfma_f32_16x16x32_bf16(a[i], b[j],
                                                            acc[i][j], 0, 0, 0);
  }

  const int rbase = quad * 4;
#pragma unroll
  for (int i = 0; i < 4; i++)
#pragma unroll
    for (int j = 0; j < 4; j++) {
      int mrow = m0 + wm * 64 + i * 16 + rbase;
      int ncol = n0 + wn * 64 + j * 16 + lm;
      if (MODE == 0) {
        float* C = (float*)Cv;
#pragma unroll
        for (int r = 0; r < 4; r++)
          C[(size_t)(mrow + r) * N + ncol] = acc[i][j][r];
      } else if (MODE == 1) {
        short* C = (short*)Cv;
#pragma unroll
        for (int r = 0; r < 4; r++)
          C[(size_t)(mrow + r) * N + ncol] = bf16s(acc[i][j][r]);
      } else {
        short* C = (short*)Cv;
        int bL = mrow >> 10, t = mrow & 1023;
        int g = ncol / Dd, d = ncol % Dd;
        short4 sv;
        sv.x = bf16s(acc[i][j][0]); sv.y = bf16s(acc[i][j][1]);
        sv.z = bf16s(acc[i][j][2]); sv.w = bf16s(acc[i][j][3]);
        *(short4*)&C[(((size_t)bL * Gg + g) * Dd + d) * Tt + t] = sv;
      }
    }
}

// ---------------------------------------------------------------------------
// 4) MFMA flash attention. grid (T/128, G, chunk), block 256 (4 waves).
//    Wave w: q-rows [q0+w*32, +32) (2 M-tiles). K-tile 32 rows per step.
//    q16/k16: bf16 [tok][768].  vt16: bf16 [(b*4+g)*192+d][1024].
//    o16 written in place of q16 region (each block owns its q-rows).
// ---------------------------------------------------------------------------
__global__ __launch_bounds__(256, 2) void attn_mfma(
    const short* __restrict__ q16, const short* __restrict__ k16,
    const short* __restrict__ vt16, short* __restrict__ o16) {
  const float scale = 0.0721687836f;  // 192^-0.5
  const int q0 = blockIdx.x * 128;
  const int g = blockIdx.y;
  const int b = blockIdx.z;
  const int tid = threadIdx.x;
  const int w = tid >> 6, lane = tid & 63, lm = lane & 15, quad = lane >> 4;

  __shared__ __align__(16) short Ks[32 * 200];  // [k][d], padded rows
  __shared__ __align__(16) short Vt[192 * 32];  // [d][k]
  __shared__ __align__(16) short Ps[4 * 32 * 32];
  short* Pw = &Ps[w * 1024];

  // preload Q fragments (A-layout: m=lm, kk=quad*8+j)
  short8 qf[2][6];
#pragma unroll
  for (int mt = 0; mt < 2; mt++)
#pragma unroll
    for (int ks = 0; ks < 6; ks++) {
      int tok = b * Tt + q0 + w * 32 + mt * 16 + lm;
      qf[mt][ks] = *(const short8*)&q16[(size_t)tok * Hh + g * Dd + ks * 32 +
                                        quad * 8];
    }

  floatx4 Oa[2][12];
#pragma unroll
  for (int mt = 0; mt < 2; mt++)
#pragma unroll
    for (int n = 0; n < 12; n++) Oa[mt][n] = (floatx4)0.f;
  float mr[2][4], lr[2][4];
#pragma unroll
  for (int mt = 0; mt < 2; mt++)
#pragma unroll
    for (int r = 0; r < 4; r++) { mr[mt][r] = -1e30f; lr[mt][r] = 0.f; }

  for (int kt = 0; kt < Tt; kt += 32) {
    __syncthreads();  // all waves done reading previous Ks/Vt
    // stage K tile: 32 rows x 192 shorts -> padded 200-short rows
#pragma unroll
    for (int it = 0; it < 3; it++) {
      int s = it * 256 + tid;            // 0..767, 24 slots/row
      int row = s / 24, cs = s - row * 24;
      short8 kv = *(const short8*)&k16[(size_t)(b * Tt + kt + row) * Hh +
                                       g * Dd + cs * 8];
      *(short8*)&Ks[row * 200 + cs * 8] = kv;
    }
    // stage V^T tile: 192 rows x 32 shorts, contiguous -> async copy
#pragma unroll
    for (int it = 0; it < 3; it++) {
      int s = it * 256 + tid;            // 0..767, 4 slots/row
      int d = s >> 2, cs = s & 3;
      async_copy16(&vt16[(((size_t)b * Gg + g) * Dd + d) * Tt + kt + cs * 8],
                   &Vt[s * 8]);
    }
    __syncthreads();

    // S = Q K^T  (rows=q in quad*4+reg, cols=k in lm + 16*ntile)
    floatx4 sa[2][2];
#pragma unroll
    for (int mt = 0; mt < 2; mt++)
#pragma unroll
      for (int j = 0; j < 2; j++) sa[mt][j] = (floatx4)0.f;
#pragma unroll
    for (int ks = 0; ks < 6; ks++) {
      short8 k0 = *(const short8*)&Ks[lm * 200 + ks * 32 + quad * 8];
      short8 k1 = *(const short8*)&Ks[(16 + lm) * 200 + ks * 32 + quad * 8];
      sa[0][0] = __builtin_amdgcn_mfma_f32_16x16x32_bf16(qf[0][ks], k0, sa[0][0], 0, 0, 0);
      sa[0][1] = __builtin_amdgcn_mfma_f32_16x16x32_bf16(qf[0][ks], k1, sa[0][1], 0, 0, 0);
      sa[1][0] = __builtin_amdgcn_mfma_f32_16x16x32_bf16(qf[1][ks], k0, sa[1][0], 0, 0, 0);
      sa[1][1] = __builtin_amdgcn_mfma_f32_16x16x32_bf16(qf[1][ks], k1, sa[1][1], 0, 0, 0);
    }

    // online softmax; write P (bf16) to wave-private LDS; rescale O
#pragma unroll
    for (int mt = 0; mt < 2; mt++) {
#pragma unroll
      for (int r = 0; r < 4; r++) {
        float s0 = sa[mt][0][r] * scale, s1 = sa[mt][1][r] * scale;
        float mx = fmaxf(s0, s1);
        mx = fmaxf(mx, __shfl_xor(mx, 1));
        mx = fmaxf(mx, __shfl_xor(mx, 2));
        mx = fmaxf(mx, __shfl_xor(mx, 4));
        mx = fmaxf(mx, __shfl_xor(mx, 8));
        float mnew = fmaxf(mr[mt][r], mx);
        float alpha = __expf(mr[mt][r] - mnew);
        float p0 = __expf(s0 - mnew), p1 = __expf(s1 - mnew);
        float sum = p0 + p1;
        sum += __shfl_xor(sum, 1);
        sum += __shfl_xor(sum, 2);
        sum += __shfl_xor(sum, 4);
        sum += __shfl_xor(sum, 8);
        lr[mt][r] = lr[mt][r] * alpha + sum;
        mr[mt][r] = mnew;
        Pw[(mt * 16 + quad * 4 + r) * 32 + lm] = bf16s(p0);
        Pw[(mt * 16 + quad * 4 + r) * 32 + 16 + lm] = bf16s(p1);
#pragma unroll
        for (int n = 0; n < 12; n++) Oa[mt][n][r] *= alpha;
      }
    }

    // O += P V  (P wave-private: no barrier needed)
    short8 pf0 = *(const short8*)&Pw[lm * 32 + quad * 8];
    short8 pf1 = *(const short8*)&Pw[(16 + lm) * 32 + quad * 8];
#pragma unroll
    for (int n = 0; n < 12; n++) {
      short8 vf = *(const short8*)&Vt[(n * 16 + lm) * 32 + quad * 8];
      Oa[0][n] = __builtin_amdgcn_mfma_f32_16x16x32_bf16(pf0, vf, Oa[0][n], 0, 0, 0);
      Oa[1][n] = __builtin_amdgcn_mfma_f32_16x16x32_bf16(pf1, vf, Oa[1][n], 0, 0, 0);
    }
  }

  // epilogue: O /= l, write bf16
#pragma unroll
  for (int mt = 0; mt < 2; mt++)
#pragma unroll
    for (int r = 0; r < 4; r++) {
      float inv = 1.f / lr[mt][r];
      int tok = b * Tt + q0 + w * 32 + mt * 16 + quad * 4 + r;
#pragma unroll
      for (int n = 0; n < 12; n++)
        o16[(size_t)tok * Hh + g * Dd + n * 16 + lm] = bf16s(Oa[mt][n][r] * inv);
    }
}

// ---------------------------------------------------------------------------
// 5) Pool (unchanged)
// ---------------------------------------------------------------------------
__global__ __launch_bounds__(256) void pool_kernel(const float* __restrict__ h,
                                                   float* __restrict__ pool) {
  int idx = blockIdx.x * 256 + threadIdx.x;
  int b = idx / Hh, c = idx % Hh;
  float s = 0.f, ss = 0.f;
  for (int t = 0; t < Tt; t++) {
    float v = h[((size_t)b * Tt + t) * Hh + c];
    s += v; ss += v * v;
  }
  float mu = s * (1.f / Tt);
  float var = ss * (1.f / Tt) - mu * mu;
  pool[(size_t)b * 1536 + c] = mu;
  pool[(size_t)b * 1536 + 768 + c] = sqrtf(fmaxf(var, 0.f));
}

// ---------------------------------------------------------------------------
// 6) Final projection (unchanged)
// ---------------------------------------------------------------------------
__global__ __launch_bounds__(256) void final_kernel(
    const float* __restrict__ pool, const float* __restrict__ pw,
    const float* __restrict__ pb, const float* __restrict__ g,
    const float* __restrict__ bt, float* __restrict__ out) {
  __shared__ float ms[1536];
  __shared__ float red[8];
  const int b = blockIdx.x;
  for (int e = threadIdx.x; e < 1536; e += 256) ms[e] = pool[(size_t)b * 1536 + e];
  __syncthreads();
  const int n0 = threadIdx.x, n1 = threadIdx.x + 256, n2 = threadIdx.x + 512;
  float a0 = pb[n0], a1 = pb[n1], a2 = pb[n2];
  for (int k = 0; k < 1536; k++) {
    float m = ms[k];
    const float* row = &pw[(size_t)k * Hh];
    a0 = fmaf(m, row[n0], a0);
    a1 = fmaf(m, row[n1], a1);
    a2 = fmaf(m, row[n2], a2);
  }
  float s = a0 + a1 + a2, ss = a0 * a0 + a1 * a1 + a2 * a2;
  float2 r = block_reduce2(s, ss, red);
  float mu = r.x * (1.f / Hh);
  float var = r.y * (1.f / Hh) - mu * mu;
  float rs = rsqrtf(var + EPS);
  float o0 = (a0 - mu) * rs * g[n0] + bt[n0];
  float o1 = (a1 - mu) * rs * g[n1] + bt[n1];
  float o2 = (a2 - mu) * rs * g[n2] + bt[n2];
  out[(size_t)b * Hh + n0] = o0 > 0.f ? o0 : 0.f;
  out[(size_t)b * Hh + n1] = o1 > 0.f ? o1 : 0.f;
  out[(size_t)b * Hh + n2] = o2 > 0.f ? o2 : 0.f;
}

// ---------------------------------------------------------------------------
extern "C" void kernel_launch(void* const* d_in, const int* in_sizes, int n_in,
                              void* d_out, int out_size, void* d_ws,
                              size_t ws_size, hipStream_t stream) {
  (void)in_sizes; (void)n_in; (void)out_size;
  const float* x = (const float*)d_in[0];
  const float* cw[3][4];
  for (int j = 0; j < 3; j++)
    for (int p = 0; p < 4; p++) cw[j][p] = (const float*)d_in[1 + j * 4 + p];
  const float* conv_ln_g = (const float*)d_in[13];
  const float* conv_ln_b = (const float*)d_in[14];
  const float* wq = (const float*)d_in[15];
  const float* wk = (const float*)d_in[16];
  const float* wv = (const float*)d_in[17];
  const float* wp = (const float*)d_in[18];
  const float* bp = (const float*)d_in[19];
  const float* lng = (const float*)d_in[20];
  const float* lnb = (const float*)d_in[21];
  const float* proj_w = (const float*)d_in[22];
  const float* proj_b = (const float*)d_in[23];
  const float* proj_ln_g = (const float*)d_in[24];
  const float* proj_ln_b = (const float*)d_in[25];
  float* out = (float*)d_out;

  // --- workspace: per-elem 16B: h(4) y(4) h16(2) q16(2) k16(2) vt16(2) ----
  const size_t perb = (size_t)Tt * Hh;
  const size_t fixedB = 8ull * Hh * Hh * 2 + (size_t)Bb * 2 * Hh * 4;  // wt+pool
  int chunk = Bb;
  while (chunk > 1 && 16ull * perb * chunk + fixedB > ws_size) chunk >>= 1;

  const size_t crow = perb * (size_t)chunk;
  char* p = (char*)d_ws;
  float* h   = (float*)p;           p += crow * 4;
  float* y   = (float*)p;           p += crow * 4;
  __hip_bfloat16* h16 = (__hip_bfloat16*)p;  p += crow * 2;
  short* q16 = (short*)p;           p += crow * 2;
  short* k16 = (short*)p;           p += crow * 2;
  short* v16t = (short*)p;          p += crow * 2;
  __hip_bfloat16* wt = (__hip_bfloat16*)p;   p += 8ull * Hh * Hh * 2;
  float* pool = (float*)p;

  wt_cast_kernel<<<dim3(24, 24, 8), 256, 0, stream>>>(wq, wk, wv, wp, wt);

  const int Ks[3] = {3, 5, 7};
  const short* wts = (const short*)wt;

  for (int b0 = 0; b0 < Bb; b0 += chunk) {
    const float* xb = x + (size_t)b0 * Tt * Ff;
    const int M = chunk * Tt;
    const dim3 ggrid(Hh / 128, M / 128);

    for (int j = 0; j < 3; j++) {
      conv_gated_kernel<<<dim3(Tt / 32, chunk), 256, 0, stream>>>(
          xb, cw[j][0], cw[j][1], cw[j][2], cw[j][3], y, Ks[j], j * CH);
    }
    ln_kernel<<<M, 256, 0, stream>>>(y, h, h16, conv_ln_g, conv_ln_b);

    for (int i = 0; i < 2; i++) {
      const short* wtq = wts + (size_t)(0 * 2 + i) * Hh * Hh;
      const short* wtk = wts + (size_t)(1 * 2 + i) * Hh * Hh;
      const short* wtv = wts + (size_t)(2 * 2 + i) * Hh * Hh;
      const short* wtp = wts + (size_t)(3 * 2 + i) * Hh * Hh;
      gemm_bf16<1><<<ggrid, 256, 0, stream>>>((const short*)h16, wtq, q16);
      gemm_bf16<1><<<ggrid, 256, 0, stream>>>((const short*)h16, wtk, k16);
      gemm_bf16<2><<<ggrid, 256, 0, stream>>>((const short*)h16, wtv, v16t);
      attn_mfma<<<dim3(Tt / 128, Gg, chunk), 256, 0, stream>>>(q16, k16, v16t,
                                                               q16);
      gemm_bf16<0><<<ggrid, 256, 0, stream>>>(q16, wtp, y);
      res_ln_kernel<<<M, 256, 0, stream>>>(h, h16, y, bp + (size_t)i * Hh,
                                           lng + (size_t)i * Hh,
                                           lnb + (size_t)i * Hh);
    }

    pool_kernel<<<(chunk * Hh) / 256, 256, 0, stream>>>(
        h, pool + (size_t)b0 * 2 * Hh);
  }

  final_kernel<<<Bb, 256, 0, stream>>>(pool, proj_w, proj_b, proj_ln_g,
                                       proj_ln_b, out);
}

// Round 5
// 1708.607 us; speedup vs baseline: 6.5549x; 1.3676x over previous
//
#include <hip/hip_runtime.h>
#include <hip/hip_bf16.h>

// ---------------------------------------------------------------------------
// TemporalExtractor round 5:
//   - conv front-end -> implicit-GEMM bf16 MFMA (shifted-window A tiles),
//     raw f/g planes written bf16; fused gate(bias+relu*sigmoid)+LN kernel.
//   - QKV GEMMs fused into one N=2304 dispatch (weights packed [i][q|k|v|p]).
//   - attention / proj GEMM / res_ln / pool / final unchanged from round 4.
// ---------------------------------------------------------------------------

constexpr int Bb = 32, Tt = 1024, Ff = 64, Hh = 768, Gg = 4, Dd = 192;
constexpr float EPS = 1e-5f;
constexpr int WKMAX = 448;  // padded conv-weight K stride (7*64)

typedef __attribute__((ext_vector_type(8))) short short8;   // 8 bf16 = 4 VGPRs
typedef __attribute__((ext_vector_type(4))) float floatx4;  // MFMA acc

__device__ __forceinline__ void async_copy16(const void* g, void* l) {
  __builtin_amdgcn_global_load_lds(
      (const __attribute__((address_space(1))) unsigned int*)g,
      (__attribute__((address_space(3))) unsigned int*)l, 16, 0, 0);
}

__device__ __forceinline__ short bf16s(float f) {
  __hip_bfloat16 h = __float2bfloat16(f);
  return *(short*)&h;
}

__device__ __forceinline__ float2 block_reduce2(float a, float b, float* tmp) {
  int lane = threadIdx.x & 63, wid = threadIdx.x >> 6;
#pragma unroll
  for (int off = 32; off > 0; off >>= 1) {
    a += __shfl_down(a, off);
    b += __shfl_down(b, off);
  }
  if (lane == 0) { tmp[wid] = a; tmp[4 + wid] = b; }
  __syncthreads();
  if (threadIdx.x == 0) {
    tmp[0] = tmp[0] + tmp[1] + tmp[2] + tmp[3];
    tmp[4] = tmp[4] + tmp[5] + tmp[6] + tmp[7];
  }
  __syncthreads();
  float2 r; r.x = tmp[0]; r.y = tmp[4];
  return r;
}

// ---------------------------------------------------------------------------
// 0a) Attn/proj weight transpose+cast: fp32 [K][N] -> bf16 [z][N][K],
//     z = i*4 + {0:q,1:k,2:v,3:p}  (q,k,v contiguous per block for fused GEMM)
// ---------------------------------------------------------------------------
__global__ __launch_bounds__(256) void wt_cast_kernel(
    const float* __restrict__ wq, const float* __restrict__ wk,
    const float* __restrict__ wv, const float* __restrict__ wp,
    __hip_bfloat16* __restrict__ wt) {
  const int z = blockIdx.z;
  const int m = z & 3, i = z >> 2;
  const float* src =
      (m == 0 ? wq : m == 1 ? wk : m == 2 ? wv : wp) + (size_t)i * Hh * Hh;
  __shared__ float tile[32][33];
  const int n0 = blockIdx.x * 32, k0 = blockIdx.y * 32;
  const int tx = threadIdx.x & 31, ty = threadIdx.x >> 5;
#pragma unroll
  for (int r = 0; r < 4; r++)
    tile[ty + 8 * r][tx] = src[(size_t)(k0 + ty + 8 * r) * Hh + n0 + tx];
  __syncthreads();
#pragma unroll
  for (int r = 0; r < 4; r++)
    wt[((size_t)z * Hh + n0 + ty + 8 * r) * Hh + k0 + tx] =
        __float2bfloat16(tile[tx][ty + 8 * r]);
}

// ---------------------------------------------------------------------------
// 0b) Conv weight cast: [Kw][64][256] fp32 (wf,wg) -> wcv bf16 [j][512][448]
//     row n<256: wf channel n; n>=256: wg channel n-256. k = kk*64+f,
//     zero-padded to 448. Tiny (1.4 MB) -> one thread per output element.
// ---------------------------------------------------------------------------
__global__ __launch_bounds__(256) void wcv_cast_kernel(
    const float* __restrict__ wf3, const float* __restrict__ wg3,
    const float* __restrict__ wf5, const float* __restrict__ wg5,
    const float* __restrict__ wf7, const float* __restrict__ wg7,
    __hip_bfloat16* __restrict__ wcv) {
  int idx = blockIdx.x * 256 + threadIdx.x;  // 3*512*448 = 688128
  if (idx >= 3 * 512 * WKMAX) return;
  int j = idx / (512 * WKMAX);
  int rem = idx - j * 512 * WKMAX;
  int n = rem / WKMAX, k = rem % WKMAX;
  int Kw = 3 + 2 * j;
  float v = 0.f;
  if (k < Kw * 64) {
    const float* src = (n < 256) ? (j == 0 ? wf3 : j == 1 ? wf5 : wf7)
                                 : (j == 0 ? wg3 : j == 1 ? wg5 : wg7);
    v = src[(size_t)k * 256 + (n & 255)];
  }
  wcv[idx] = __float2bfloat16(v);
}

// 0c) x cast fp32 -> bf16, B*T*64 elems
__global__ __launch_bounds__(256) void x_cast_kernel(
    const float* __restrict__ x, short* __restrict__ x16, int n8) {
  int idx = blockIdx.x * 256 + threadIdx.x;  // n8 = total/8
  if (idx >= n8) return;
  const float4 a = ((const float4*)x)[idx * 2];
  const float4 b = ((const float4*)x)[idx * 2 + 1];
  short8 o;
  o[0] = bf16s(a.x); o[1] = bf16s(a.y); o[2] = bf16s(a.z); o[3] = bf16s(a.w);
  o[4] = bf16s(b.x); o[5] = bf16s(b.y); o[6] = bf16s(b.z); o[7] = bf16s(b.w);
  ((short8*)x16)[idx] = o;
}

// ---------------------------------------------------------------------------
// 1) Conv as implicit GEMM. grid (T/128, 512/128, chunk*3), block 256.
//    C[t][n] = sum_kk sum_f x[t+kk-pad][f] * w[j][n][kk*64+f]
//    A-tile per kk: shifted x16 window (bounds-checked). LDS stride 72.
//    Output raw bf16 -> yraw[tok][j*512 + n].
// ---------------------------------------------------------------------------
__global__ __launch_bounds__(256) void conv_gemm_kernel(
    const short* __restrict__ x16, const short* __restrict__ wcv,
    short* __restrict__ yraw, int b0) {
  __shared__ __align__(16) short Asl[128 * 72];
  __shared__ __align__(16) short Bsl[128 * 72];
  const int t0 = blockIdx.x * 128, n0 = blockIdx.y * 128;
  const int bl = blockIdx.z / 3, j = blockIdx.z % 3;
  const int Kw = 3 + 2 * j, pad = j + 1;
  const int bglob = b0 + bl;
  const short* wb = wcv + (size_t)j * 512 * WKMAX;
  const int tid = threadIdx.x;
  const int lane = tid & 63;
  const int w = tid >> 6, wm = w >> 1, wn = w & 1;
  const int lm = lane & 15, quad = lane >> 4;

  floatx4 acc[4][4];
#pragma unroll
  for (int i = 0; i < 4; i++)
#pragma unroll
    for (int jj = 0; jj < 4; jj++) acc[i][jj] = (floatx4)0.f;

  for (int kk = 0; kk < Kw; kk++) {
    __syncthreads();
#pragma unroll
    for (int it = 0; it < 4; it++) {
      int s = it * 256 + tid;        // 1024 slots of 8 shorts
      int row = s >> 3, c8 = s & 7;
      int t = t0 + row + kk - pad;
      short8 av = (short8)0;
      if (t >= 0 && t < Tt)
        av = *(const short8*)&x16[((size_t)bglob * Tt + t) * Ff + c8 * 8];
      *(short8*)&Asl[row * 72 + c8 * 8] = av;
      short8 bv = *(const short8*)&wb[(size_t)(n0 + row) * WKMAX + kk * 64 +
                                      c8 * 8];
      *(short8*)&Bsl[row * 72 + c8 * 8] = bv;
    }
    __syncthreads();
#pragma unroll
    for (int ks = 0; ks < 2; ks++) {
      short8 a[4], b[4];
#pragma unroll
      for (int i = 0; i < 4; i++)
        a[i] = *(const short8*)&Asl[(wm * 64 + i * 16 + lm) * 72 + ks * 32 +
                                    quad * 8];
#pragma unroll
      for (int jj = 0; jj < 4; jj++)
        b[jj] = *(const short8*)&Bsl[(wn * 64 + jj * 16 + lm) * 72 + ks * 32 +
                                     quad * 8];
#pragma unroll
      for (int i = 0; i < 4; i++)
#pragma unroll
        for (int jj = 0; jj < 4; jj++)
          acc[i][jj] = __builtin_amdgcn_mfma_f32_16x16x32_bf16(a[i], b[jj],
                                                               acc[i][jj],
                                                               0, 0, 0);
    }
  }

  const int rbase = quad * 4;
#pragma unroll
  for (int i = 0; i < 4; i++)
#pragma unroll
    for (int jj = 0; jj < 4; jj++) {
      int mrow = t0 + wm * 64 + i * 16 + rbase;
      int ncol = n0 + wn * 64 + jj * 16 + lm;
#pragma unroll
      for (int r = 0; r < 4; r++)
        yraw[((size_t)bl * Tt + mrow + r) * 1536 + j * 512 + ncol] =
            bf16s(acc[i][jj][r]);
    }
}

// ---------------------------------------------------------------------------
// 2) Fused gate + LayerNorm: per token read 1536 raw bf16, gate -> 768,
//    LN -> h fp32 + h16 bf16. One block per token row.
// ---------------------------------------------------------------------------
__global__ __launch_bounds__(256) void gate_ln_kernel(
    const short* __restrict__ yraw, float* __restrict__ h,
    __hip_bfloat16* __restrict__ h16, const float* __restrict__ bf3,
    const float* __restrict__ bg3, const float* __restrict__ bf5,
    const float* __restrict__ bg5, const float* __restrict__ bf7,
    const float* __restrict__ bg7, const float* __restrict__ g,
    const float* __restrict__ bt) {
  __shared__ float red[8];
  const size_t row = blockIdx.x;
  float v[3], s = 0.f, ss = 0.f;
#pragma unroll
  for (int jj = 0; jj < 3; jj++) {
    int c = threadIdx.x + jj * 256;
    int br = c >> 8, cc = c & 255;
    const float* bfp = br == 0 ? bf3 : br == 1 ? bf5 : bf7;
    const float* bgp = br == 0 ? bg3 : br == 1 ? bg5 : bg7;
    __hip_bfloat16 rf = *(const __hip_bfloat16*)&yraw[row * 1536 + br * 512 + cc];
    __hip_bfloat16 rg =
        *(const __hip_bfloat16*)&yraw[row * 1536 + br * 512 + 256 + cc];
    float f = __bfloat162float(rf) + bfp[cc];
    float gt = __bfloat162float(rg) + bgp[cc];
    float a = f > 0.f ? f : 0.f;
    float t = a * (1.f / (1.f + __expf(-gt)));
    v[jj] = t; s += t; ss += t * t;
  }
  float2 r = block_reduce2(s, ss, red);
  float mu = r.x * (1.f / Hh);
  float var = r.y * (1.f / Hh) - mu * mu;
  float rs = rsqrtf(var + EPS);
#pragma unroll
  for (int jj = 0; jj < 3; jj++) {
    int c = threadIdx.x + jj * 256;
    float o = (v[jj] - mu) * rs * g[c] + bt[c];
    h[row * Hh + c] = o;
    h16[row * Hh + c] = __float2bfloat16(o);
  }
}

// residual LN: h = LN(h + y + bp), emit fp32 + bf16
__global__ __launch_bounds__(256) void res_ln_kernel(
    float* __restrict__ h, __hip_bfloat16* __restrict__ h16,
    const float* __restrict__ y, const float* __restrict__ bp,
    const float* __restrict__ g, const float* __restrict__ bt) {
  __shared__ float red[8];
  const size_t row = blockIdx.x;
  float v[3], s = 0.f, ss = 0.f;
#pragma unroll
  for (int jj = 0; jj < 3; jj++) {
    int c = threadIdx.x + jj * 256;
    float t = h[row * Hh + c] + y[row * Hh + c] + bp[c];
    v[jj] = t; s += t; ss += t * t;
  }
  float2 r = block_reduce2(s, ss, red);
  float mu = r.x * (1.f / Hh);
  float var = r.y * (1.f / Hh) - mu * mu;
  float rs = rsqrtf(var + EPS);
#pragma unroll
  for (int jj = 0; jj < 3; jj++) {
    int c = threadIdx.x + jj * 256;
    float o = (v[jj] - mu) * rs * g[c] + bt[c];
    h[row * Hh + c] = o;
    h16[row * Hh + c] = __float2bfloat16(o);
  }
}

// ---------------------------------------------------------------------------
// 3a) Fused QKV GEMM: A[M,768]bf16 @ Bt[2304,768]^T. grid (18, M/128).
//     Output routed: n<768 -> q16, <1536 -> k16, else v^T [(b*4+g)*192+d][T].
// ---------------------------------------------------------------------------
__global__ __launch_bounds__(256) void gemm_qkv(
    const short* __restrict__ A, const short* __restrict__ Bt,
    short* __restrict__ q16, short* __restrict__ k16,
    short* __restrict__ vt16) {
  constexpr int K = 768;
  __shared__ __align__(16) short Asl[128 * 32];
  __shared__ __align__(16) short Bsl[128 * 32];
  const int n0 = blockIdx.x * 128, m0 = blockIdx.y * 128;
  const int lane = threadIdx.x & 63;
  const int w = threadIdx.x >> 6, wm = w >> 1, wn = w & 1;
  const int lm = lane & 15, quad = lane >> 4;

  floatx4 acc[4][4];
#pragma unroll
  for (int i = 0; i < 4; i++)
#pragma unroll
    for (int jj = 0; jj < 4; jj++) acc[i][jj] = (floatx4)0.f;

  for (int k0 = 0; k0 < K; k0 += 32) {
    __syncthreads();
#pragma unroll
    for (int half = 0; half < 2; half++) {
      int s = half * 256 + threadIdx.x;
      int m = s >> 2, ks = (s & 3) * 8;
      async_copy16(&A[(size_t)(m0 + m) * K + k0 + ks], &Asl[s * 8]);
      async_copy16(&Bt[(size_t)(n0 + m) * K + k0 + ks], &Bsl[s * 8]);
    }
    __syncthreads();

    short8 a[4], b[4];
#pragma unroll
    for (int i = 0; i < 4; i++)
      a[i] = *(const short8*)&Asl[(wm * 64 + i * 16 + lm) * 32 + quad * 8];
#pragma unroll
    for (int jj = 0; jj < 4; jj++)
      b[jj] = *(const short8*)&Bsl[(wn * 64 + jj * 16 + lm) * 32 + quad * 8];
#pragma unroll
    for (int i = 0; i < 4; i++)
#pragma unroll
      for (int jj = 0; jj < 4; jj++)
        acc[i][jj] = __builtin_amdgcn_mfma_f32_16x16x32_bf16(a[i], b[jj],
                                                             acc[i][jj],
                                                             0, 0, 0);
  }

  const int which = blockIdx.x / 6;  // 0:q 1:k 2:v
  const int rbase = quad * 4;
#pragma unroll
  for (int i = 0; i < 4; i++)
#pragma unroll
    for (int jj = 0; jj < 4; jj++) {
      int mrow = m0 + wm * 64 + i * 16 + rbase;
      int nl = n0 - which * Hh + wn * 64 + jj * 16 + lm;
      if (which == 0) {
#pragma unroll
        for (int r = 0; r < 4; r++)
          q16[(size_t)(mrow + r) * Hh + nl] = bf16s(acc[i][jj][r]);
      } else if (which == 1) {
#pragma unroll
        for (int r = 0; r < 4; r++)
          k16[(size_t)(mrow + r) * Hh + nl] = bf16s(acc[i][jj][r]);
      } else {
        int bL = mrow >> 10, t = mrow & 1023;
        int g = nl / Dd, d = nl % Dd;
        short4 sv;
        sv.x = bf16s(acc[i][jj][0]); sv.y = bf16s(acc[i][jj][1]);
        sv.z = bf16s(acc[i][jj][2]); sv.w = bf16s(acc[i][jj][3]);
        *(short4*)&vt16[(((size_t)bL * Gg + g) * Dd + d) * Tt + t] = sv;
      }
    }
}

// 3b) Proj GEMM: fp32 out [M,768]
__global__ __launch_bounds__(256) void gemm_proj(
    const short* __restrict__ A, const short* __restrict__ Bt,
    float* __restrict__ C) {
  constexpr int K = 768, N = 768;
  __shared__ __align__(16) short Asl[128 * 32];
  __shared__ __align__(16) short Bsl[128 * 32];
  const int n0 = blockIdx.x * 128, m0 = blockIdx.y * 128;
  const int lane = threadIdx.x & 63;
  const int w = threadIdx.x >> 6, wm = w >> 1, wn = w & 1;
  const int lm = lane & 15, quad = lane >> 4;

  floatx4 acc[4][4];
#pragma unroll
  for (int i = 0; i < 4; i++)
#pragma unroll
    for (int jj = 0; jj < 4; jj++) acc[i][jj] = (floatx4)0.f;

  for (int k0 = 0; k0 < K; k0 += 32) {
    __syncthreads();
#pragma unroll
    for (int half = 0; half < 2; half++) {
      int s = half * 256 + threadIdx.x;
      int m = s >> 2, ks = (s & 3) * 8;
      async_copy16(&A[(size_t)(m0 + m) * K + k0 + ks], &Asl[s * 8]);
      async_copy16(&Bt[(size_t)(n0 + m) * K + k0 + ks], &Bsl[s * 8]);
    }
    __syncthreads();

    short8 a[4], b[4];
#pragma unroll
    for (int i = 0; i < 4; i++)
      a[i] = *(const short8*)&Asl[(wm * 64 + i * 16 + lm) * 32 + quad * 8];
#pragma unroll
    for (int jj = 0; jj < 4; jj++)
      b[jj] = *(const short8*)&Bsl[(wn * 64 + jj * 16 + lm) * 32 + quad * 8];
#pragma unroll
    for (int i = 0; i < 4; i++)
#pragma unroll
      for (int jj = 0; jj < 4; jj++)
        acc[i][jj] = __builtin_amdgcn_mfma_f32_16x16x32_bf16(a[i], b[jj],
                                                             acc[i][jj],
                                                             0, 0, 0);
  }

  const int rbase = quad * 4;
#pragma unroll
  for (int i = 0; i < 4; i++)
#pragma unroll
    for (int jj = 0; jj < 4; jj++) {
      int mrow = m0 + wm * 64 + i * 16 + rbase;
      int ncol = n0 + wn * 64 + jj * 16 + lm;
#pragma unroll
      for (int r = 0; r < 4; r++)
        C[(size_t)(mrow + r) * N + ncol] = acc[i][jj][r];
    }
}

// ---------------------------------------------------------------------------
// 4) MFMA flash attention (unchanged from round 4)
// ---------------------------------------------------------------------------
__global__ __launch_bounds__(256, 2) void attn_mfma(
    const short* __restrict__ q16, const short* __restrict__ k16,
    const short* __restrict__ vt16, short* __restrict__ o16) {
  const float scale = 0.0721687836f;  // 192^-0.5
  const int q0 = blockIdx.x * 128;
  const int g = blockIdx.y;
  const int b = blockIdx.z;
  const int tid = threadIdx.x;
  const int w = tid >> 6, lane = tid & 63, lm = lane & 15, quad = lane >> 4;

  __shared__ __align__(16) short Ks[32 * 200];
  __shared__ __align__(16) short Vt[192 * 32];
  __shared__ __align__(16) short Ps[4 * 32 * 32];
  short* Pw = &Ps[w * 1024];

  short8 qf[2][6];
#pragma unroll
  for (int mt = 0; mt < 2; mt++)
#pragma unroll
    for (int ks = 0; ks < 6; ks++) {
      int tok = b * Tt + q0 + w * 32 + mt * 16 + lm;
      qf[mt][ks] = *(const short8*)&q16[(size_t)tok * Hh + g * Dd + ks * 32 +
                                        quad * 8];
    }

  floatx4 Oa[2][12];
#pragma unroll
  for (int mt = 0; mt < 2; mt++)
#pragma unroll
    for (int n = 0; n < 12; n++) Oa[mt][n] = (floatx4)0.f;
  float mr[2][4], lr[2][4];
#pragma unroll
  for (int mt = 0; mt < 2; mt++)
#pragma unroll
    for (int r = 0; r < 4; r++) { mr[mt][r] = -1e30f; lr[mt][r] = 0.f; }

  for (int kt = 0; kt < Tt; kt += 32) {
    __syncthreads();
#pragma unroll
    for (int it = 0; it < 3; it++) {
      int s = it * 256 + tid;
      int row = s / 24, cs = s - row * 24;
      short8 kv = *(const short8*)&k16[(size_t)(b * Tt + kt + row) * Hh +
                                       g * Dd + cs * 8];
      *(short8*)&Ks[row * 200 + cs * 8] = kv;
    }
#pragma unroll
    for (int it = 0; it < 3; it++) {
      int s = it * 256 + tid;
      int d = s >> 2, cs = s & 3;
      async_copy16(&vt16[(((size_t)b * Gg + g) * Dd + d) * Tt + kt + cs * 8],
                   &Vt[s * 8]);
    }
    __syncthreads();

    floatx4 sa[2][2];
#pragma unroll
    for (int mt = 0; mt < 2; mt++)
#pragma unroll
      for (int jj = 0; jj < 2; jj++) sa[mt][jj] = (floatx4)0.f;
#pragma unroll
    for (int ks = 0; ks < 6; ks++) {
      short8 k0 = *(const short8*)&Ks[lm * 200 + ks * 32 + quad * 8];
      short8 k1 = *(const short8*)&Ks[(16 + lm) * 200 + ks * 32 + quad * 8];
      sa[0][0] = __builtin_amdgcn_mfma_f32_16x16x32_bf16(qf[0][ks], k0, sa[0][0], 0, 0, 0);
      sa[0][1] = __builtin_amdgcn_mfma_f32_16x16x32_bf16(qf[0][ks], k1, sa[0][1], 0, 0, 0);
      sa[1][0] = __builtin_amdgcn_mfma_f32_16x16x32_bf16(qf[1][ks], k0, sa[1][0], 0, 0, 0);
      sa[1][1] = __builtin_amdgcn_mfma_f32_16x16x32_bf16(qf[1][ks], k1, sa[1][1], 0, 0, 0);
    }

#pragma unroll
    for (int mt = 0; mt < 2; mt++) {
#pragma unroll
      for (int r = 0; r < 4; r++) {
        float s0 = sa[mt][0][r] * scale, s1 = sa[mt][1][r] * scale;
        float mx = fmaxf(s0, s1);
        mx = fmaxf(mx, __shfl_xor(mx, 1));
        mx = fmaxf(mx, __shfl_xor(mx, 2));
        mx = fmaxf(mx, __shfl_xor(mx, 4));
        mx = fmaxf(mx, __shfl_xor(mx, 8));
        float mnew = fmaxf(mr[mt][r], mx);
        float alpha = __expf(mr[mt][r] - mnew);
        float p0 = __expf(s0 - mnew), p1 = __expf(s1 - mnew);
        float sum = p0 + p1;
        sum += __shfl_xor(sum, 1);
        sum += __shfl_xor(sum, 2);
        sum += __shfl_xor(sum, 4);
        sum += __shfl_xor(sum, 8);
        lr[mt][r] = lr[mt][r] * alpha + sum;
        mr[mt][r] = mnew;
        Pw[(mt * 16 + quad * 4 + r) * 32 + lm] = bf16s(p0);
        Pw[(mt * 16 + quad * 4 + r) * 32 + 16 + lm] = bf16s(p1);
#pragma unroll
        for (int n = 0; n < 12; n++) Oa[mt][n][r] *= alpha;
      }
    }

    short8 pf0 = *(const short8*)&Pw[lm * 32 + quad * 8];
    short8 pf1 = *(const short8*)&Pw[(16 + lm) * 32 + quad * 8];
#pragma unroll
    for (int n = 0; n < 12; n++) {
      short8 vf = *(const short8*)&Vt[(n * 16 + lm) * 32 + quad * 8];
      Oa[0][n] = __builtin_amdgcn_mfma_f32_16x16x32_bf16(pf0, vf, Oa[0][n], 0, 0, 0);
      Oa[1][n] = __builtin_amdgcn_mfma_f32_16x16x32_bf16(pf1, vf, Oa[1][n], 0, 0, 0);
    }
  }

#pragma unroll
  for (int mt = 0; mt < 2; mt++)
#pragma unroll
    for (int r = 0; r < 4; r++) {
      float inv = 1.f / lr[mt][r];
      int tok = b * Tt + q0 + w * 32 + mt * 16 + quad * 4 + r;
#pragma unroll
      for (int n = 0; n < 12; n++)
        o16[(size_t)tok * Hh + g * Dd + n * 16 + lm] = bf16s(Oa[mt][n][r] * inv);
    }
}

// ---------------------------------------------------------------------------
// 5) Pool (unchanged)
// ---------------------------------------------------------------------------
__global__ __launch_bounds__(256) void pool_kernel(const float* __restrict__ h,
                                                   float* __restrict__ pool) {
  int idx = blockIdx.x * 256 + threadIdx.x;
  int b = idx / Hh, c = idx % Hh;
  float s = 0.f, ss = 0.f;
  for (int t = 0; t < Tt; t++) {
    float v = h[((size_t)b * Tt + t) * Hh + c];
    s += v; ss += v * v;
  }
  float mu = s * (1.f / Tt);
  float var = ss * (1.f / Tt) - mu * mu;
  pool[(size_t)b * 1536 + c] = mu;
  pool[(size_t)b * 1536 + 768 + c] = sqrtf(fmaxf(var, 0.f));
}

// ---------------------------------------------------------------------------
// 6) Final projection (unchanged)
// ---------------------------------------------------------------------------
__global__ __launch_bounds__(256) void final_kernel(
    const float* __restrict__ pool, const float* __restrict__ pw,
    const float* __restrict__ pb, const float* __restrict__ g,
    const float* __restrict__ bt, float* __restrict__ out) {
  __shared__ float ms[1536];
  __shared__ float red[8];
  const int b = blockIdx.x;
  for (int e = threadIdx.x; e < 1536; e += 256) ms[e] = pool[(size_t)b * 1536 + e];
  __syncthreads();
  const int n0 = threadIdx.x, n1 = threadIdx.x + 256, n2 = threadIdx.x + 512;
  float a0 = pb[n0], a1 = pb[n1], a2 = pb[n2];
  for (int k = 0; k < 1536; k++) {
    float m = ms[k];
    const float* row = &pw[(size_t)k * Hh];
    a0 = fmaf(m, row[n0], a0);
    a1 = fmaf(m, row[n1], a1);
    a2 = fmaf(m, row[n2], a2);
  }
  float s = a0 + a1 + a2, ss = a0 * a0 + a1 * a1 + a2 * a2;
  float2 r = block_reduce2(s, ss, red);
  float mu = r.x * (1.f / Hh);
  float var = r.y * (1.f / Hh) - mu * mu;
  float rs = rsqrtf(var + EPS);
  float o0 = (a0 - mu) * rs * g[n0] + bt[n0];
  float o1 = (a1 - mu) * rs * g[n1] + bt[n1];
  float o2 = (a2 - mu) * rs * g[n2] + bt[n2];
  out[(size_t)b * Hh + n0] = o0 > 0.f ? o0 : 0.f;
  out[(size_t)b * Hh + n1] = o1 > 0.f ? o1 : 0.f;
  out[(size_t)b * Hh + n2] = o2 > 0.f ? o2 : 0.f;
}

// ---------------------------------------------------------------------------
extern "C" void kernel_launch(void* const* d_in, const int* in_sizes, int n_in,
                              void* d_out, int out_size, void* d_ws,
                              size_t ws_size, hipStream_t stream) {
  (void)in_sizes; (void)n_in; (void)out_size;
  const float* x = (const float*)d_in[0];
  const float* cw[3][4];
  for (int j = 0; j < 3; j++)
    for (int p2 = 0; p2 < 4; p2++) cw[j][p2] = (const float*)d_in[1 + j * 4 + p2];
  const float* conv_ln_g = (const float*)d_in[13];
  const float* conv_ln_b = (const float*)d_in[14];
  const float* wq = (const float*)d_in[15];
  const float* wk = (const float*)d_in[16];
  const float* wv = (const float*)d_in[17];
  const float* wp = (const float*)d_in[18];
  const float* bp = (const float*)d_in[19];
  const float* lng = (const float*)d_in[20];
  const float* lnb = (const float*)d_in[21];
  const float* proj_w = (const float*)d_in[22];
  const float* proj_b = (const float*)d_in[23];
  const float* proj_ln_g = (const float*)d_in[24];
  const float* proj_ln_b = (const float*)d_in[25];
  float* out = (float*)d_out;

  // --- workspace ----------------------------------------------------------
  // per-token chunk buffers (12288 B/token): h fp32 | y(fp32)/yraw(bf16)
  // union | h16 | q16 | k16 | vt16.  fixed: wt 9.44MB + wcv 1.38MB +
  // x16 4.19MB + pool 196KB.
  const size_t perb = (size_t)Tt * Hh;
  const size_t fixedB = 8ull * Hh * Hh * 2 + 3ull * 512 * WKMAX * 2 +
                        (size_t)Bb * Tt * Ff * 2 + (size_t)Bb * 2 * Hh * 4;
  int chunk = Bb;
  while (chunk > 1 && 16ull * perb * chunk + fixedB > ws_size) chunk >>= 1;

  const size_t crow = perb * (size_t)chunk;
  char* p = (char*)d_ws;
  float* h = (float*)p;              p += crow * 4;
  float* y = (float*)p;              // union with yraw16
  short* yraw16 = (short*)y;         p += crow * 4;
  __hip_bfloat16* h16 = (__hip_bfloat16*)p;  p += crow * 2;
  short* q16 = (short*)p;            p += crow * 2;
  short* k16 = (short*)p;            p += crow * 2;
  short* v16t = (short*)p;           p += crow * 2;
  __hip_bfloat16* wt = (__hip_bfloat16*)p;   p += 8ull * Hh * Hh * 2;
  __hip_bfloat16* wcv = (__hip_bfloat16*)p;  p += 3ull * 512 * WKMAX * 2;
  short* x16 = (short*)p;            p += (size_t)Bb * Tt * Ff * 2;
  float* pool = (float*)p;

  // one-time casts
  wt_cast_kernel<<<dim3(24, 24, 8), 256, 0, stream>>>(wq, wk, wv, wp, wt);
  wcv_cast_kernel<<<(3 * 512 * WKMAX + 255) / 256, 256, 0, stream>>>(
      cw[0][0], cw[0][2], cw[1][0], cw[1][2], cw[2][0], cw[2][2], wcv);
  x_cast_kernel<<<(Bb * Tt * Ff / 8 + 255) / 256, 256, 0, stream>>>(
      x, x16, Bb * Tt * Ff / 8);

  const short* wts = (const short*)wt;

  for (int b0 = 0; b0 < Bb; b0 += chunk) {
    const int M = chunk * Tt;

    conv_gemm_kernel<<<dim3(Tt / 128, 4, chunk * 3), 256, 0, stream>>>(
        x16, (const short*)wcv, yraw16, b0);
    gate_ln_kernel<<<M, 256, 0, stream>>>(
        yraw16, h, h16, cw[0][1], cw[0][3], cw[1][1], cw[1][3], cw[2][1],
        cw[2][3], conv_ln_g, conv_ln_b);

    for (int i = 0; i < 2; i++) {
      const short* wqkv = wts + (size_t)(i * 4) * Hh * Hh;      // q,k,v rows
      const short* wtp = wts + (size_t)(i * 4 + 3) * Hh * Hh;   // p rows
      gemm_qkv<<<dim3(18, M / 128), 256, 0, stream>>>((const short*)h16, wqkv,
                                                      q16, k16, v16t);
      attn_mfma<<<dim3(Tt / 128, Gg, chunk), 256, 0, stream>>>(q16, k16, v16t,
                                                               q16);
      gemm_proj<<<dim3(6, M / 128), 256, 0, stream>>>(q16, wtp, y);
      res_ln_kernel<<<M, 256, 0, stream>>>(h, h16, y, bp + (size_t)i * Hh,
                                           lng + (size_t)i * Hh,
                                           lnb + (size_t)i * Hh);
    }

    pool_kernel<<<(chunk * Hh) / 256, 256, 0, stream>>>(
        h, pool + (size_t)b0 * 2 * Hh);
  }

  final_kernel<<<Bb, 256, 0, stream>>>(pool, proj_w, proj_b, proj_ln_g,
                                       proj_ln_b, out);
}

// Round 6
// 1600.944 us; speedup vs baseline: 6.9957x; 1.0672x over previous
//
#include <hip/hip_runtime.h>
#include <hip/hip_bf16.h>

// ---------------------------------------------------------------------------
// TemporalExtractor round 6:
//   - attn: Vt/Ps LDS strides 32->40 shorts (kill 8-way bank conflicts on the
//     PV fragment reads; 20 dwords/row => <=2-way). Vt staged via VGPR
//     (padding breaks global_load_lds lane contiguity). 1/sqrt(D) folded
//     into Q weights at wt_cast time.
//   - pool: two-stage (8 T-segments partials -> combine) for occupancy.
//   - conv implicit-GEMM / fused QKV / proj / LN / final unchanged.
// ---------------------------------------------------------------------------

constexpr int Bb = 32, Tt = 1024, Ff = 64, Hh = 768, Gg = 4, Dd = 192;
constexpr float EPS = 1e-5f;
constexpr int WKMAX = 448;  // padded conv-weight K stride (7*64)
constexpr int VTS = 40;     // Vt/Ps LDS row stride in shorts (80B = 20 dwords)

typedef __attribute__((ext_vector_type(8))) short short8;   // 8 bf16 = 4 VGPRs
typedef __attribute__((ext_vector_type(4))) float floatx4;  // MFMA acc

__device__ __forceinline__ void async_copy16(const void* g, void* l) {
  __builtin_amdgcn_global_load_lds(
      (const __attribute__((address_space(1))) unsigned int*)g,
      (__attribute__((address_space(3))) unsigned int*)l, 16, 0, 0);
}

__device__ __forceinline__ short bf16s(float f) {
  __hip_bfloat16 h = __float2bfloat16(f);
  return *(short*)&h;
}

__device__ __forceinline__ float2 block_reduce2(float a, float b, float* tmp) {
  int lane = threadIdx.x & 63, wid = threadIdx.x >> 6;
#pragma unroll
  for (int off = 32; off > 0; off >>= 1) {
    a += __shfl_down(a, off);
    b += __shfl_down(b, off);
  }
  if (lane == 0) { tmp[wid] = a; tmp[4 + wid] = b; }
  __syncthreads();
  if (threadIdx.x == 0) {
    tmp[0] = tmp[0] + tmp[1] + tmp[2] + tmp[3];
    tmp[4] = tmp[4] + tmp[5] + tmp[6] + tmp[7];
  }
  __syncthreads();
  float2 r; r.x = tmp[0]; r.y = tmp[4];
  return r;
}

// ---------------------------------------------------------------------------
// 0a) Attn/proj weight transpose+cast: fp32 [K][N] -> bf16 [z][N][K],
//     z = i*4 + {0:q,1:k,2:v,3:p}. Q weights pre-scaled by 192^-0.5.
// ---------------------------------------------------------------------------
__global__ __launch_bounds__(256) void wt_cast_kernel(
    const float* __restrict__ wq, const float* __restrict__ wk,
    const float* __restrict__ wv, const float* __restrict__ wp,
    __hip_bfloat16* __restrict__ wt) {
  const int z = blockIdx.z;
  const int m = z & 3, i = z >> 2;
  const float* src =
      (m == 0 ? wq : m == 1 ? wk : m == 2 ? wv : wp) + (size_t)i * Hh * Hh;
  const float sc = (m == 0) ? 0.0721687836f : 1.f;  // fold 1/sqrt(D) into Q
  __shared__ float tile[32][33];
  const int n0 = blockIdx.x * 32, k0 = blockIdx.y * 32;
  const int tx = threadIdx.x & 31, ty = threadIdx.x >> 5;
#pragma unroll
  for (int r = 0; r < 4; r++)
    tile[ty + 8 * r][tx] = src[(size_t)(k0 + ty + 8 * r) * Hh + n0 + tx];
  __syncthreads();
#pragma unroll
  for (int r = 0; r < 4; r++)
    wt[((size_t)z * Hh + n0 + ty + 8 * r) * Hh + k0 + tx] =
        __float2bfloat16(tile[tx][ty + 8 * r] * sc);
}

// ---------------------------------------------------------------------------
// 0b) Conv weight cast: [Kw][64][256] fp32 (wf,wg) -> wcv bf16 [j][512][448]
// ---------------------------------------------------------------------------
__global__ __launch_bounds__(256) void wcv_cast_kernel(
    const float* __restrict__ wf3, const float* __restrict__ wg3,
    const float* __restrict__ wf5, const float* __restrict__ wg5,
    const float* __restrict__ wf7, const float* __restrict__ wg7,
    __hip_bfloat16* __restrict__ wcv) {
  int idx = blockIdx.x * 256 + threadIdx.x;
  if (idx >= 3 * 512 * WKMAX) return;
  int j = idx / (512 * WKMAX);
  int rem = idx - j * 512 * WKMAX;
  int n = rem / WKMAX, k = rem % WKMAX;
  int Kw = 3 + 2 * j;
  float v = 0.f;
  if (k < Kw * 64) {
    const float* src = (n < 256) ? (j == 0 ? wf3 : j == 1 ? wf5 : wf7)
                                 : (j == 0 ? wg3 : j == 1 ? wg5 : wg7);
    v = src[(size_t)k * 256 + (n & 255)];
  }
  wcv[idx] = __float2bfloat16(v);
}

// 0c) x cast fp32 -> bf16
__global__ __launch_bounds__(256) void x_cast_kernel(
    const float* __restrict__ x, short* __restrict__ x16, int n8) {
  int idx = blockIdx.x * 256 + threadIdx.x;
  if (idx >= n8) return;
  const float4 a = ((const float4*)x)[idx * 2];
  const float4 b = ((const float4*)x)[idx * 2 + 1];
  short8 o;
  o[0] = bf16s(a.x); o[1] = bf16s(a.y); o[2] = bf16s(a.z); o[3] = bf16s(a.w);
  o[4] = bf16s(b.x); o[5] = bf16s(b.y); o[6] = bf16s(b.z); o[7] = bf16s(b.w);
  ((short8*)x16)[idx] = o;
}

// ---------------------------------------------------------------------------
// 1) Conv as implicit GEMM (unchanged)
// ---------------------------------------------------------------------------
__global__ __launch_bounds__(256) void conv_gemm_kernel(
    const short* __restrict__ x16, const short* __restrict__ wcv,
    short* __restrict__ yraw, int b0) {
  __shared__ __align__(16) short Asl[128 * 72];
  __shared__ __align__(16) short Bsl[128 * 72];
  const int t0 = blockIdx.x * 128, n0 = blockIdx.y * 128;
  const int bl = blockIdx.z / 3, j = blockIdx.z % 3;
  const int Kw = 3 + 2 * j, pad = j + 1;
  const int bglob = b0 + bl;
  const short* wb = wcv + (size_t)j * 512 * WKMAX;
  const int tid = threadIdx.x;
  const int lane = tid & 63;
  const int w = tid >> 6, wm = w >> 1, wn = w & 1;
  const int lm = lane & 15, quad = lane >> 4;

  floatx4 acc[4][4];
#pragma unroll
  for (int i = 0; i < 4; i++)
#pragma unroll
    for (int jj = 0; jj < 4; jj++) acc[i][jj] = (floatx4)0.f;

  for (int kk = 0; kk < Kw; kk++) {
    __syncthreads();
#pragma unroll
    for (int it = 0; it < 4; it++) {
      int s = it * 256 + tid;
      int row = s >> 3, c8 = s & 7;
      int t = t0 + row + kk - pad;
      short8 av = (short8)0;
      if (t >= 0 && t < Tt)
        av = *(const short8*)&x16[((size_t)bglob * Tt + t) * Ff + c8 * 8];
      *(short8*)&Asl[row * 72 + c8 * 8] = av;
      short8 bv = *(const short8*)&wb[(size_t)(n0 + row) * WKMAX + kk * 64 +
                                      c8 * 8];
      *(short8*)&Bsl[row * 72 + c8 * 8] = bv;
    }
    __syncthreads();
#pragma unroll
    for (int ks = 0; ks < 2; ks++) {
      short8 a[4], b[4];
#pragma unroll
      for (int i = 0; i < 4; i++)
        a[i] = *(const short8*)&Asl[(wm * 64 + i * 16 + lm) * 72 + ks * 32 +
                                    quad * 8];
#pragma unroll
      for (int jj = 0; jj < 4; jj++)
        b[jj] = *(const short8*)&Bsl[(wn * 64 + jj * 16 + lm) * 72 + ks * 32 +
                                     quad * 8];
#pragma unroll
      for (int i = 0; i < 4; i++)
#pragma unroll
        for (int jj = 0; jj < 4; jj++)
          acc[i][jj] = __builtin_amdgcn_mfma_f32_16x16x32_bf16(a[i], b[jj],
                                                               acc[i][jj],
                                                               0, 0, 0);
    }
  }

  const int rbase = quad * 4;
#pragma unroll
  for (int i = 0; i < 4; i++)
#pragma unroll
    for (int jj = 0; jj < 4; jj++) {
      int mrow = t0 + wm * 64 + i * 16 + rbase;
      int ncol = n0 + wn * 64 + jj * 16 + lm;
#pragma unroll
      for (int r = 0; r < 4; r++)
        yraw[((size_t)bl * Tt + mrow + r) * 1536 + j * 512 + ncol] =
            bf16s(acc[i][jj][r]);
    }
}

// ---------------------------------------------------------------------------
// 2) Fused gate + LayerNorm (unchanged)
// ---------------------------------------------------------------------------
__global__ __launch_bounds__(256) void gate_ln_kernel(
    const short* __restrict__ yraw, float* __restrict__ h,
    __hip_bfloat16* __restrict__ h16, const float* __restrict__ bf3,
    const float* __restrict__ bg3, const float* __restrict__ bf5,
    const float* __restrict__ bg5, const float* __restrict__ bf7,
    const float* __restrict__ bg7, const float* __restrict__ g,
    const float* __restrict__ bt) {
  __shared__ float red[8];
  const size_t row = blockIdx.x;
  float v[3], s = 0.f, ss = 0.f;
#pragma unroll
  for (int jj = 0; jj < 3; jj++) {
    int c = threadIdx.x + jj * 256;
    int br = c >> 8, cc = c & 255;
    const float* bfp = br == 0 ? bf3 : br == 1 ? bf5 : bf7;
    const float* bgp = br == 0 ? bg3 : br == 1 ? bg5 : bg7;
    __hip_bfloat16 rf = *(const __hip_bfloat16*)&yraw[row * 1536 + br * 512 + cc];
    __hip_bfloat16 rg =
        *(const __hip_bfloat16*)&yraw[row * 1536 + br * 512 + 256 + cc];
    float f = __bfloat162float(rf) + bfp[cc];
    float gt = __bfloat162float(rg) + bgp[cc];
    float a = f > 0.f ? f : 0.f;
    float t = a * (1.f / (1.f + __expf(-gt)));
    v[jj] = t; s += t; ss += t * t;
  }
  float2 r = block_reduce2(s, ss, red);
  float mu = r.x * (1.f / Hh);
  float var = r.y * (1.f / Hh) - mu * mu;
  float rs = rsqrtf(var + EPS);
#pragma unroll
  for (int jj = 0; jj < 3; jj++) {
    int c = threadIdx.x + jj * 256;
    float o = (v[jj] - mu) * rs * g[c] + bt[c];
    h[row * Hh + c] = o;
    h16[row * Hh + c] = __float2bfloat16(o);
  }
}

// residual LN: h = LN(h + y + bp), emit fp32 + bf16
__global__ __launch_bounds__(256) void res_ln_kernel(
    float* __restrict__ h, __hip_bfloat16* __restrict__ h16,
    const float* __restrict__ y, const float* __restrict__ bp,
    const float* __restrict__ g, const float* __restrict__ bt) {
  __shared__ float red[8];
  const size_t row = blockIdx.x;
  float v[3], s = 0.f, ss = 0.f;
#pragma unroll
  for (int jj = 0; jj < 3; jj++) {
    int c = threadIdx.x + jj * 256;
    float t = h[row * Hh + c] + y[row * Hh + c] + bp[c];
    v[jj] = t; s += t; ss += t * t;
  }
  float2 r = block_reduce2(s, ss, red);
  float mu = r.x * (1.f / Hh);
  float var = r.y * (1.f / Hh) - mu * mu;
  float rs = rsqrtf(var + EPS);
#pragma unroll
  for (int jj = 0; jj < 3; jj++) {
    int c = threadIdx.x + jj * 256;
    float o = (v[jj] - mu) * rs * g[c] + bt[c];
    h[row * Hh + c] = o;
    h16[row * Hh + c] = __float2bfloat16(o);
  }
}

// ---------------------------------------------------------------------------
// 3a) Fused QKV GEMM (unchanged)
// ---------------------------------------------------------------------------
__global__ __launch_bounds__(256) void gemm_qkv(
    const short* __restrict__ A, const short* __restrict__ Bt,
    short* __restrict__ q16, short* __restrict__ k16,
    short* __restrict__ vt16) {
  constexpr int K = 768;
  __shared__ __align__(16) short Asl[128 * 32];
  __shared__ __align__(16) short Bsl[128 * 32];
  const int n0 = blockIdx.x * 128, m0 = blockIdx.y * 128;
  const int lane = threadIdx.x & 63;
  const int w = threadIdx.x >> 6, wm = w >> 1, wn = w & 1;
  const int lm = lane & 15, quad = lane >> 4;

  floatx4 acc[4][4];
#pragma unroll
  for (int i = 0; i < 4; i++)
#pragma unroll
    for (int jj = 0; jj < 4; jj++) acc[i][jj] = (floatx4)0.f;

  for (int k0 = 0; k0 < K; k0 += 32) {
    __syncthreads();
#pragma unroll
    for (int half = 0; half < 2; half++) {
      int s = half * 256 + threadIdx.x;
      int m = s >> 2, ks = (s & 3) * 8;
      async_copy16(&A[(size_t)(m0 + m) * K + k0 + ks], &Asl[s * 8]);
      async_copy16(&Bt[(size_t)(n0 + m) * K + k0 + ks], &Bsl[s * 8]);
    }
    __syncthreads();

    short8 a[4], b[4];
#pragma unroll
    for (int i = 0; i < 4; i++)
      a[i] = *(const short8*)&Asl[(wm * 64 + i * 16 + lm) * 32 + quad * 8];
#pragma unroll
    for (int jj = 0; jj < 4; jj++)
      b[jj] = *(const short8*)&Bsl[(wn * 64 + jj * 16 + lm) * 32 + quad * 8];
#pragma unroll
    for (int i = 0; i < 4; i++)
#pragma unroll
      for (int jj = 0; jj < 4; jj++)
        acc[i][jj] = __builtin_amdgcn_mfma_f32_16x16x32_bf16(a[i], b[jj],
                                                             acc[i][jj],
                                                             0, 0, 0);
  }

  const int which = blockIdx.x / 6;  // 0:q 1:k 2:v
  const int rbase = quad * 4;
#pragma unroll
  for (int i = 0; i < 4; i++)
#pragma unroll
    for (int jj = 0; jj < 4; jj++) {
      int mrow = m0 + wm * 64 + i * 16 + rbase;
      int nl = n0 - which * Hh + wn * 64 + jj * 16 + lm;
      if (which == 0) {
#pragma unroll
        for (int r = 0; r < 4; r++)
          q16[(size_t)(mrow + r) * Hh + nl] = bf16s(acc[i][jj][r]);
      } else if (which == 1) {
#pragma unroll
        for (int r = 0; r < 4; r++)
          k16[(size_t)(mrow + r) * Hh + nl] = bf16s(acc[i][jj][r]);
      } else {
        int bL = mrow >> 10, t = mrow & 1023;
        int g = nl / Dd, d = nl % Dd;
        short4 sv;
        sv.x = bf16s(acc[i][jj][0]); sv.y = bf16s(acc[i][jj][1]);
        sv.z = bf16s(acc[i][jj][2]); sv.w = bf16s(acc[i][jj][3]);
        *(short4*)&vt16[(((size_t)bL * Gg + g) * Dd + d) * Tt + t] = sv;
      }
    }
}

// 3b) Proj GEMM: fp32 out (unchanged)
__global__ __launch_bounds__(256) void gemm_proj(
    const short* __restrict__ A, const short* __restrict__ Bt,
    float* __restrict__ C) {
  constexpr int K = 768, N = 768;
  __shared__ __align__(16) short Asl[128 * 32];
  __shared__ __align__(16) short Bsl[128 * 32];
  const int n0 = blockIdx.x * 128, m0 = blockIdx.y * 128;
  const int lane = threadIdx.x & 63;
  const int w = threadIdx.x >> 6, wm = w >> 1, wn = w & 1;
  const int lm = lane & 15, quad = lane >> 4;

  floatx4 acc[4][4];
#pragma unroll
  for (int i = 0; i < 4; i++)
#pragma unroll
    for (int jj = 0; jj < 4; jj++) acc[i][jj] = (floatx4)0.f;

  for (int k0 = 0; k0 < K; k0 += 32) {
    __syncthreads();
#pragma unroll
    for (int half = 0; half < 2; half++) {
      int s = half * 256 + threadIdx.x;
      int m = s >> 2, ks = (s & 3) * 8;
      async_copy16(&A[(size_t)(m0 + m) * K + k0 + ks], &Asl[s * 8]);
      async_copy16(&Bt[(size_t)(n0 + m) * K + k0 + ks], &Bsl[s * 8]);
    }
    __syncthreads();

    short8 a[4], b[4];
#pragma unroll
    for (int i = 0; i < 4; i++)
      a[i] = *(const short8*)&Asl[(wm * 64 + i * 16 + lm) * 32 + quad * 8];
#pragma unroll
    for (int jj = 0; jj < 4; jj++)
      b[jj] = *(const short8*)&Bsl[(wn * 64 + jj * 16 + lm) * 32 + quad * 8];
#pragma unroll
    for (int i = 0; i < 4; i++)
#pragma unroll
      for (int jj = 0; jj < 4; jj++)
        acc[i][jj] = __builtin_amdgcn_mfma_f32_16x16x32_bf16(a[i], b[jj],
                                                             acc[i][jj],
                                                             0, 0, 0);
  }

  const int rbase = quad * 4;
#pragma unroll
  for (int i = 0; i < 4; i++)
#pragma unroll
    for (int jj = 0; jj < 4; jj++) {
      int mrow = m0 + wm * 64 + i * 16 + rbase;
      int ncol = n0 + wn * 64 + jj * 16 + lm;
#pragma unroll
      for (int r = 0; r < 4; r++)
        C[(size_t)(mrow + r) * N + ncol] = acc[i][jj][r];
    }
}

// ---------------------------------------------------------------------------
// 4) MFMA flash attention. Vt/Ps stride VTS=40 shorts (bank-conflict fix),
//    Vt staged via VGPR. Q pre-scaled (weights), so raw scores used.
// ---------------------------------------------------------------------------
__global__ __launch_bounds__(256, 2) void attn_mfma(
    const short* __restrict__ q16, const short* __restrict__ k16,
    const short* __restrict__ vt16, short* __restrict__ o16) {
  const int q0 = blockIdx.x * 128;
  const int g = blockIdx.y;
  const int b = blockIdx.z;
  const int tid = threadIdx.x;
  const int w = tid >> 6, lane = tid & 63, lm = lane & 15, quad = lane >> 4;

  __shared__ __align__(16) short Ks[32 * 200];      // 2-way max (100 dwords)
  __shared__ __align__(16) short Vt[192 * VTS];     // 20 dwords -> <=2-way
  __shared__ __align__(16) short Ps[4 * 32 * VTS];
  short* Pw = &Ps[w * 32 * VTS];

  short8 qf[2][6];
#pragma unroll
  for (int mt = 0; mt < 2; mt++)
#pragma unroll
    for (int ks = 0; ks < 6; ks++) {
      int tok = b * Tt + q0 + w * 32 + mt * 16 + lm;
      qf[mt][ks] = *(const short8*)&q16[(size_t)tok * Hh + g * Dd + ks * 32 +
                                        quad * 8];
    }

  floatx4 Oa[2][12];
#pragma unroll
  for (int mt = 0; mt < 2; mt++)
#pragma unroll
    for (int n = 0; n < 12; n++) Oa[mt][n] = (floatx4)0.f;
  float mr[2][4], lr[2][4];
#pragma unroll
  for (int mt = 0; mt < 2; mt++)
#pragma unroll
    for (int r = 0; r < 4; r++) { mr[mt][r] = -1e30f; lr[mt][r] = 0.f; }

  for (int kt = 0; kt < Tt; kt += 32) {
    __syncthreads();
#pragma unroll
    for (int it = 0; it < 3; it++) {
      int s = it * 256 + tid;
      int row = s / 24, cs = s - row * 24;
      short8 kv = *(const short8*)&k16[(size_t)(b * Tt + kt + row) * Hh +
                                       g * Dd + cs * 8];
      *(short8*)&Ks[row * 200 + cs * 8] = kv;
    }
#pragma unroll
    for (int it = 0; it < 3; it++) {
      int s = it * 256 + tid;
      int d = s >> 2, cs = s & 3;
      short8 vv = *(const short8*)&vt16[(((size_t)b * Gg + g) * Dd + d) * Tt +
                                        kt + cs * 8];
      *(short8*)&Vt[d * VTS + cs * 8] = vv;
    }
    __syncthreads();

    floatx4 sa[2][2];
#pragma unroll
    for (int mt = 0; mt < 2; mt++)
#pragma unroll
      for (int jj = 0; jj < 2; jj++) sa[mt][jj] = (floatx4)0.f;
#pragma unroll
    for (int ks = 0; ks < 6; ks++) {
      short8 k0 = *(const short8*)&Ks[lm * 200 + ks * 32 + quad * 8];
      short8 k1 = *(const short8*)&Ks[(16 + lm) * 200 + ks * 32 + quad * 8];
      sa[0][0] = __builtin_amdgcn_mfma_f32_16x16x32_bf16(qf[0][ks], k0, sa[0][0], 0, 0, 0);
      sa[0][1] = __builtin_amdgcn_mfma_f32_16x16x32_bf16(qf[0][ks], k1, sa[0][1], 0, 0, 0);
      sa[1][0] = __builtin_amdgcn_mfma_f32_16x16x32_bf16(qf[1][ks], k0, sa[1][0], 0, 0, 0);
      sa[1][1] = __builtin_amdgcn_mfma_f32_16x16x32_bf16(qf[1][ks], k1, sa[1][1], 0, 0, 0);
    }

#pragma unroll
    for (int mt = 0; mt < 2; mt++) {
#pragma unroll
      for (int r = 0; r < 4; r++) {
        float s0 = sa[mt][0][r], s1 = sa[mt][1][r];  // scale folded into Q
        float mx = fmaxf(s0, s1);
        mx = fmaxf(mx, __shfl_xor(mx, 1));
        mx = fmaxf(mx, __shfl_xor(mx, 2));
        mx = fmaxf(mx, __shfl_xor(mx, 4));
        mx = fmaxf(mx, __shfl_xor(mx, 8));
        float mnew = fmaxf(mr[mt][r], mx);
        float alpha = __expf(mr[mt][r] - mnew);
        float p0 = __expf(s0 - mnew), p1 = __expf(s1 - mnew);
        float sum = p0 + p1;
        sum += __shfl_xor(sum, 1);
        sum += __shfl_xor(sum, 2);
        sum += __shfl_xor(sum, 4);
        sum += __shfl_xor(sum, 8);
        lr[mt][r] = lr[mt][r] * alpha + sum;
        mr[mt][r] = mnew;
        Pw[(mt * 16 + quad * 4 + r) * VTS + lm] = bf16s(p0);
        Pw[(mt * 16 + quad * 4 + r) * VTS + 16 + lm] = bf16s(p1);
#pragma unroll
        for (int n = 0; n < 12; n++) Oa[mt][n][r] *= alpha;
      }
    }

    short8 pf0 = *(const short8*)&Pw[lm * VTS + quad * 8];
    short8 pf1 = *(const short8*)&Pw[(16 + lm) * VTS + quad * 8];
#pragma unroll
    for (int n = 0; n < 12; n++) {
      short8 vf = *(const short8*)&Vt[(n * 16 + lm) * VTS + quad * 8];
      Oa[0][n] = __builtin_amdgcn_mfma_f32_16x16x32_bf16(pf0, vf, Oa[0][n], 0, 0, 0);
      Oa[1][n] = __builtin_amdgcn_mfma_f32_16x16x32_bf16(pf1, vf, Oa[1][n], 0, 0, 0);
    }
  }

#pragma unroll
  for (int mt = 0; mt < 2; mt++)
#pragma unroll
    for (int r = 0; r < 4; r++) {
      float inv = 1.f / lr[mt][r];
      int tok = b * Tt + q0 + w * 32 + mt * 16 + quad * 4 + r;
#pragma unroll
      for (int n = 0; n < 12; n++)
        o16[(size_t)tok * Hh + g * Dd + n * 16 + lm] = bf16s(Oa[mt][n][r] * inv);
    }
}

// ---------------------------------------------------------------------------
// 5) Pool, two-stage. Stage1: 8 T-segments -> partial (sum, sumsq).
//    Stage2: combine 8 partials -> mean/std.
// ---------------------------------------------------------------------------
__global__ __launch_bounds__(256) void pool_stage1(const float* __restrict__ h,
                                                   float* __restrict__ ppart,
                                                   int b0) {
  int idx = blockIdx.x * 256 + threadIdx.x;  // chunk*768
  int seg = blockIdx.y;
  int bl = idx / Hh, c = idx % Hh;
  float s = 0.f, ss = 0.f;
  const float* hp = &h[((size_t)bl * Tt + seg * 128) * Hh + c];
  for (int t = 0; t < 128; t++) {
    float v = hp[(size_t)t * Hh];
    s += v; ss += v * v;
  }
  float* o = &ppart[(((size_t)(b0 + bl) * 8 + seg) * 2) * Hh + c];
  o[0] = s;
  o[Hh] = ss;
}

__global__ __launch_bounds__(256) void pool_stage2(
    const float* __restrict__ ppart, float* __restrict__ pool) {
  int idx = blockIdx.x * 256 + threadIdx.x;  // 32*768
  int b = idx / Hh, c = idx % Hh;
  float s = 0.f, ss = 0.f;
#pragma unroll
  for (int seg = 0; seg < 8; seg++) {
    const float* o = &ppart[(((size_t)b * 8 + seg) * 2) * Hh + c];
    s += o[0]; ss += o[Hh];
  }
  float mu = s * (1.f / Tt);
  float var = ss * (1.f / Tt) - mu * mu;
  pool[(size_t)b * 1536 + c] = mu;
  pool[(size_t)b * 1536 + 768 + c] = sqrtf(fmaxf(var, 0.f));
}

// ---------------------------------------------------------------------------
// 6) Final projection (unchanged)
// ---------------------------------------------------------------------------
__global__ __launch_bounds__(256) void final_kernel(
    const float* __restrict__ pool, const float* __restrict__ pw,
    const float* __restrict__ pb, const float* __restrict__ g,
    const float* __restrict__ bt, float* __restrict__ out) {
  __shared__ float ms[1536];
  __shared__ float red[8];
  const int b = blockIdx.x;
  for (int e = threadIdx.x; e < 1536; e += 256) ms[e] = pool[(size_t)b * 1536 + e];
  __syncthreads();
  const int n0 = threadIdx.x, n1 = threadIdx.x + 256, n2 = threadIdx.x + 512;
  float a0 = pb[n0], a1 = pb[n1], a2 = pb[n2];
  for (int k = 0; k < 1536; k++) {
    float m = ms[k];
    const float* row = &pw[(size_t)k * Hh];
    a0 = fmaf(m, row[n0], a0);
    a1 = fmaf(m, row[n1], a1);
    a2 = fmaf(m, row[n2], a2);
  }
  float s = a0 + a1 + a2, ss = a0 * a0 + a1 * a1 + a2 * a2;
  float2 r = block_reduce2(s, ss, red);
  float mu = r.x * (1.f / Hh);
  float var = r.y * (1.f / Hh) - mu * mu;
  float rs = rsqrtf(var + EPS);
  float o0 = (a0 - mu) * rs * g[n0] + bt[n0];
  float o1 = (a1 - mu) * rs * g[n1] + bt[n1];
  float o2 = (a2 - mu) * rs * g[n2] + bt[n2];
  out[(size_t)b * Hh + n0] = o0 > 0.f ? o0 : 0.f;
  out[(size_t)b * Hh + n1] = o1 > 0.f ? o1 : 0.f;
  out[(size_t)b * Hh + n2] = o2 > 0.f ? o2 : 0.f;
}

// ---------------------------------------------------------------------------
extern "C" void kernel_launch(void* const* d_in, const int* in_sizes, int n_in,
                              void* d_out, int out_size, void* d_ws,
                              size_t ws_size, hipStream_t stream) {
  (void)in_sizes; (void)n_in; (void)out_size;
  const float* x = (const float*)d_in[0];
  const float* cw[3][4];
  for (int j = 0; j < 3; j++)
    for (int p2 = 0; p2 < 4; p2++) cw[j][p2] = (const float*)d_in[1 + j * 4 + p2];
  const float* conv_ln_g = (const float*)d_in[13];
  const float* conv_ln_b = (const float*)d_in[14];
  const float* wq = (const float*)d_in[15];
  const float* wk = (const float*)d_in[16];
  const float* wv = (const float*)d_in[17];
  const float* wp = (const float*)d_in[18];
  const float* bp = (const float*)d_in[19];
  const float* lng = (const float*)d_in[20];
  const float* lnb = (const float*)d_in[21];
  const float* proj_w = (const float*)d_in[22];
  const float* proj_b = (const float*)d_in[23];
  const float* proj_ln_g = (const float*)d_in[24];
  const float* proj_ln_b = (const float*)d_in[25];
  float* out = (float*)d_out;

  // --- workspace ----------------------------------------------------------
  const size_t perb = (size_t)Tt * Hh;
  const size_t fixedB = 8ull * Hh * Hh * 2 + 3ull * 512 * WKMAX * 2 +
                        (size_t)Bb * Tt * Ff * 2 + (size_t)Bb * 2 * Hh * 4 +
                        (size_t)Bb * 8 * 2 * Hh * 4;  // + ppart
  int chunk = Bb;
  while (chunk > 1 && 16ull * perb * chunk + fixedB > ws_size) chunk >>= 1;

  const size_t crow = perb * (size_t)chunk;
  char* p = (char*)d_ws;
  float* h = (float*)p;              p += crow * 4;
  float* y = (float*)p;              // union with yraw16
  short* yraw16 = (short*)y;         p += crow * 4;
  __hip_bfloat16* h16 = (__hip_bfloat16*)p;  p += crow * 2;
  short* q16 = (short*)p;            p += crow * 2;
  short* k16 = (short*)p;            p += crow * 2;
  short* v16t = (short*)p;           p += crow * 2;
  __hip_bfloat16* wt = (__hip_bfloat16*)p;   p += 8ull * Hh * Hh * 2;
  __hip_bfloat16* wcv = (__hip_bfloat16*)p;  p += 3ull * 512 * WKMAX * 2;
  short* x16 = (short*)p;            p += (size_t)Bb * Tt * Ff * 2;
  float* pool = (float*)p;           p += (size_t)Bb * 2 * Hh * 4;
  float* ppart = (float*)p;

  // one-time casts
  wt_cast_kernel<<<dim3(24, 24, 8), 256, 0, stream>>>(wq, wk, wv, wp, wt);
  wcv_cast_kernel<<<(3 * 512 * WKMAX + 255) / 256, 256, 0, stream>>>(
      cw[0][0], cw[0][2], cw[1][0], cw[1][2], cw[2][0], cw[2][2], wcv);
  x_cast_kernel<<<(Bb * Tt * Ff / 8 + 255) / 256, 256, 0, stream>>>(
      x, x16, Bb * Tt * Ff / 8);

  const short* wts = (const short*)wt;

  for (int b0 = 0; b0 < Bb; b0 += chunk) {
    const int M = chunk * Tt;

    conv_gemm_kernel<<<dim3(Tt / 128, 4, chunk * 3), 256, 0, stream>>>(
        x16, (const short*)wcv, yraw16, b0);
    gate_ln_kernel<<<M, 256, 0, stream>>>(
        yraw16, h, h16, cw[0][1], cw[0][3], cw[1][1], cw[1][3], cw[2][1],
        cw[2][3], conv_ln_g, conv_ln_b);

    for (int i = 0; i < 2; i++) {
      const short* wqkv = wts + (size_t)(i * 4) * Hh * Hh;
      const short* wtp = wts + (size_t)(i * 4 + 3) * Hh * Hh;
      gemm_qkv<<<dim3(18, M / 128), 256, 0, stream>>>((const short*)h16, wqkv,
                                                      q16, k16, v16t);
      attn_mfma<<<dim3(Tt / 128, Gg, chunk), 256, 0, stream>>>(q16, k16, v16t,
                                                               q16);
      gemm_proj<<<dim3(6, M / 128), 256, 0, stream>>>(q16, wtp, y);
      res_ln_kernel<<<M, 256, 0, stream>>>(h, h16, y, bp + (size_t)i * Hh,
                                           lng + (size_t)i * Hh,
                                           lnb + (size_t)i * Hh);
    }

    pool_stage1<<<dim3((chunk * Hh) / 256, 8), 256, 0, stream>>>(h, ppart, b0);
  }

  pool_stage2<<<(Bb * Hh) / 256, 256, 0, stream>>>(ppart, pool);
  final_kernel<<<Bb, 256, 0, stream>>>(pool, proj_w, proj_b, proj_ln_g,
                                       proj_ln_b, out);
}

// Round 7
// 1247.715 us; speedup vs baseline: 8.9762x; 1.2831x over previous
//
#include <hip/hip_runtime.h>
#include <hip/hip_bf16.h>

// ---------------------------------------------------------------------------
// TemporalExtractor round 7:
//   - attn restructured: S^T formulation (P transform via register shuffles,
//     no P LDS round-trip), VGPR-prefetch software pipeline for K/V staging,
//     XCD-friendly grid order (b fastest), short4 epilogue.
//   - proj GEMM writes bf16 y; res_ln reads bf16 y.
//   - conv implicit-GEMM / fused QKV / LN / pool / final unchanged.
// ---------------------------------------------------------------------------

constexpr int Bb = 32, Tt = 1024, Ff = 64, Hh = 768, Gg = 4, Dd = 192;
constexpr float EPS = 1e-5f;
constexpr int WKMAX = 448;  // padded conv-weight K stride (7*64)
constexpr int VTS = 40;     // Vt LDS row stride in shorts

typedef __attribute__((ext_vector_type(8))) short short8;   // 8 bf16 = 4 VGPRs
typedef __attribute__((ext_vector_type(4))) float floatx4;  // MFMA acc

__device__ __forceinline__ void async_copy16(const void* g, void* l) {
  __builtin_amdgcn_global_load_lds(
      (const __attribute__((address_space(1))) unsigned int*)g,
      (__attribute__((address_space(3))) unsigned int*)l, 16, 0, 0);
}

__device__ __forceinline__ short bf16s(float f) {
  __hip_bfloat16 h = __float2bfloat16(f);
  return *(short*)&h;
}

__device__ __forceinline__ unsigned int pack_bf16(float lo, float hi) {
  return (unsigned int)(unsigned short)bf16s(lo) |
         ((unsigned int)(unsigned short)bf16s(hi) << 16);
}

__device__ __forceinline__ float2 block_reduce2(float a, float b, float* tmp) {
  int lane = threadIdx.x & 63, wid = threadIdx.x >> 6;
#pragma unroll
  for (int off = 32; off > 0; off >>= 1) {
    a += __shfl_down(a, off);
    b += __shfl_down(b, off);
  }
  if (lane == 0) { tmp[wid] = a; tmp[4 + wid] = b; }
  __syncthreads();
  if (threadIdx.x == 0) {
    tmp[0] = tmp[0] + tmp[1] + tmp[2] + tmp[3];
    tmp[4] = tmp[4] + tmp[5] + tmp[6] + tmp[7];
  }
  __syncthreads();
  float2 r; r.x = tmp[0]; r.y = tmp[4];
  return r;
}

// ---------------------------------------------------------------------------
// 0a) Attn/proj weight transpose+cast (Q pre-scaled by 192^-0.5)
// ---------------------------------------------------------------------------
__global__ __launch_bounds__(256) void wt_cast_kernel(
    const float* __restrict__ wq, const float* __restrict__ wk,
    const float* __restrict__ wv, const float* __restrict__ wp,
    __hip_bfloat16* __restrict__ wt) {
  const int z = blockIdx.z;
  const int m = z & 3, i = z >> 2;
  const float* src =
      (m == 0 ? wq : m == 1 ? wk : m == 2 ? wv : wp) + (size_t)i * Hh * Hh;
  const float sc = (m == 0) ? 0.0721687836f : 1.f;
  __shared__ float tile[32][33];
  const int n0 = blockIdx.x * 32, k0 = blockIdx.y * 32;
  const int tx = threadIdx.x & 31, ty = threadIdx.x >> 5;
#pragma unroll
  for (int r = 0; r < 4; r++)
    tile[ty + 8 * r][tx] = src[(size_t)(k0 + ty + 8 * r) * Hh + n0 + tx];
  __syncthreads();
#pragma unroll
  for (int r = 0; r < 4; r++)
    wt[((size_t)z * Hh + n0 + ty + 8 * r) * Hh + k0 + tx] =
        __float2bfloat16(tile[tx][ty + 8 * r] * sc);
}

// ---------------------------------------------------------------------------
// 0b) Conv weight cast
// ---------------------------------------------------------------------------
__global__ __launch_bounds__(256) void wcv_cast_kernel(
    const float* __restrict__ wf3, const float* __restrict__ wg3,
    const float* __restrict__ wf5, const float* __restrict__ wg5,
    const float* __restrict__ wf7, const float* __restrict__ wg7,
    __hip_bfloat16* __restrict__ wcv) {
  int idx = blockIdx.x * 256 + threadIdx.x;
  if (idx >= 3 * 512 * WKMAX) return;
  int j = idx / (512 * WKMAX);
  int rem = idx - j * 512 * WKMAX;
  int n = rem / WKMAX, k = rem % WKMAX;
  int Kw = 3 + 2 * j;
  float v = 0.f;
  if (k < Kw * 64) {
    const float* src = (n < 256) ? (j == 0 ? wf3 : j == 1 ? wf5 : wf7)
                                 : (j == 0 ? wg3 : j == 1 ? wg5 : wg7);
    v = src[(size_t)k * 256 + (n & 255)];
  }
  wcv[idx] = __float2bfloat16(v);
}

// 0c) x cast fp32 -> bf16
__global__ __launch_bounds__(256) void x_cast_kernel(
    const float* __restrict__ x, short* __restrict__ x16, int n8) {
  int idx = blockIdx.x * 256 + threadIdx.x;
  if (idx >= n8) return;
  const float4 a = ((const float4*)x)[idx * 2];
  const float4 b = ((const float4*)x)[idx * 2 + 1];
  short8 o;
  o[0] = bf16s(a.x); o[1] = bf16s(a.y); o[2] = bf16s(a.z); o[3] = bf16s(a.w);
  o[4] = bf16s(b.x); o[5] = bf16s(b.y); o[6] = bf16s(b.z); o[7] = bf16s(b.w);
  ((short8*)x16)[idx] = o;
}

// ---------------------------------------------------------------------------
// 1) Conv as implicit GEMM (unchanged)
// ---------------------------------------------------------------------------
__global__ __launch_bounds__(256) void conv_gemm_kernel(
    const short* __restrict__ x16, const short* __restrict__ wcv,
    short* __restrict__ yraw, int b0) {
  __shared__ __align__(16) short Asl[128 * 72];
  __shared__ __align__(16) short Bsl[128 * 72];
  const int t0 = blockIdx.x * 128, n0 = blockIdx.y * 128;
  const int bl = blockIdx.z / 3, j = blockIdx.z % 3;
  const int Kw = 3 + 2 * j, pad = j + 1;
  const int bglob = b0 + bl;
  const short* wb = wcv + (size_t)j * 512 * WKMAX;
  const int tid = threadIdx.x;
  const int lane = tid & 63;
  const int w = tid >> 6, wm = w >> 1, wn = w & 1;
  const int lm = lane & 15, quad = lane >> 4;

  floatx4 acc[4][4];
#pragma unroll
  for (int i = 0; i < 4; i++)
#pragma unroll
    for (int jj = 0; jj < 4; jj++) acc[i][jj] = (floatx4)0.f;

  for (int kk = 0; kk < Kw; kk++) {
    __syncthreads();
#pragma unroll
    for (int it = 0; it < 4; it++) {
      int s = it * 256 + tid;
      int row = s >> 3, c8 = s & 7;
      int t = t0 + row + kk - pad;
      short8 av = (short8)0;
      if (t >= 0 && t < Tt)
        av = *(const short8*)&x16[((size_t)bglob * Tt + t) * Ff + c8 * 8];
      *(short8*)&Asl[row * 72 + c8 * 8] = av;
      short8 bv = *(const short8*)&wb[(size_t)(n0 + row) * WKMAX + kk * 64 +
                                      c8 * 8];
      *(short8*)&Bsl[row * 72 + c8 * 8] = bv;
    }
    __syncthreads();
#pragma unroll
    for (int ks = 0; ks < 2; ks++) {
      short8 a[4], b[4];
#pragma unroll
      for (int i = 0; i < 4; i++)
        a[i] = *(const short8*)&Asl[(wm * 64 + i * 16 + lm) * 72 + ks * 32 +
                                    quad * 8];
#pragma unroll
      for (int jj = 0; jj < 4; jj++)
        b[jj] = *(const short8*)&Bsl[(wn * 64 + jj * 16 + lm) * 72 + ks * 32 +
                                     quad * 8];
#pragma unroll
      for (int i = 0; i < 4; i++)
#pragma unroll
        for (int jj = 0; jj < 4; jj++)
          acc[i][jj] = __builtin_amdgcn_mfma_f32_16x16x32_bf16(a[i], b[jj],
                                                               acc[i][jj],
                                                               0, 0, 0);
    }
  }

  const int rbase = quad * 4;
#pragma unroll
  for (int i = 0; i < 4; i++)
#pragma unroll
    for (int jj = 0; jj < 4; jj++) {
      int mrow = t0 + wm * 64 + i * 16 + rbase;
      int ncol = n0 + wn * 64 + jj * 16 + lm;
#pragma unroll
      for (int r = 0; r < 4; r++)
        yraw[((size_t)bl * Tt + mrow + r) * 1536 + j * 512 + ncol] =
            bf16s(acc[i][jj][r]);
    }
}

// ---------------------------------------------------------------------------
// 2) Fused gate + LayerNorm (unchanged)
// ---------------------------------------------------------------------------
__global__ __launch_bounds__(256) void gate_ln_kernel(
    const short* __restrict__ yraw, float* __restrict__ h,
    __hip_bfloat16* __restrict__ h16, const float* __restrict__ bf3,
    const float* __restrict__ bg3, const float* __restrict__ bf5,
    const float* __restrict__ bg5, const float* __restrict__ bf7,
    const float* __restrict__ bg7, const float* __restrict__ g,
    const float* __restrict__ bt) {
  __shared__ float red[8];
  const size_t row = blockIdx.x;
  float v[3], s = 0.f, ss = 0.f;
#pragma unroll
  for (int jj = 0; jj < 3; jj++) {
    int c = threadIdx.x + jj * 256;
    int br = c >> 8, cc = c & 255;
    const float* bfp = br == 0 ? bf3 : br == 1 ? bf5 : bf7;
    const float* bgp = br == 0 ? bg3 : br == 1 ? bg5 : bg7;
    __hip_bfloat16 rf = *(const __hip_bfloat16*)&yraw[row * 1536 + br * 512 + cc];
    __hip_bfloat16 rg =
        *(const __hip_bfloat16*)&yraw[row * 1536 + br * 512 + 256 + cc];
    float f = __bfloat162float(rf) + bfp[cc];
    float gt = __bfloat162float(rg) + bgp[cc];
    float a = f > 0.f ? f : 0.f;
    float t = a * (1.f / (1.f + __expf(-gt)));
    v[jj] = t; s += t; ss += t * t;
  }
  float2 r = block_reduce2(s, ss, red);
  float mu = r.x * (1.f / Hh);
  float var = r.y * (1.f / Hh) - mu * mu;
  float rs = rsqrtf(var + EPS);
#pragma unroll
  for (int jj = 0; jj < 3; jj++) {
    int c = threadIdx.x + jj * 256;
    float o = (v[jj] - mu) * rs * g[c] + bt[c];
    h[row * Hh + c] = o;
    h16[row * Hh + c] = __float2bfloat16(o);
  }
}

// residual LN: h = LN(h + y(bf16) + bp), emit fp32 + bf16
__global__ __launch_bounds__(256) void res_ln_kernel(
    float* __restrict__ h, __hip_bfloat16* __restrict__ h16,
    const __hip_bfloat16* __restrict__ y, const float* __restrict__ bp,
    const float* __restrict__ g, const float* __restrict__ bt) {
  __shared__ float red[8];
  const size_t row = blockIdx.x;
  float v[3], s = 0.f, ss = 0.f;
#pragma unroll
  for (int jj = 0; jj < 3; jj++) {
    int c = threadIdx.x + jj * 256;
    float t = h[row * Hh + c] + __bfloat162float(y[row * Hh + c]) + bp[c];
    v[jj] = t; s += t; ss += t * t;
  }
  float2 r = block_reduce2(s, ss, red);
  float mu = r.x * (1.f / Hh);
  float var = r.y * (1.f / Hh) - mu * mu;
  float rs = rsqrtf(var + EPS);
#pragma unroll
  for (int jj = 0; jj < 3; jj++) {
    int c = threadIdx.x + jj * 256;
    float o = (v[jj] - mu) * rs * g[c] + bt[c];
    h[row * Hh + c] = o;
    h16[row * Hh + c] = __float2bfloat16(o);
  }
}

// ---------------------------------------------------------------------------
// 3a) Fused QKV GEMM (unchanged)
// ---------------------------------------------------------------------------
__global__ __launch_bounds__(256) void gemm_qkv(
    const short* __restrict__ A, const short* __restrict__ Bt,
    short* __restrict__ q16, short* __restrict__ k16,
    short* __restrict__ vt16) {
  constexpr int K = 768;
  __shared__ __align__(16) short Asl[128 * 32];
  __shared__ __align__(16) short Bsl[128 * 32];
  const int n0 = blockIdx.x * 128, m0 = blockIdx.y * 128;
  const int lane = threadIdx.x & 63;
  const int w = threadIdx.x >> 6, wm = w >> 1, wn = w & 1;
  const int lm = lane & 15, quad = lane >> 4;

  floatx4 acc[4][4];
#pragma unroll
  for (int i = 0; i < 4; i++)
#pragma unroll
    for (int jj = 0; jj < 4; jj++) acc[i][jj] = (floatx4)0.f;

  for (int k0 = 0; k0 < K; k0 += 32) {
    __syncthreads();
#pragma unroll
    for (int half = 0; half < 2; half++) {
      int s = half * 256 + threadIdx.x;
      int m = s >> 2, ks = (s & 3) * 8;
      async_copy16(&A[(size_t)(m0 + m) * K + k0 + ks], &Asl[s * 8]);
      async_copy16(&Bt[(size_t)(n0 + m) * K + k0 + ks], &Bsl[s * 8]);
    }
    __syncthreads();

    short8 a[4], b[4];
#pragma unroll
    for (int i = 0; i < 4; i++)
      a[i] = *(const short8*)&Asl[(wm * 64 + i * 16 + lm) * 32 + quad * 8];
#pragma unroll
    for (int jj = 0; jj < 4; jj++)
      b[jj] = *(const short8*)&Bsl[(wn * 64 + jj * 16 + lm) * 32 + quad * 8];
#pragma unroll
    for (int i = 0; i < 4; i++)
#pragma unroll
      for (int jj = 0; jj < 4; jj++)
        acc[i][jj] = __builtin_amdgcn_mfma_f32_16x16x32_bf16(a[i], b[jj],
                                                             acc[i][jj],
                                                             0, 0, 0);
  }

  const int which = blockIdx.x / 6;  // 0:q 1:k 2:v
  const int rbase = quad * 4;
#pragma unroll
  for (int i = 0; i < 4; i++)
#pragma unroll
    for (int jj = 0; jj < 4; jj++) {
      int mrow = m0 + wm * 64 + i * 16 + rbase;
      int nl = n0 - which * Hh + wn * 64 + jj * 16 + lm;
      if (which == 0) {
#pragma unroll
        for (int r = 0; r < 4; r++)
          q16[(size_t)(mrow + r) * Hh + nl] = bf16s(acc[i][jj][r]);
      } else if (which == 1) {
#pragma unroll
        for (int r = 0; r < 4; r++)
          k16[(size_t)(mrow + r) * Hh + nl] = bf16s(acc[i][jj][r]);
      } else {
        int bL = mrow >> 10, t = mrow & 1023;
        int g = nl / Dd, d = nl % Dd;
        short4 sv;
        sv.x = bf16s(acc[i][jj][0]); sv.y = bf16s(acc[i][jj][1]);
        sv.z = bf16s(acc[i][jj][2]); sv.w = bf16s(acc[i][jj][3]);
        *(short4*)&vt16[(((size_t)bL * Gg + g) * Dd + d) * Tt + t] = sv;
      }
    }
}

// 3b) Proj GEMM: bf16 out [tok][768]
__global__ __launch_bounds__(256) void gemm_proj(
    const short* __restrict__ A, const short* __restrict__ Bt,
    short* __restrict__ C) {
  constexpr int K = 768, N = 768;
  __shared__ __align__(16) short Asl[128 * 32];
  __shared__ __align__(16) short Bsl[128 * 32];
  const int n0 = blockIdx.x * 128, m0 = blockIdx.y * 128;
  const int lane = threadIdx.x & 63;
  const int w = threadIdx.x >> 6, wm = w >> 1, wn = w & 1;
  const int lm = lane & 15, quad = lane >> 4;

  floatx4 acc[4][4];
#pragma unroll
  for (int i = 0; i < 4; i++)
#pragma unroll
    for (int jj = 0; jj < 4; jj++) acc[i][jj] = (floatx4)0.f;

  for (int k0 = 0; k0 < K; k0 += 32) {
    __syncthreads();
#pragma unroll
    for (int half = 0; half < 2; half++) {
      int s = half * 256 + threadIdx.x;
      int m = s >> 2, ks = (s & 3) * 8;
      async_copy16(&A[(size_t)(m0 + m) * K + k0 + ks], &Asl[s * 8]);
      async_copy16(&Bt[(size_t)(n0 + m) * K + k0 + ks], &Bsl[s * 8]);
    }
    __syncthreads();

    short8 a[4], b[4];
#pragma unroll
    for (int i = 0; i < 4; i++)
      a[i] = *(const short8*)&Asl[(wm * 64 + i * 16 + lm) * 32 + quad * 8];
#pragma unroll
    for (int jj = 0; jj < 4; jj++)
      b[jj] = *(const short8*)&Bsl[(wn * 64 + jj * 16 + lm) * 32 + quad * 8];
#pragma unroll
    for (int i = 0; i < 4; i++)
#pragma unroll
      for (int jj = 0; jj < 4; jj++)
        acc[i][jj] = __builtin_amdgcn_mfma_f32_16x16x32_bf16(a[i], b[jj],
                                                             acc[i][jj],
                                                             0, 0, 0);
  }

  const int rbase = quad * 4;
#pragma unroll
  for (int i = 0; i < 4; i++)
#pragma unroll
    for (int jj = 0; jj < 4; jj++) {
      int mrow = m0 + wm * 64 + i * 16 + rbase;
      int ncol = n0 + wn * 64 + jj * 16 + lm;
#pragma unroll
      for (int r = 0; r < 4; r++)
        C[(size_t)(mrow + r) * N + ncol] = bf16s(acc[i][jj][r]);
    }
}

// ---------------------------------------------------------------------------
// 4) MFMA flash attention, S^T formulation + pipelined staging.
//    grid (chunk, G, T/128): b fastest => q-blocks sharing K/V land on one
//    XCD's L2. Per wave: q-rows w*32..+31 (2 tiles), K-tile 32 rows.
//    S^T = MFMA(K-frag, Q-frag)  (C: row=kk=quad*4+r, col=q=lm)
//    P^T B-frag built via 8 cross-quad shuffles per q-tile.
//    O^T = MFMA(Vt-frag, P^T-frag) (C: row=d, col=q). No P LDS round-trip.
// ---------------------------------------------------------------------------
__global__ __launch_bounds__(256, 2) void attn_mfma(
    const short* __restrict__ q16, const short* __restrict__ k16,
    const short* __restrict__ vt16, short* __restrict__ o16) {
  const int b = blockIdx.x;
  const int g = blockIdx.y;
  const int q0 = blockIdx.z * 128;
  const int tid = threadIdx.x;
  const int w = tid >> 6, lane = tid & 63, lm = lane & 15, quad = lane >> 4;

  __shared__ __align__(16) short Ks[32 * 200];   // [kk][d], stride 200
  __shared__ __align__(16) short Vt[192 * VTS];  // [d][kk], stride 40

  // Q fragments (serve as MFMA B operands; layout index-identical to A)
  short8 qf[2][6];
#pragma unroll
  for (int mt = 0; mt < 2; mt++)
#pragma unroll
    for (int ks = 0; ks < 6; ks++) {
      int tok = b * Tt + q0 + w * 32 + mt * 16 + lm;
      qf[mt][ks] = *(const short8*)&q16[(size_t)tok * Hh + g * Dd + ks * 32 +
                                        quad * 8];
    }

  floatx4 Oa[2][12];  // O^T accum: [q-tile][d-tile], col=q=lm, row=d
#pragma unroll
  for (int mt = 0; mt < 2; mt++)
#pragma unroll
    for (int n = 0; n < 12; n++) Oa[mt][n] = (floatx4)0.f;
  float mr[2] = {-1e30f, -1e30f}, lr[2] = {0.f, 0.f};  // per q=lm, repl x4

  // prefetch tile 0 into VGPRs
  short8 kvK[3], kvV[3];
#pragma unroll
  for (int it = 0; it < 3; it++) {
    int s = it * 256 + tid;
    int row = s / 24, cs = s - row * 24;
    kvK[it] = *(const short8*)&k16[(size_t)(b * Tt + row) * Hh + g * Dd +
                                   cs * 8];
    int d = s >> 2, c2 = s & 3;
    kvV[it] = *(const short8*)&vt16[(((size_t)b * Gg + g) * Dd + d) * Tt +
                                    c2 * 8];
  }

  for (int kt = 0; kt < Tt; kt += 32) {
    __syncthreads();  // all waves done reading LDS from previous tile
#pragma unroll
    for (int it = 0; it < 3; it++) {
      int s = it * 256 + tid;
      int row = s / 24, cs = s - row * 24;
      *(short8*)&Ks[row * 200 + cs * 8] = kvK[it];
      int d = s >> 2, c2 = s & 3;
      *(short8*)&Vt[d * VTS + c2 * 8] = kvV[it];
    }
    __syncthreads();  // LDS writes visible

    // issue next tile's loads; they land during compute below
    if (kt + 32 < Tt) {
#pragma unroll
      for (int it = 0; it < 3; it++) {
        int s = it * 256 + tid;
        int row = s / 24, cs = s - row * 24;
        kvK[it] = *(const short8*)&k16[(size_t)(b * Tt + kt + 32 + row) * Hh +
                                       g * Dd + cs * 8];
        int d = s >> 2, c2 = s & 3;
        kvV[it] = *(const short8*)&vt16[(((size_t)b * Gg + g) * Dd + d) * Tt +
                                        kt + 32 + c2 * 8];
      }
    }

    // S^T tiles: st[mt][jj], rows kk=jj*16+quad*4+r, col q=lm
    floatx4 st[2][2];
#pragma unroll
    for (int mt = 0; mt < 2; mt++)
#pragma unroll
      for (int jj = 0; jj < 2; jj++) st[mt][jj] = (floatx4)0.f;
#pragma unroll
    for (int ks = 0; ks < 6; ks++) {
      short8 k0 = *(const short8*)&Ks[lm * 200 + ks * 32 + quad * 8];
      short8 k1 = *(const short8*)&Ks[(16 + lm) * 200 + ks * 32 + quad * 8];
      st[0][0] = __builtin_amdgcn_mfma_f32_16x16x32_bf16(k0, qf[0][ks], st[0][0], 0, 0, 0);
      st[0][1] = __builtin_amdgcn_mfma_f32_16x16x32_bf16(k1, qf[0][ks], st[0][1], 0, 0, 0);
      st[1][0] = __builtin_amdgcn_mfma_f32_16x16x32_bf16(k0, qf[1][ks], st[1][0], 0, 0, 0);
      st[1][1] = __builtin_amdgcn_mfma_f32_16x16x32_bf16(k1, qf[1][ks], st[1][1], 0, 0, 0);
    }

    // online softmax over kk (per q=lm) + P^T fragment build
    short8 ptf[2];
#pragma unroll
    for (int mt = 0; mt < 2; mt++) {
      float smax = st[mt][0][0];
#pragma unroll
      for (int r = 1; r < 4; r++) smax = fmaxf(smax, st[mt][0][r]);
#pragma unroll
      for (int r = 0; r < 4; r++) smax = fmaxf(smax, st[mt][1][r]);
      smax = fmaxf(smax, __shfl_xor(smax, 16));
      smax = fmaxf(smax, __shfl_xor(smax, 32));
      float mnew = fmaxf(mr[mt], smax);
      float alpha = __expf(mr[mt] - mnew);
      mr[mt] = mnew;
      float p[2][4];
      float sum = 0.f;
#pragma unroll
      for (int jj = 0; jj < 2; jj++)
#pragma unroll
        for (int r = 0; r < 4; r++) {
          p[jj][r] = __expf(st[mt][jj][r] - mnew);
          sum += p[jj][r];
        }
      sum += __shfl_xor(sum, 16);
      sum += __shfl_xor(sum, 32);
      lr[mt] = lr[mt] * alpha + sum;

      // pack p -> bf16x2 dwords; cross-quad shuffle into B-frag layout:
      // target lane (Q,lm) k=8Q+j: jj=Q>>1, src quad 2(Q&1)+(j>>2), r=j&3
      int pk00 = (int)pack_bf16(p[0][0], p[0][1]);
      int pk01 = (int)pack_bf16(p[0][2], p[0][3]);
      int pk10 = (int)pack_bf16(p[1][0], p[1][1]);
      int pk11 = (int)pack_bf16(p[1][2], p[1][3]);
      int srcA = ((quad & 1) << 5) + lm;  // lane 32*(Q&1)+lm
      int srcB = srcA + 16;
      int a0 = __shfl(pk00, srcA), a1 = __shfl(pk01, srcA);
      int a2 = __shfl(pk00, srcB), a3 = __shfl(pk01, srcB);
      int b0 = __shfl(pk10, srcA), b1 = __shfl(pk11, srcA);
      int b2 = __shfl(pk10, srcB), b3 = __shfl(pk11, srcB);
      bool hi = quad >= 2;  // jj = Q>>1
      union { int u[4]; short8 v; } pu;
      pu.u[0] = hi ? b0 : a0;
      pu.u[1] = hi ? b1 : a1;
      pu.u[2] = hi ? b2 : a2;
      pu.u[3] = hi ? b3 : a3;
      ptf[mt] = pu.v;

#pragma unroll
      for (int n = 0; n < 12; n++)
#pragma unroll
        for (int r = 0; r < 4; r++) Oa[mt][n][r] *= alpha;
    }

    // O^T += V^T P^T
#pragma unroll
    for (int n = 0; n < 12; n++) {
      short8 vf = *(const short8*)&Vt[(n * 16 + lm) * VTS + quad * 8];
      Oa[0][n] = __builtin_amdgcn_mfma_f32_16x16x32_bf16(vf, ptf[0], Oa[0][n], 0, 0, 0);
      Oa[1][n] = __builtin_amdgcn_mfma_f32_16x16x32_bf16(vf, ptf[1], Oa[1][n], 0, 0, 0);
    }
  }

  // epilogue: O^T[d=n*16+quad*4+r][q=lm] / l  -> short4 per (mt,n)
#pragma unroll
  for (int mt = 0; mt < 2; mt++) {
    float inv = 1.f / lr[mt];
    int tok = b * Tt + q0 + w * 32 + mt * 16 + lm;
#pragma unroll
    for (int n = 0; n < 12; n++) {
      short4 sv;
      sv.x = bf16s(Oa[mt][n][0] * inv);
      sv.y = bf16s(Oa[mt][n][1] * inv);
      sv.z = bf16s(Oa[mt][n][2] * inv);
      sv.w = bf16s(Oa[mt][n][3] * inv);
      *(short4*)&o16[(size_t)tok * Hh + g * Dd + n * 16 + quad * 4] = sv;
    }
  }
}

// ---------------------------------------------------------------------------
// 5) Pool, two-stage (unchanged)
// ---------------------------------------------------------------------------
__global__ __launch_bounds__(256) void pool_stage1(const float* __restrict__ h,
                                                   float* __restrict__ ppart,
                                                   int b0) {
  int idx = blockIdx.x * 256 + threadIdx.x;
  int seg = blockIdx.y;
  int bl = idx / Hh, c = idx % Hh;
  float s = 0.f, ss = 0.f;
  const float* hp = &h[((size_t)bl * Tt + seg * 128) * Hh + c];
  for (int t = 0; t < 128; t++) {
    float v = hp[(size_t)t * Hh];
    s += v; ss += v * v;
  }
  float* o = &ppart[(((size_t)(b0 + bl) * 8 + seg) * 2) * Hh + c];
  o[0] = s;
  o[Hh] = ss;
}

__global__ __launch_bounds__(256) void pool_stage2(
    const float* __restrict__ ppart, float* __restrict__ pool) {
  int idx = blockIdx.x * 256 + threadIdx.x;
  int b = idx / Hh, c = idx % Hh;
  float s = 0.f, ss = 0.f;
#pragma unroll
  for (int seg = 0; seg < 8; seg++) {
    const float* o = &ppart[(((size_t)b * 8 + seg) * 2) * Hh + c];
    s += o[0]; ss += o[Hh];
  }
  float mu = s * (1.f / Tt);
  float var = ss * (1.f / Tt) - mu * mu;
  pool[(size_t)b * 1536 + c] = mu;
  pool[(size_t)b * 1536 + 768 + c] = sqrtf(fmaxf(var, 0.f));
}

// ---------------------------------------------------------------------------
// 6) Final projection (unchanged)
// ---------------------------------------------------------------------------
__global__ __launch_bounds__(256) void final_kernel(
    const float* __restrict__ pool, const float* __restrict__ pw,
    const float* __restrict__ pb, const float* __restrict__ g,
    const float* __restrict__ bt, float* __restrict__ out) {
  __shared__ float ms[1536];
  __shared__ float red[8];
  const int b = blockIdx.x;
  for (int e = threadIdx.x; e < 1536; e += 256) ms[e] = pool[(size_t)b * 1536 + e];
  __syncthreads();
  const int n0 = threadIdx.x, n1 = threadIdx.x + 256, n2 = threadIdx.x + 512;
  float a0 = pb[n0], a1 = pb[n1], a2 = pb[n2];
  for (int k = 0; k < 1536; k++) {
    float m = ms[k];
    const float* row = &pw[(size_t)k * Hh];
    a0 = fmaf(m, row[n0], a0);
    a1 = fmaf(m, row[n1], a1);
    a2 = fmaf(m, row[n2], a2);
  }
  float s = a0 + a1 + a2, ss = a0 * a0 + a1 * a1 + a2 * a2;
  float2 r = block_reduce2(s, ss, red);
  float mu = r.x * (1.f / Hh);
  float var = r.y * (1.f / Hh) - mu * mu;
  float rs = rsqrtf(var + EPS);
  float o0 = (a0 - mu) * rs * g[n0] + bt[n0];
  float o1 = (a1 - mu) * rs * g[n1] + bt[n1];
  float o2 = (a2 - mu) * rs * g[n2] + bt[n2];
  out[(size_t)b * Hh + n0] = o0 > 0.f ? o0 : 0.f;
  out[(size_t)b * Hh + n1] = o1 > 0.f ? o1 : 0.f;
  out[(size_t)b * Hh + n2] = o2 > 0.f ? o2 : 0.f;
}

// ---------------------------------------------------------------------------
extern "C" void kernel_launch(void* const* d_in, const int* in_sizes, int n_in,
                              void* d_out, int out_size, void* d_ws,
                              size_t ws_size, hipStream_t stream) {
  (void)in_sizes; (void)n_in; (void)out_size;
  const float* x = (const float*)d_in[0];
  const float* cw[3][4];
  for (int j = 0; j < 3; j++)
    for (int p2 = 0; p2 < 4; p2++) cw[j][p2] = (const float*)d_in[1 + j * 4 + p2];
  const float* conv_ln_g = (const float*)d_in[13];
  const float* conv_ln_b = (const float*)d_in[14];
  const float* wq = (const float*)d_in[15];
  const float* wk = (const float*)d_in[16];
  const float* wv = (const float*)d_in[17];
  const float* wp = (const float*)d_in[18];
  const float* bp = (const float*)d_in[19];
  const float* lng = (const float*)d_in[20];
  const float* lnb = (const float*)d_in[21];
  const float* proj_w = (const float*)d_in[22];
  const float* proj_b = (const float*)d_in[23];
  const float* proj_ln_g = (const float*)d_in[24];
  const float* proj_ln_b = (const float*)d_in[25];
  float* out = (float*)d_out;

  // --- workspace ----------------------------------------------------------
  const size_t perb = (size_t)Tt * Hh;
  const size_t fixedB = 8ull * Hh * Hh * 2 + 3ull * 512 * WKMAX * 2 +
                        (size_t)Bb * Tt * Ff * 2 + (size_t)Bb * 2 * Hh * 4 +
                        (size_t)Bb * 8 * 2 * Hh * 4;
  int chunk = Bb;
  while (chunk > 1 && 16ull * perb * chunk + fixedB > ws_size) chunk >>= 1;

  const size_t crow = perb * (size_t)chunk;
  char* p = (char*)d_ws;
  float* h = (float*)p;              p += crow * 4;
  short* yraw16 = (short*)p;         // union: conv raw (bf16) / proj out y16
  short* y16 = yraw16;               p += crow * 4;
  __hip_bfloat16* h16 = (__hip_bfloat16*)p;  p += crow * 2;
  short* q16 = (short*)p;            p += crow * 2;
  short* k16 = (short*)p;            p += crow * 2;
  short* v16t = (short*)p;           p += crow * 2;
  __hip_bfloat16* wt = (__hip_bfloat16*)p;   p += 8ull * Hh * Hh * 2;
  __hip_bfloat16* wcv = (__hip_bfloat16*)p;  p += 3ull * 512 * WKMAX * 2;
  short* x16 = (short*)p;            p += (size_t)Bb * Tt * Ff * 2;
  float* pool = (float*)p;           p += (size_t)Bb * 2 * Hh * 4;
  float* ppart = (float*)p;

  // one-time casts
  wt_cast_kernel<<<dim3(24, 24, 8), 256, 0, stream>>>(wq, wk, wv, wp, wt);
  wcv_cast_kernel<<<(3 * 512 * WKMAX + 255) / 256, 256, 0, stream>>>(
      cw[0][0], cw[0][2], cw[1][0], cw[1][2], cw[2][0], cw[2][2], wcv);
  x_cast_kernel<<<(Bb * Tt * Ff / 8 + 255) / 256, 256, 0, stream>>>(
      x, x16, Bb * Tt * Ff / 8);

  const short* wts = (const short*)wt;

  for (int b0 = 0; b0 < Bb; b0 += chunk) {
    const int M = chunk * Tt;

    conv_gemm_kernel<<<dim3(Tt / 128, 4, chunk * 3), 256, 0, stream>>>(
        x16, (const short*)wcv, yraw16, b0);
    gate_ln_kernel<<<M, 256, 0, stream>>>(
        yraw16, h, h16, cw[0][1], cw[0][3], cw[1][1], cw[1][3], cw[2][1],
        cw[2][3], conv_ln_g, conv_ln_b);

    for (int i = 0; i < 2; i++) {
      const short* wqkv = wts + (size_t)(i * 4) * Hh * Hh;
      const short* wtp = wts + (size_t)(i * 4 + 3) * Hh * Hh;
      gemm_qkv<<<dim3(18, M / 128), 256, 0, stream>>>((const short*)h16, wqkv,
                                                      q16, k16, v16t);
      attn_mfma<<<dim3(chunk, Gg, Tt / 128), 256, 0, stream>>>(q16, k16, v16t,
                                                               q16);
      gemm_proj<<<dim3(6, M / 128), 256, 0, stream>>>(q16, wtp, y16);
      res_ln_kernel<<<M, 256, 0, stream>>>(h, h16, (const __hip_bfloat16*)y16,
                                           bp + (size_t)i * Hh,
                                           lng + (size_t)i * Hh,
                                           lnb + (size_t)i * Hh);
    }

    pool_stage1<<<dim3((chunk * Hh) / 256, 8), 256, 0, stream>>>(h, ppart, b0);
  }

  pool_stage2<<<(Bb * Hh) / 256, 256, 0, stream>>>(ppart, pool);
  final_kernel<<<Bb, 256, 0, stream>>>(pool, proj_w, proj_b, proj_ln_g,
                                       proj_ln_b, out);
}

// Round 8
// 1158.860 us; speedup vs baseline: 9.6644x; 1.0767x over previous
//
#include <hip/hip_runtime.h>
#include <hip/hip_bf16.h>

// ---------------------------------------------------------------------------
// TemporalExtractor round 8:
//   - final projection -> split-K two-stage (was 32-block latency-bound
//     serial K-loop at 115 us, occupancy 1.4%): final_partial (192 blocks,
//     8 k-slices) + final_stage2 (combine + LN + relu).
//   - everything else unchanged from round 7.
// ---------------------------------------------------------------------------

constexpr int Bb = 32, Tt = 1024, Ff = 64, Hh = 768, Gg = 4, Dd = 192;
constexpr float EPS = 1e-5f;
constexpr int WKMAX = 448;  // padded conv-weight K stride (7*64)
constexpr int VTS = 40;     // Vt LDS row stride in shorts

typedef __attribute__((ext_vector_type(8))) short short8;   // 8 bf16 = 4 VGPRs
typedef __attribute__((ext_vector_type(4))) float floatx4;  // MFMA acc

__device__ __forceinline__ void async_copy16(const void* g, void* l) {
  __builtin_amdgcn_global_load_lds(
      (const __attribute__((address_space(1))) unsigned int*)g,
      (__attribute__((address_space(3))) unsigned int*)l, 16, 0, 0);
}

__device__ __forceinline__ short bf16s(float f) {
  __hip_bfloat16 h = __float2bfloat16(f);
  return *(short*)&h;
}

__device__ __forceinline__ unsigned int pack_bf16(float lo, float hi) {
  return (unsigned int)(unsigned short)bf16s(lo) |
         ((unsigned int)(unsigned short)bf16s(hi) << 16);
}

__device__ __forceinline__ float2 block_reduce2(float a, float b, float* tmp) {
  int lane = threadIdx.x & 63, wid = threadIdx.x >> 6;
#pragma unroll
  for (int off = 32; off > 0; off >>= 1) {
    a += __shfl_down(a, off);
    b += __shfl_down(b, off);
  }
  if (lane == 0) { tmp[wid] = a; tmp[4 + wid] = b; }
  __syncthreads();
  if (threadIdx.x == 0) {
    tmp[0] = tmp[0] + tmp[1] + tmp[2] + tmp[3];
    tmp[4] = tmp[4] + tmp[5] + tmp[6] + tmp[7];
  }
  __syncthreads();
  float2 r; r.x = tmp[0]; r.y = tmp[4];
  return r;
}

// ---------------------------------------------------------------------------
// 0a) Attn/proj weight transpose+cast (Q pre-scaled by 192^-0.5)
// ---------------------------------------------------------------------------
__global__ __launch_bounds__(256) void wt_cast_kernel(
    const float* __restrict__ wq, const float* __restrict__ wk,
    const float* __restrict__ wv, const float* __restrict__ wp,
    __hip_bfloat16* __restrict__ wt) {
  const int z = blockIdx.z;
  const int m = z & 3, i = z >> 2;
  const float* src =
      (m == 0 ? wq : m == 1 ? wk : m == 2 ? wv : wp) + (size_t)i * Hh * Hh;
  const float sc = (m == 0) ? 0.0721687836f : 1.f;
  __shared__ float tile[32][33];
  const int n0 = blockIdx.x * 32, k0 = blockIdx.y * 32;
  const int tx = threadIdx.x & 31, ty = threadIdx.x >> 5;
#pragma unroll
  for (int r = 0; r < 4; r++)
    tile[ty + 8 * r][tx] = src[(size_t)(k0 + ty + 8 * r) * Hh + n0 + tx];
  __syncthreads();
#pragma unroll
  for (int r = 0; r < 4; r++)
    wt[((size_t)z * Hh + n0 + ty + 8 * r) * Hh + k0 + tx] =
        __float2bfloat16(tile[tx][ty + 8 * r] * sc);
}

// ---------------------------------------------------------------------------
// 0b) Conv weight cast
// ---------------------------------------------------------------------------
__global__ __launch_bounds__(256) void wcv_cast_kernel(
    const float* __restrict__ wf3, const float* __restrict__ wg3,
    const float* __restrict__ wf5, const float* __restrict__ wg5,
    const float* __restrict__ wf7, const float* __restrict__ wg7,
    __hip_bfloat16* __restrict__ wcv) {
  int idx = blockIdx.x * 256 + threadIdx.x;
  if (idx >= 3 * 512 * WKMAX) return;
  int j = idx / (512 * WKMAX);
  int rem = idx - j * 512 * WKMAX;
  int n = rem / WKMAX, k = rem % WKMAX;
  int Kw = 3 + 2 * j;
  float v = 0.f;
  if (k < Kw * 64) {
    const float* src = (n < 256) ? (j == 0 ? wf3 : j == 1 ? wf5 : wf7)
                                 : (j == 0 ? wg3 : j == 1 ? wg5 : wg7);
    v = src[(size_t)k * 256 + (n & 255)];
  }
  wcv[idx] = __float2bfloat16(v);
}

// 0c) x cast fp32 -> bf16
__global__ __launch_bounds__(256) void x_cast_kernel(
    const float* __restrict__ x, short* __restrict__ x16, int n8) {
  int idx = blockIdx.x * 256 + threadIdx.x;
  if (idx >= n8) return;
  const float4 a = ((const float4*)x)[idx * 2];
  const float4 b = ((const float4*)x)[idx * 2 + 1];
  short8 o;
  o[0] = bf16s(a.x); o[1] = bf16s(a.y); o[2] = bf16s(a.z); o[3] = bf16s(a.w);
  o[4] = bf16s(b.x); o[5] = bf16s(b.y); o[6] = bf16s(b.z); o[7] = bf16s(b.w);
  ((short8*)x16)[idx] = o;
}

// ---------------------------------------------------------------------------
// 1) Conv as implicit GEMM (unchanged)
// ---------------------------------------------------------------------------
__global__ __launch_bounds__(256) void conv_gemm_kernel(
    const short* __restrict__ x16, const short* __restrict__ wcv,
    short* __restrict__ yraw, int b0) {
  __shared__ __align__(16) short Asl[128 * 72];
  __shared__ __align__(16) short Bsl[128 * 72];
  const int t0 = blockIdx.x * 128, n0 = blockIdx.y * 128;
  const int bl = blockIdx.z / 3, j = blockIdx.z % 3;
  const int Kw = 3 + 2 * j, pad = j + 1;
  const int bglob = b0 + bl;
  const short* wb = wcv + (size_t)j * 512 * WKMAX;
  const int tid = threadIdx.x;
  const int lane = tid & 63;
  const int w = tid >> 6, wm = w >> 1, wn = w & 1;
  const int lm = lane & 15, quad = lane >> 4;

  floatx4 acc[4][4];
#pragma unroll
  for (int i = 0; i < 4; i++)
#pragma unroll
    for (int jj = 0; jj < 4; jj++) acc[i][jj] = (floatx4)0.f;

  for (int kk = 0; kk < Kw; kk++) {
    __syncthreads();
#pragma unroll
    for (int it = 0; it < 4; it++) {
      int s = it * 256 + tid;
      int row = s >> 3, c8 = s & 7;
      int t = t0 + row + kk - pad;
      short8 av = (short8)0;
      if (t >= 0 && t < Tt)
        av = *(const short8*)&x16[((size_t)bglob * Tt + t) * Ff + c8 * 8];
      *(short8*)&Asl[row * 72 + c8 * 8] = av;
      short8 bv = *(const short8*)&wb[(size_t)(n0 + row) * WKMAX + kk * 64 +
                                      c8 * 8];
      *(short8*)&Bsl[row * 72 + c8 * 8] = bv;
    }
    __syncthreads();
#pragma unroll
    for (int ks = 0; ks < 2; ks++) {
      short8 a[4], b[4];
#pragma unroll
      for (int i = 0; i < 4; i++)
        a[i] = *(const short8*)&Asl[(wm * 64 + i * 16 + lm) * 72 + ks * 32 +
                                    quad * 8];
#pragma unroll
      for (int jj = 0; jj < 4; jj++)
        b[jj] = *(const short8*)&Bsl[(wn * 64 + jj * 16 + lm) * 72 + ks * 32 +
                                     quad * 8];
#pragma unroll
      for (int i = 0; i < 4; i++)
#pragma unroll
        for (int jj = 0; jj < 4; jj++)
          acc[i][jj] = __builtin_amdgcn_mfma_f32_16x16x32_bf16(a[i], b[jj],
                                                               acc[i][jj],
                                                               0, 0, 0);
    }
  }

  const int rbase = quad * 4;
#pragma unroll
  for (int i = 0; i < 4; i++)
#pragma unroll
    for (int jj = 0; jj < 4; jj++) {
      int mrow = t0 + wm * 64 + i * 16 + rbase;
      int ncol = n0 + wn * 64 + jj * 16 + lm;
#pragma unroll
      for (int r = 0; r < 4; r++)
        yraw[((size_t)bl * Tt + mrow + r) * 1536 + j * 512 + ncol] =
            bf16s(acc[i][jj][r]);
    }
}

// ---------------------------------------------------------------------------
// 2) Fused gate + LayerNorm (unchanged)
// ---------------------------------------------------------------------------
__global__ __launch_bounds__(256) void gate_ln_kernel(
    const short* __restrict__ yraw, float* __restrict__ h,
    __hip_bfloat16* __restrict__ h16, const float* __restrict__ bf3,
    const float* __restrict__ bg3, const float* __restrict__ bf5,
    const float* __restrict__ bg5, const float* __restrict__ bf7,
    const float* __restrict__ bg7, const float* __restrict__ g,
    const float* __restrict__ bt) {
  __shared__ float red[8];
  const size_t row = blockIdx.x;
  float v[3], s = 0.f, ss = 0.f;
#pragma unroll
  for (int jj = 0; jj < 3; jj++) {
    int c = threadIdx.x + jj * 256;
    int br = c >> 8, cc = c & 255;
    const float* bfp = br == 0 ? bf3 : br == 1 ? bf5 : bf7;
    const float* bgp = br == 0 ? bg3 : br == 1 ? bg5 : bg7;
    __hip_bfloat16 rf = *(const __hip_bfloat16*)&yraw[row * 1536 + br * 512 + cc];
    __hip_bfloat16 rg =
        *(const __hip_bfloat16*)&yraw[row * 1536 + br * 512 + 256 + cc];
    float f = __bfloat162float(rf) + bfp[cc];
    float gt = __bfloat162float(rg) + bgp[cc];
    float a = f > 0.f ? f : 0.f;
    float t = a * (1.f / (1.f + __expf(-gt)));
    v[jj] = t; s += t; ss += t * t;
  }
  float2 r = block_reduce2(s, ss, red);
  float mu = r.x * (1.f / Hh);
  float var = r.y * (1.f / Hh) - mu * mu;
  float rs = rsqrtf(var + EPS);
#pragma unroll
  for (int jj = 0; jj < 3; jj++) {
    int c = threadIdx.x + jj * 256;
    float o = (v[jj] - mu) * rs * g[c] + bt[c];
    h[row * Hh + c] = o;
    h16[row * Hh + c] = __float2bfloat16(o);
  }
}

// residual LN: h = LN(h + y(bf16) + bp), emit fp32 + bf16
__global__ __launch_bounds__(256) void res_ln_kernel(
    float* __restrict__ h, __hip_bfloat16* __restrict__ h16,
    const __hip_bfloat16* __restrict__ y, const float* __restrict__ bp,
    const float* __restrict__ g, const float* __restrict__ bt) {
  __shared__ float red[8];
  const size_t row = blockIdx.x;
  float v[3], s = 0.f, ss = 0.f;
#pragma unroll
  for (int jj = 0; jj < 3; jj++) {
    int c = threadIdx.x + jj * 256;
    float t = h[row * Hh + c] + __bfloat162float(y[row * Hh + c]) + bp[c];
    v[jj] = t; s += t; ss += t * t;
  }
  float2 r = block_reduce2(s, ss, red);
  float mu = r.x * (1.f / Hh);
  float var = r.y * (1.f / Hh) - mu * mu;
  float rs = rsqrtf(var + EPS);
#pragma unroll
  for (int jj = 0; jj < 3; jj++) {
    int c = threadIdx.x + jj * 256;
    float o = (v[jj] - mu) * rs * g[c] + bt[c];
    h[row * Hh + c] = o;
    h16[row * Hh + c] = __float2bfloat16(o);
  }
}

// ---------------------------------------------------------------------------
// 3a) Fused QKV GEMM (unchanged)
// ---------------------------------------------------------------------------
__global__ __launch_bounds__(256) void gemm_qkv(
    const short* __restrict__ A, const short* __restrict__ Bt,
    short* __restrict__ q16, short* __restrict__ k16,
    short* __restrict__ vt16) {
  constexpr int K = 768;
  __shared__ __align__(16) short Asl[128 * 32];
  __shared__ __align__(16) short Bsl[128 * 32];
  const int n0 = blockIdx.x * 128, m0 = blockIdx.y * 128;
  const int lane = threadIdx.x & 63;
  const int w = threadIdx.x >> 6, wm = w >> 1, wn = w & 1;
  const int lm = lane & 15, quad = lane >> 4;

  floatx4 acc[4][4];
#pragma unroll
  for (int i = 0; i < 4; i++)
#pragma unroll
    for (int jj = 0; jj < 4; jj++) acc[i][jj] = (floatx4)0.f;

  for (int k0 = 0; k0 < K; k0 += 32) {
    __syncthreads();
#pragma unroll
    for (int half = 0; half < 2; half++) {
      int s = half * 256 + threadIdx.x;
      int m = s >> 2, ks = (s & 3) * 8;
      async_copy16(&A[(size_t)(m0 + m) * K + k0 + ks], &Asl[s * 8]);
      async_copy16(&Bt[(size_t)(n0 + m) * K + k0 + ks], &Bsl[s * 8]);
    }
    __syncthreads();

    short8 a[4], b[4];
#pragma unroll
    for (int i = 0; i < 4; i++)
      a[i] = *(const short8*)&Asl[(wm * 64 + i * 16 + lm) * 32 + quad * 8];
#pragma unroll
    for (int jj = 0; jj < 4; jj++)
      b[jj] = *(const short8*)&Bsl[(wn * 64 + jj * 16 + lm) * 32 + quad * 8];
#pragma unroll
    for (int i = 0; i < 4; i++)
#pragma unroll
      for (int jj = 0; jj < 4; jj++)
        acc[i][jj] = __builtin_amdgcn_mfma_f32_16x16x32_bf16(a[i], b[jj],
                                                             acc[i][jj],
                                                             0, 0, 0);
  }

  const int which = blockIdx.x / 6;  // 0:q 1:k 2:v
  const int rbase = quad * 4;
#pragma unroll
  for (int i = 0; i < 4; i++)
#pragma unroll
    for (int jj = 0; jj < 4; jj++) {
      int mrow = m0 + wm * 64 + i * 16 + rbase;
      int nl = n0 - which * Hh + wn * 64 + jj * 16 + lm;
      if (which == 0) {
#pragma unroll
        for (int r = 0; r < 4; r++)
          q16[(size_t)(mrow + r) * Hh + nl] = bf16s(acc[i][jj][r]);
      } else if (which == 1) {
#pragma unroll
        for (int r = 0; r < 4; r++)
          k16[(size_t)(mrow + r) * Hh + nl] = bf16s(acc[i][jj][r]);
      } else {
        int bL = mrow >> 10, t = mrow & 1023;
        int g = nl / Dd, d = nl % Dd;
        short4 sv;
        sv.x = bf16s(acc[i][jj][0]); sv.y = bf16s(acc[i][jj][1]);
        sv.z = bf16s(acc[i][jj][2]); sv.w = bf16s(acc[i][jj][3]);
        *(short4*)&vt16[(((size_t)bL * Gg + g) * Dd + d) * Tt + t] = sv;
      }
    }
}

// 3b) Proj GEMM: bf16 out [tok][768] (unchanged)
__global__ __launch_bounds__(256) void gemm_proj(
    const short* __restrict__ A, const short* __restrict__ Bt,
    short* __restrict__ C) {
  constexpr int K = 768, N = 768;
  __shared__ __align__(16) short Asl[128 * 32];
  __shared__ __align__(16) short Bsl[128 * 32];
  const int n0 = blockIdx.x * 128, m0 = blockIdx.y * 128;
  const int lane = threadIdx.x & 63;
  const int w = threadIdx.x >> 6, wm = w >> 1, wn = w & 1;
  const int lm = lane & 15, quad = lane >> 4;

  floatx4 acc[4][4];
#pragma unroll
  for (int i = 0; i < 4; i++)
#pragma unroll
    for (int jj = 0; jj < 4; jj++) acc[i][jj] = (floatx4)0.f;

  for (int k0 = 0; k0 < K; k0 += 32) {
    __syncthreads();
#pragma unroll
    for (int half = 0; half < 2; half++) {
      int s = half * 256 + threadIdx.x;
      int m = s >> 2, ks = (s & 3) * 8;
      async_copy16(&A[(size_t)(m0 + m) * K + k0 + ks], &Asl[s * 8]);
      async_copy16(&Bt[(size_t)(n0 + m) * K + k0 + ks], &Bsl[s * 8]);
    }
    __syncthreads();

    short8 a[4], b[4];
#pragma unroll
    for (int i = 0; i < 4; i++)
      a[i] = *(const short8*)&Asl[(wm * 64 + i * 16 + lm) * 32 + quad * 8];
#pragma unroll
    for (int jj = 0; jj < 4; jj++)
      b[jj] = *(const short8*)&Bsl[(wn * 64 + jj * 16 + lm) * 32 + quad * 8];
#pragma unroll
    for (int i = 0; i < 4; i++)
#pragma unroll
      for (int jj = 0; jj < 4; jj++)
        acc[i][jj] = __builtin_amdgcn_mfma_f32_16x16x32_bf16(a[i], b[jj],
                                                             acc[i][jj],
                                                             0, 0, 0);
  }

  const int rbase = quad * 4;
#pragma unroll
  for (int i = 0; i < 4; i++)
#pragma unroll
    for (int jj = 0; jj < 4; jj++) {
      int mrow = m0 + wm * 64 + i * 16 + rbase;
      int ncol = n0 + wn * 64 + jj * 16 + lm;
#pragma unroll
      for (int r = 0; r < 4; r++)
        C[(size_t)(mrow + r) * N + ncol] = bf16s(acc[i][jj][r]);
    }
}

// ---------------------------------------------------------------------------
// 4) MFMA flash attention, S^T formulation + pipelined staging (unchanged)
// ---------------------------------------------------------------------------
__global__ __launch_bounds__(256, 2) void attn_mfma(
    const short* __restrict__ q16, const short* __restrict__ k16,
    const short* __restrict__ vt16, short* __restrict__ o16) {
  const int b = blockIdx.x;
  const int g = blockIdx.y;
  const int q0 = blockIdx.z * 128;
  const int tid = threadIdx.x;
  const int w = tid >> 6, lane = tid & 63, lm = lane & 15, quad = lane >> 4;

  __shared__ __align__(16) short Ks[32 * 200];   // [kk][d], stride 200
  __shared__ __align__(16) short Vt[192 * VTS];  // [d][kk], stride 40

  short8 qf[2][6];
#pragma unroll
  for (int mt = 0; mt < 2; mt++)
#pragma unroll
    for (int ks = 0; ks < 6; ks++) {
      int tok = b * Tt + q0 + w * 32 + mt * 16 + lm;
      qf[mt][ks] = *(const short8*)&q16[(size_t)tok * Hh + g * Dd + ks * 32 +
                                        quad * 8];
    }

  floatx4 Oa[2][12];
#pragma unroll
  for (int mt = 0; mt < 2; mt++)
#pragma unroll
    for (int n = 0; n < 12; n++) Oa[mt][n] = (floatx4)0.f;
  float mr[2] = {-1e30f, -1e30f}, lr[2] = {0.f, 0.f};

  short8 kvK[3], kvV[3];
#pragma unroll
  for (int it = 0; it < 3; it++) {
    int s = it * 256 + tid;
    int row = s / 24, cs = s - row * 24;
    kvK[it] = *(const short8*)&k16[(size_t)(b * Tt + row) * Hh + g * Dd +
                                   cs * 8];
    int d = s >> 2, c2 = s & 3;
    kvV[it] = *(const short8*)&vt16[(((size_t)b * Gg + g) * Dd + d) * Tt +
                                    c2 * 8];
  }

  for (int kt = 0; kt < Tt; kt += 32) {
    __syncthreads();
#pragma unroll
    for (int it = 0; it < 3; it++) {
      int s = it * 256 + tid;
      int row = s / 24, cs = s - row * 24;
      *(short8*)&Ks[row * 200 + cs * 8] = kvK[it];
      int d = s >> 2, c2 = s & 3;
      *(short8*)&Vt[d * VTS + c2 * 8] = kvV[it];
    }
    __syncthreads();

    if (kt + 32 < Tt) {
#pragma unroll
      for (int it = 0; it < 3; it++) {
        int s = it * 256 + tid;
        int row = s / 24, cs = s - row * 24;
        kvK[it] = *(const short8*)&k16[(size_t)(b * Tt + kt + 32 + row) * Hh +
                                       g * Dd + cs * 8];
        int d = s >> 2, c2 = s & 3;
        kvV[it] = *(const short8*)&vt16[(((size_t)b * Gg + g) * Dd + d) * Tt +
                                        kt + 32 + c2 * 8];
      }
    }

    floatx4 st[2][2];
#pragma unroll
    for (int mt = 0; mt < 2; mt++)
#pragma unroll
      for (int jj = 0; jj < 2; jj++) st[mt][jj] = (floatx4)0.f;
#pragma unroll
    for (int ks = 0; ks < 6; ks++) {
      short8 k0 = *(const short8*)&Ks[lm * 200 + ks * 32 + quad * 8];
      short8 k1 = *(const short8*)&Ks[(16 + lm) * 200 + ks * 32 + quad * 8];
      st[0][0] = __builtin_amdgcn_mfma_f32_16x16x32_bf16(k0, qf[0][ks], st[0][0], 0, 0, 0);
      st[0][1] = __builtin_amdgcn_mfma_f32_16x16x32_bf16(k1, qf[0][ks], st[0][1], 0, 0, 0);
      st[1][0] = __builtin_amdgcn_mfma_f32_16x16x32_bf16(k0, qf[1][ks], st[1][0], 0, 0, 0);
      st[1][1] = __builtin_amdgcn_mfma_f32_16x16x32_bf16(k1, qf[1][ks], st[1][1], 0, 0, 0);
    }

    short8 ptf[2];
#pragma unroll
    for (int mt = 0; mt < 2; mt++) {
      float smax = st[mt][0][0];
#pragma unroll
      for (int r = 1; r < 4; r++) smax = fmaxf(smax, st[mt][0][r]);
#pragma unroll
      for (int r = 0; r < 4; r++) smax = fmaxf(smax, st[mt][1][r]);
      smax = fmaxf(smax, __shfl_xor(smax, 16));
      smax = fmaxf(smax, __shfl_xor(smax, 32));
      float mnew = fmaxf(mr[mt], smax);
      float alpha = __expf(mr[mt] - mnew);
      mr[mt] = mnew;
      float p[2][4];
      float sum = 0.f;
#pragma unroll
      for (int jj = 0; jj < 2; jj++)
#pragma unroll
        for (int r = 0; r < 4; r++) {
          p[jj][r] = __expf(st[mt][jj][r] - mnew);
          sum += p[jj][r];
        }
      sum += __shfl_xor(sum, 16);
      sum += __shfl_xor(sum, 32);
      lr[mt] = lr[mt] * alpha + sum;

      int pk00 = (int)pack_bf16(p[0][0], p[0][1]);
      int pk01 = (int)pack_bf16(p[0][2], p[0][3]);
      int pk10 = (int)pack_bf16(p[1][0], p[1][1]);
      int pk11 = (int)pack_bf16(p[1][2], p[1][3]);
      int srcA = ((quad & 1) << 5) + lm;
      int srcB = srcA + 16;
      int a0 = __shfl(pk00, srcA), a1 = __shfl(pk01, srcA);
      int a2 = __shfl(pk00, srcB), a3 = __shfl(pk01, srcB);
      int b0 = __shfl(pk10, srcA), b1 = __shfl(pk11, srcA);
      int b2 = __shfl(pk10, srcB), b3 = __shfl(pk11, srcB);
      bool hi = quad >= 2;
      union { int u[4]; short8 v; } pu;
      pu.u[0] = hi ? b0 : a0;
      pu.u[1] = hi ? b1 : a1;
      pu.u[2] = hi ? b2 : a2;
      pu.u[3] = hi ? b3 : a3;
      ptf[mt] = pu.v;

#pragma unroll
      for (int n = 0; n < 12; n++)
#pragma unroll
        for (int r = 0; r < 4; r++) Oa[mt][n][r] *= alpha;
    }

#pragma unroll
    for (int n = 0; n < 12; n++) {
      short8 vf = *(const short8*)&Vt[(n * 16 + lm) * VTS + quad * 8];
      Oa[0][n] = __builtin_amdgcn_mfma_f32_16x16x32_bf16(vf, ptf[0], Oa[0][n], 0, 0, 0);
      Oa[1][n] = __builtin_amdgcn_mfma_f32_16x16x32_bf16(vf, ptf[1], Oa[1][n], 0, 0, 0);
    }
  }

#pragma unroll
  for (int mt = 0; mt < 2; mt++) {
    float inv = 1.f / lr[mt];
    int tok = b * Tt + q0 + w * 32 + mt * 16 + lm;
#pragma unroll
    for (int n = 0; n < 12; n++) {
      short4 sv;
      sv.x = bf16s(Oa[mt][n][0] * inv);
      sv.y = bf16s(Oa[mt][n][1] * inv);
      sv.z = bf16s(Oa[mt][n][2] * inv);
      sv.w = bf16s(Oa[mt][n][3] * inv);
      *(short4*)&o16[(size_t)tok * Hh + g * Dd + n * 16 + quad * 4] = sv;
    }
  }
}

// ---------------------------------------------------------------------------
// 5) Pool, two-stage (unchanged)
// ---------------------------------------------------------------------------
__global__ __launch_bounds__(256) void pool_stage1(const float* __restrict__ h,
                                                   float* __restrict__ ppart,
                                                   int b0) {
  int idx = blockIdx.x * 256 + threadIdx.x;
  int seg = blockIdx.y;
  int bl = idx / Hh, c = idx % Hh;
  float s = 0.f, ss = 0.f;
  const float* hp = &h[((size_t)bl * Tt + seg * 128) * Hh + c];
  for (int t = 0; t < 128; t++) {
    float v = hp[(size_t)t * Hh];
    s += v; ss += v * v;
  }
  float* o = &ppart[(((size_t)(b0 + bl) * 8 + seg) * 2) * Hh + c];
  o[0] = s;
  o[Hh] = ss;
}

__global__ __launch_bounds__(256) void pool_stage2(
    const float* __restrict__ ppart, float* __restrict__ pool) {
  int idx = blockIdx.x * 256 + threadIdx.x;
  int b = idx / Hh, c = idx % Hh;
  float s = 0.f, ss = 0.f;
#pragma unroll
  for (int seg = 0; seg < 8; seg++) {
    const float* o = &ppart[(((size_t)b * 8 + seg) * 2) * Hh + c];
    s += o[0]; ss += o[Hh];
  }
  float mu = s * (1.f / Tt);
  float var = ss * (1.f / Tt) - mu * mu;
  pool[(size_t)b * 1536 + c] = mu;
  pool[(size_t)b * 1536 + 768 + c] = sqrtf(fmaxf(var, 0.f));
}

// ---------------------------------------------------------------------------
// 6) Final projection, split-K two-stage.
//    6a: partial[ks][b][n] = sum_{k in slice ks} pool[b][k] * pw[k][n]
//        grid (3 n-blocks of 256, 8 b-groups of 4, 8 k-slices of 192).
//    6b: combine 8 partials + bias -> LN -> relu -> out. one block per b.
// ---------------------------------------------------------------------------
__global__ __launch_bounds__(256) void final_partial(
    const float* __restrict__ pool, const float* __restrict__ pw,
    float* __restrict__ part) {
  const int n = blockIdx.x * 256 + threadIdx.x;
  const int bg = blockIdx.y * 4;
  const int ks = blockIdx.z, k0 = ks * 192;
  __shared__ float ms[4][192];
  for (int e = threadIdx.x; e < 4 * 192; e += 256) {
    int bb = e / 192, kk = e % 192;
    ms[bb][kk] = pool[(size_t)(bg + bb) * 1536 + k0 + kk];
  }
  __syncthreads();
  float a0 = 0.f, a1 = 0.f, a2 = 0.f, a3 = 0.f;
  for (int kk = 0; kk < 192; kk++) {
    float wv = pw[(size_t)(k0 + kk) * Hh + n];
    a0 = fmaf(ms[0][kk], wv, a0);
    a1 = fmaf(ms[1][kk], wv, a1);
    a2 = fmaf(ms[2][kk], wv, a2);
    a3 = fmaf(ms[3][kk], wv, a3);
  }
  part[((size_t)ks * Bb + bg + 0) * Hh + n] = a0;
  part[((size_t)ks * Bb + bg + 1) * Hh + n] = a1;
  part[((size_t)ks * Bb + bg + 2) * Hh + n] = a2;
  part[((size_t)ks * Bb + bg + 3) * Hh + n] = a3;
}

__global__ __launch_bounds__(256) void final_stage2(
    const float* __restrict__ part, const float* __restrict__ pb,
    const float* __restrict__ g, const float* __restrict__ bt,
    float* __restrict__ out) {
  __shared__ float red[8];
  const int b = blockIdx.x;
  float v[3], s = 0.f, ss = 0.f;
#pragma unroll
  for (int jj = 0; jj < 3; jj++) {
    int n = threadIdx.x + jj * 256;
    float a = pb[n];
#pragma unroll
    for (int ks = 0; ks < 8; ks++) a += part[((size_t)ks * Bb + b) * Hh + n];
    v[jj] = a; s += a; ss += a * a;
  }
  float2 r = block_reduce2(s, ss, red);
  float mu = r.x * (1.f / Hh);
  float var = r.y * (1.f / Hh) - mu * mu;
  float rs = rsqrtf(var + EPS);
#pragma unroll
  for (int jj = 0; jj < 3; jj++) {
    int n = threadIdx.x + jj * 256;
    float o = (v[jj] - mu) * rs * g[n] + bt[n];
    out[(size_t)b * Hh + n] = o > 0.f ? o : 0.f;
  }
}

// ---------------------------------------------------------------------------
extern "C" void kernel_launch(void* const* d_in, const int* in_sizes, int n_in,
                              void* d_out, int out_size, void* d_ws,
                              size_t ws_size, hipStream_t stream) {
  (void)in_sizes; (void)n_in; (void)out_size;
  const float* x = (const float*)d_in[0];
  const float* cw[3][4];
  for (int j = 0; j < 3; j++)
    for (int p2 = 0; p2 < 4; p2++) cw[j][p2] = (const float*)d_in[1 + j * 4 + p2];
  const float* conv_ln_g = (const float*)d_in[13];
  const float* conv_ln_b = (const float*)d_in[14];
  const float* wq = (const float*)d_in[15];
  const float* wk = (const float*)d_in[16];
  const float* wv = (const float*)d_in[17];
  const float* wp = (const float*)d_in[18];
  const float* bp = (const float*)d_in[19];
  const float* lng = (const float*)d_in[20];
  const float* lnb = (const float*)d_in[21];
  const float* proj_w = (const float*)d_in[22];
  const float* proj_b = (const float*)d_in[23];
  const float* proj_ln_g = (const float*)d_in[24];
  const float* proj_ln_b = (const float*)d_in[25];
  float* out = (float*)d_out;

  // --- workspace ----------------------------------------------------------
  const size_t perb = (size_t)Tt * Hh;
  const size_t fixedB = 8ull * Hh * Hh * 2 + 3ull * 512 * WKMAX * 2 +
                        (size_t)Bb * Tt * Ff * 2 + (size_t)Bb * 2 * Hh * 4 +
                        (size_t)Bb * 8 * 2 * Hh * 4 +
                        8ull * Bb * Hh * 4;  // + final partials
  int chunk = Bb;
  while (chunk > 1 && 16ull * perb * chunk + fixedB > ws_size) chunk >>= 1;

  const size_t crow = perb * (size_t)chunk;
  char* p = (char*)d_ws;
  float* h = (float*)p;              p += crow * 4;
  short* yraw16 = (short*)p;         // union: conv raw (bf16) / proj out y16
  short* y16 = yraw16;               p += crow * 4;
  __hip_bfloat16* h16 = (__hip_bfloat16*)p;  p += crow * 2;
  short* q16 = (short*)p;            p += crow * 2;
  short* k16 = (short*)p;            p += crow * 2;
  short* v16t = (short*)p;           p += crow * 2;
  __hip_bfloat16* wt = (__hip_bfloat16*)p;   p += 8ull * Hh * Hh * 2;
  __hip_bfloat16* wcv = (__hip_bfloat16*)p;  p += 3ull * 512 * WKMAX * 2;
  short* x16 = (short*)p;            p += (size_t)Bb * Tt * Ff * 2;
  float* pool = (float*)p;           p += (size_t)Bb * 2 * Hh * 4;
  float* ppart = (float*)p;          p += (size_t)Bb * 8 * 2 * Hh * 4;
  float* fpart = (float*)p;

  // one-time casts
  wt_cast_kernel<<<dim3(24, 24, 8), 256, 0, stream>>>(wq, wk, wv, wp, wt);
  wcv_cast_kernel<<<(3 * 512 * WKMAX + 255) / 256, 256, 0, stream>>>(
      cw[0][0], cw[0][2], cw[1][0], cw[1][2], cw[2][0], cw[2][2], wcv);
  x_cast_kernel<<<(Bb * Tt * Ff / 8 + 255) / 256, 256, 0, stream>>>(
      x, x16, Bb * Tt * Ff / 8);

  const short* wts = (const short*)wt;

  for (int b0 = 0; b0 < Bb; b0 += chunk) {
    const int M = chunk * Tt;

    conv_gemm_kernel<<<dim3(Tt / 128, 4, chunk * 3), 256, 0, stream>>>(
        x16, (const short*)wcv, yraw16, b0);
    gate_ln_kernel<<<M, 256, 0, stream>>>(
        yraw16, h, h16, cw[0][1], cw[0][3], cw[1][1], cw[1][3], cw[2][1],
        cw[2][3], conv_ln_g, conv_ln_b);

    for (int i = 0; i < 2; i++) {
      const short* wqkv = wts + (size_t)(i * 4) * Hh * Hh;
      const short* wtp = wts + (size_t)(i * 4 + 3) * Hh * Hh;
      gemm_qkv<<<dim3(18, M / 128), 256, 0, stream>>>((const short*)h16, wqkv,
                                                      q16, k16, v16t);
      attn_mfma<<<dim3(chunk, Gg, Tt / 128), 256, 0, stream>>>(q16, k16, v16t,
                                                               q16);
      gemm_proj<<<dim3(6, M / 128), 256, 0, stream>>>(q16, wtp, y16);
      res_ln_kernel<<<M, 256, 0, stream>>>(h, h16, (const __hip_bfloat16*)y16,
                                           bp + (size_t)i * Hh,
                                           lng + (size_t)i * Hh,
                                           lnb + (size_t)i * Hh);
    }

    pool_stage1<<<dim3((chunk * Hh) / 256, 8), 256, 0, stream>>>(h, ppart, b0);
  }

  pool_stage2<<<(Bb * Hh) / 256, 256, 0, stream>>>(ppart, pool);
  final_partial<<<dim3(3, 8, 8), 256, 0, stream>>>(pool, proj_w, fpart);
  final_stage2<<<Bb, 256, 0, stream>>>(fpart, proj_b, proj_ln_g, proj_ln_b,
                                       out);
}

// Round 9
// 1066.469 us; speedup vs baseline: 10.5016x; 1.0866x over previous
//
#include <hip/hip_runtime.h>
#include <hip/hip_bf16.h>

// ---------------------------------------------------------------------------
// TemporalExtractor round 9:
//   - workspace footprint 16 -> 8 B/element: residual h carried in bf16 only
//     (no fp32 h), proj output y16 unioned into k16 (dead after attn), conv
//     yraw unioned into q16||k16 (dead after gate_ln).
//     => chunk 8 -> 16 within the same 118 MB budget: 2 passes instead of 4,
//     attn concurrency 1 -> 2 blocks/CU, half the attn dispatches.
//   - attn / GEMM kernels unchanged (one structural change per round).
// ---------------------------------------------------------------------------

constexpr int Bb = 32, Tt = 1024, Ff = 64, Hh = 768, Gg = 4, Dd = 192;
constexpr float EPS = 1e-5f;
constexpr int WKMAX = 448;  // padded conv-weight K stride (7*64)
constexpr int VTS = 40;     // Vt LDS row stride in shorts

typedef __attribute__((ext_vector_type(8))) short short8;   // 8 bf16 = 4 VGPRs
typedef __attribute__((ext_vector_type(4))) float floatx4;  // MFMA acc

__device__ __forceinline__ void async_copy16(const void* g, void* l) {
  __builtin_amdgcn_global_load_lds(
      (const __attribute__((address_space(1))) unsigned int*)g,
      (__attribute__((address_space(3))) unsigned int*)l, 16, 0, 0);
}

__device__ __forceinline__ short bf16s(float f) {
  __hip_bfloat16 h = __float2bfloat16(f);
  return *(short*)&h;
}

__device__ __forceinline__ unsigned int pack_bf16(float lo, float hi) {
  return (unsigned int)(unsigned short)bf16s(lo) |
         ((unsigned int)(unsigned short)bf16s(hi) << 16);
}

__device__ __forceinline__ float2 block_reduce2(float a, float b, float* tmp) {
  int lane = threadIdx.x & 63, wid = threadIdx.x >> 6;
#pragma unroll
  for (int off = 32; off > 0; off >>= 1) {
    a += __shfl_down(a, off);
    b += __shfl_down(b, off);
  }
  if (lane == 0) { tmp[wid] = a; tmp[4 + wid] = b; }
  __syncthreads();
  if (threadIdx.x == 0) {
    tmp[0] = tmp[0] + tmp[1] + tmp[2] + tmp[3];
    tmp[4] = tmp[4] + tmp[5] + tmp[6] + tmp[7];
  }
  __syncthreads();
  float2 r; r.x = tmp[0]; r.y = tmp[4];
  return r;
}

// ---------------------------------------------------------------------------
// 0a) Attn/proj weight transpose+cast (Q pre-scaled by 192^-0.5)
// ---------------------------------------------------------------------------
__global__ __launch_bounds__(256) void wt_cast_kernel(
    const float* __restrict__ wq, const float* __restrict__ wk,
    const float* __restrict__ wv, const float* __restrict__ wp,
    __hip_bfloat16* __restrict__ wt) {
  const int z = blockIdx.z;
  const int m = z & 3, i = z >> 2;
  const float* src =
      (m == 0 ? wq : m == 1 ? wk : m == 2 ? wv : wp) + (size_t)i * Hh * Hh;
  const float sc = (m == 0) ? 0.0721687836f : 1.f;
  __shared__ float tile[32][33];
  const int n0 = blockIdx.x * 32, k0 = blockIdx.y * 32;
  const int tx = threadIdx.x & 31, ty = threadIdx.x >> 5;
#pragma unroll
  for (int r = 0; r < 4; r++)
    tile[ty + 8 * r][tx] = src[(size_t)(k0 + ty + 8 * r) * Hh + n0 + tx];
  __syncthreads();
#pragma unroll
  for (int r = 0; r < 4; r++)
    wt[((size_t)z * Hh + n0 + ty + 8 * r) * Hh + k0 + tx] =
        __float2bfloat16(tile[tx][ty + 8 * r] * sc);
}

// ---------------------------------------------------------------------------
// 0b) Conv weight cast
// ---------------------------------------------------------------------------
__global__ __launch_bounds__(256) void wcv_cast_kernel(
    const float* __restrict__ wf3, const float* __restrict__ wg3,
    const float* __restrict__ wf5, const float* __restrict__ wg5,
    const float* __restrict__ wf7, const float* __restrict__ wg7,
    __hip_bfloat16* __restrict__ wcv) {
  int idx = blockIdx.x * 256 + threadIdx.x;
  if (idx >= 3 * 512 * WKMAX) return;
  int j = idx / (512 * WKMAX);
  int rem = idx - j * 512 * WKMAX;
  int n = rem / WKMAX, k = rem % WKMAX;
  int Kw = 3 + 2 * j;
  float v = 0.f;
  if (k < Kw * 64) {
    const float* src = (n < 256) ? (j == 0 ? wf3 : j == 1 ? wf5 : wf7)
                                 : (j == 0 ? wg3 : j == 1 ? wg5 : wg7);
    v = src[(size_t)k * 256 + (n & 255)];
  }
  wcv[idx] = __float2bfloat16(v);
}

// 0c) x cast fp32 -> bf16
__global__ __launch_bounds__(256) void x_cast_kernel(
    const float* __restrict__ x, short* __restrict__ x16, int n8) {
  int idx = blockIdx.x * 256 + threadIdx.x;
  if (idx >= n8) return;
  const float4 a = ((const float4*)x)[idx * 2];
  const float4 b = ((const float4*)x)[idx * 2 + 1];
  short8 o;
  o[0] = bf16s(a.x); o[1] = bf16s(a.y); o[2] = bf16s(a.z); o[3] = bf16s(a.w);
  o[4] = bf16s(b.x); o[5] = bf16s(b.y); o[6] = bf16s(b.z); o[7] = bf16s(b.w);
  ((short8*)x16)[idx] = o;
}

// ---------------------------------------------------------------------------
// 1) Conv as implicit GEMM (unchanged)
// ---------------------------------------------------------------------------
__global__ __launch_bounds__(256) void conv_gemm_kernel(
    const short* __restrict__ x16, const short* __restrict__ wcv,
    short* __restrict__ yraw, int b0) {
  __shared__ __align__(16) short Asl[128 * 72];
  __shared__ __align__(16) short Bsl[128 * 72];
  const int t0 = blockIdx.x * 128, n0 = blockIdx.y * 128;
  const int bl = blockIdx.z / 3, j = blockIdx.z % 3;
  const int Kw = 3 + 2 * j, pad = j + 1;
  const int bglob = b0 + bl;
  const short* wb = wcv + (size_t)j * 512 * WKMAX;
  const int tid = threadIdx.x;
  const int lane = tid & 63;
  const int w = tid >> 6, wm = w >> 1, wn = w & 1;
  const int lm = lane & 15, quad = lane >> 4;

  floatx4 acc[4][4];
#pragma unroll
  for (int i = 0; i < 4; i++)
#pragma unroll
    for (int jj = 0; jj < 4; jj++) acc[i][jj] = (floatx4)0.f;

  for (int kk = 0; kk < Kw; kk++) {
    __syncthreads();
#pragma unroll
    for (int it = 0; it < 4; it++) {
      int s = it * 256 + tid;
      int row = s >> 3, c8 = s & 7;
      int t = t0 + row + kk - pad;
      short8 av = (short8)0;
      if (t >= 0 && t < Tt)
        av = *(const short8*)&x16[((size_t)bglob * Tt + t) * Ff + c8 * 8];
      *(short8*)&Asl[row * 72 + c8 * 8] = av;
      short8 bv = *(const short8*)&wb[(size_t)(n0 + row) * WKMAX + kk * 64 +
                                      c8 * 8];
      *(short8*)&Bsl[row * 72 + c8 * 8] = bv;
    }
    __syncthreads();
#pragma unroll
    for (int ks = 0; ks < 2; ks++) {
      short8 a[4], b[4];
#pragma unroll
      for (int i = 0; i < 4; i++)
        a[i] = *(const short8*)&Asl[(wm * 64 + i * 16 + lm) * 72 + ks * 32 +
                                    quad * 8];
#pragma unroll
      for (int jj = 0; jj < 4; jj++)
        b[jj] = *(const short8*)&Bsl[(wn * 64 + jj * 16 + lm) * 72 + ks * 32 +
                                     quad * 8];
#pragma unroll
      for (int i = 0; i < 4; i++)
#pragma unroll
        for (int jj = 0; jj < 4; jj++)
          acc[i][jj] = __builtin_amdgcn_mfma_f32_16x16x32_bf16(a[i], b[jj],
                                                               acc[i][jj],
                                                               0, 0, 0);
    }
  }

  const int rbase = quad * 4;
#pragma unroll
  for (int i = 0; i < 4; i++)
#pragma unroll
    for (int jj = 0; jj < 4; jj++) {
      int mrow = t0 + wm * 64 + i * 16 + rbase;
      int ncol = n0 + wn * 64 + jj * 16 + lm;
#pragma unroll
      for (int r = 0; r < 4; r++)
        yraw[((size_t)bl * Tt + mrow + r) * 1536 + j * 512 + ncol] =
            bf16s(acc[i][jj][r]);
    }
}

// ---------------------------------------------------------------------------
// 2) Fused gate + LayerNorm: yraw(bf16) -> h16(bf16 only)
// ---------------------------------------------------------------------------
__global__ __launch_bounds__(256) void gate_ln_kernel(
    const short* __restrict__ yraw, __hip_bfloat16* __restrict__ h16,
    const float* __restrict__ bf3, const float* __restrict__ bg3,
    const float* __restrict__ bf5, const float* __restrict__ bg5,
    const float* __restrict__ bf7, const float* __restrict__ bg7,
    const float* __restrict__ g, const float* __restrict__ bt) {
  __shared__ float red[8];
  const size_t row = blockIdx.x;
  float v[3], s = 0.f, ss = 0.f;
#pragma unroll
  for (int jj = 0; jj < 3; jj++) {
    int c = threadIdx.x + jj * 256;
    int br = c >> 8, cc = c & 255;
    const float* bfp = br == 0 ? bf3 : br == 1 ? bf5 : bf7;
    const float* bgp = br == 0 ? bg3 : br == 1 ? bg5 : bg7;
    __hip_bfloat16 rf = *(const __hip_bfloat16*)&yraw[row * 1536 + br * 512 + cc];
    __hip_bfloat16 rg =
        *(const __hip_bfloat16*)&yraw[row * 1536 + br * 512 + 256 + cc];
    float f = __bfloat162float(rf) + bfp[cc];
    float gt = __bfloat162float(rg) + bgp[cc];
    float a = f > 0.f ? f : 0.f;
    float t = a * (1.f / (1.f + __expf(-gt)));
    v[jj] = t; s += t; ss += t * t;
  }
  float2 r = block_reduce2(s, ss, red);
  float mu = r.x * (1.f / Hh);
  float var = r.y * (1.f / Hh) - mu * mu;
  float rs = rsqrtf(var + EPS);
#pragma unroll
  for (int jj = 0; jj < 3; jj++) {
    int c = threadIdx.x + jj * 256;
    float o = (v[jj] - mu) * rs * g[c] + bt[c];
    h16[row * Hh + c] = __float2bfloat16(o);
  }
}

// residual LN: h16 = LN(h16 + y16 + bp)   (bf16 in/out, fp32 math)
__global__ __launch_bounds__(256) void res_ln_kernel(
    __hip_bfloat16* __restrict__ h16, const __hip_bfloat16* __restrict__ y,
    const float* __restrict__ bp, const float* __restrict__ g,
    const float* __restrict__ bt) {
  __shared__ float red[8];
  const size_t row = blockIdx.x;
  float v[3], s = 0.f, ss = 0.f;
#pragma unroll
  for (int jj = 0; jj < 3; jj++) {
    int c = threadIdx.x + jj * 256;
    float t = __bfloat162float(h16[row * Hh + c]) +
              __bfloat162float(y[row * Hh + c]) + bp[c];
    v[jj] = t; s += t; ss += t * t;
  }
  float2 r = block_reduce2(s, ss, red);
  float mu = r.x * (1.f / Hh);
  float var = r.y * (1.f / Hh) - mu * mu;
  float rs = rsqrtf(var + EPS);
#pragma unroll
  for (int jj = 0; jj < 3; jj++) {
    int c = threadIdx.x + jj * 256;
    float o = (v[jj] - mu) * rs * g[c] + bt[c];
    h16[row * Hh + c] = __float2bfloat16(o);
  }
}

// ---------------------------------------------------------------------------
// 3a) Fused QKV GEMM (unchanged)
// ---------------------------------------------------------------------------
__global__ __launch_bounds__(256) void gemm_qkv(
    const short* __restrict__ A, const short* __restrict__ Bt,
    short* __restrict__ q16, short* __restrict__ k16,
    short* __restrict__ vt16) {
  constexpr int K = 768;
  __shared__ __align__(16) short Asl[128 * 32];
  __shared__ __align__(16) short Bsl[128 * 32];
  const int n0 = blockIdx.x * 128, m0 = blockIdx.y * 128;
  const int lane = threadIdx.x & 63;
  const int w = threadIdx.x >> 6, wm = w >> 1, wn = w & 1;
  const int lm = lane & 15, quad = lane >> 4;

  floatx4 acc[4][4];
#pragma unroll
  for (int i = 0; i < 4; i++)
#pragma unroll
    for (int jj = 0; jj < 4; jj++) acc[i][jj] = (floatx4)0.f;

  for (int k0 = 0; k0 < K; k0 += 32) {
    __syncthreads();
#pragma unroll
    for (int half = 0; half < 2; half++) {
      int s = half * 256 + threadIdx.x;
      int m = s >> 2, ks = (s & 3) * 8;
      async_copy16(&A[(size_t)(m0 + m) * K + k0 + ks], &Asl[s * 8]);
      async_copy16(&Bt[(size_t)(n0 + m) * K + k0 + ks], &Bsl[s * 8]);
    }
    __syncthreads();

    short8 a[4], b[4];
#pragma unroll
    for (int i = 0; i < 4; i++)
      a[i] = *(const short8*)&Asl[(wm * 64 + i * 16 + lm) * 32 + quad * 8];
#pragma unroll
    for (int jj = 0; jj < 4; jj++)
      b[jj] = *(const short8*)&Bsl[(wn * 64 + jj * 16 + lm) * 32 + quad * 8];
#pragma unroll
    for (int i = 0; i < 4; i++)
#pragma unroll
      for (int jj = 0; jj < 4; jj++)
        acc[i][jj] = __builtin_amdgcn_mfma_f32_16x16x32_bf16(a[i], b[jj],
                                                             acc[i][jj],
                                                             0, 0, 0);
  }

  const int which = blockIdx.x / 6;  // 0:q 1:k 2:v
  const int rbase = quad * 4;
#pragma unroll
  for (int i = 0; i < 4; i++)
#pragma unroll
    for (int jj = 0; jj < 4; jj++) {
      int mrow = m0 + wm * 64 + i * 16 + rbase;
      int nl = n0 - which * Hh + wn * 64 + jj * 16 + lm;
      if (which == 0) {
#pragma unroll
        for (int r = 0; r < 4; r++)
          q16[(size_t)(mrow + r) * Hh + nl] = bf16s(acc[i][jj][r]);
      } else if (which == 1) {
#pragma unroll
        for (int r = 0; r < 4; r++)
          k16[(size_t)(mrow + r) * Hh + nl] = bf16s(acc[i][jj][r]);
      } else {
        int bL = mrow >> 10, t = mrow & 1023;
        int g = nl / Dd, d = nl % Dd;
        short4 sv;
        sv.x = bf16s(acc[i][jj][0]); sv.y = bf16s(acc[i][jj][1]);
        sv.z = bf16s(acc[i][jj][2]); sv.w = bf16s(acc[i][jj][3]);
        *(short4*)&vt16[(((size_t)bL * Gg + g) * Dd + d) * Tt + t] = sv;
      }
    }
}

// 3b) Proj GEMM: bf16 out [tok][768] (unchanged)
__global__ __launch_bounds__(256) void gemm_proj(
    const short* __restrict__ A, const short* __restrict__ Bt,
    short* __restrict__ C) {
  constexpr int K = 768, N = 768;
  __shared__ __align__(16) short Asl[128 * 32];
  __shared__ __align__(16) short Bsl[128 * 32];
  const int n0 = blockIdx.x * 128, m0 = blockIdx.y * 128;
  const int lane = threadIdx.x & 63;
  const int w = threadIdx.x >> 6, wm = w >> 1, wn = w & 1;
  const int lm = lane & 15, quad = lane >> 4;

  floatx4 acc[4][4];
#pragma unroll
  for (int i = 0; i < 4; i++)
#pragma unroll
    for (int jj = 0; jj < 4; jj++) acc[i][jj] = (floatx4)0.f;

  for (int k0 = 0; k0 < K; k0 += 32) {
    __syncthreads();
#pragma unroll
    for (int half = 0; half < 2; half++) {
      int s = half * 256 + threadIdx.x;
      int m = s >> 2, ks = (s & 3) * 8;
      async_copy16(&A[(size_t)(m0 + m) * K + k0 + ks], &Asl[s * 8]);
      async_copy16(&Bt[(size_t)(n0 + m) * K + k0 + ks], &Bsl[s * 8]);
    }
    __syncthreads();

    short8 a[4], b[4];
#pragma unroll
    for (int i = 0; i < 4; i++)
      a[i] = *(const short8*)&Asl[(wm * 64 + i * 16 + lm) * 32 + quad * 8];
#pragma unroll
    for (int jj = 0; jj < 4; jj++)
      b[jj] = *(const short8*)&Bsl[(wn * 64 + jj * 16 + lm) * 32 + quad * 8];
#pragma unroll
    for (int i = 0; i < 4; i++)
#pragma unroll
      for (int jj = 0; jj < 4; jj++)
        acc[i][jj] = __builtin_amdgcn_mfma_f32_16x16x32_bf16(a[i], b[jj],
                                                             acc[i][jj],
                                                             0, 0, 0);
  }

  const int rbase = quad * 4;
#pragma unroll
  for (int i = 0; i < 4; i++)
#pragma unroll
    for (int jj = 0; jj < 4; jj++) {
      int mrow = m0 + wm * 64 + i * 16 + rbase;
      int ncol = n0 + wn * 64 + jj * 16 + lm;
#pragma unroll
      for (int r = 0; r < 4; r++)
        C[(size_t)(mrow + r) * N + ncol] = bf16s(acc[i][jj][r]);
    }
}

// ---------------------------------------------------------------------------
// 4) MFMA flash attention, S^T formulation + pipelined staging (unchanged)
// ---------------------------------------------------------------------------
__global__ __launch_bounds__(256, 2) void attn_mfma(
    const short* __restrict__ q16, const short* __restrict__ k16,
    const short* __restrict__ vt16, short* __restrict__ o16) {
  const int b = blockIdx.x;
  const int g = blockIdx.y;
  const int q0 = blockIdx.z * 128;
  const int tid = threadIdx.x;
  const int w = tid >> 6, lane = tid & 63, lm = lane & 15, quad = lane >> 4;

  __shared__ __align__(16) short Ks[32 * 200];   // [kk][d], stride 200
  __shared__ __align__(16) short Vt[192 * VTS];  // [d][kk], stride 40

  short8 qf[2][6];
#pragma unroll
  for (int mt = 0; mt < 2; mt++)
#pragma unroll
    for (int ks = 0; ks < 6; ks++) {
      int tok = b * Tt + q0 + w * 32 + mt * 16 + lm;
      qf[mt][ks] = *(const short8*)&q16[(size_t)tok * Hh + g * Dd + ks * 32 +
                                        quad * 8];
    }

  floatx4 Oa[2][12];
#pragma unroll
  for (int mt = 0; mt < 2; mt++)
#pragma unroll
    for (int n = 0; n < 12; n++) Oa[mt][n] = (floatx4)0.f;
  float mr[2] = {-1e30f, -1e30f}, lr[2] = {0.f, 0.f};

  short8 kvK[3], kvV[3];
#pragma unroll
  for (int it = 0; it < 3; it++) {
    int s = it * 256 + tid;
    int row = s / 24, cs = s - row * 24;
    kvK[it] = *(const short8*)&k16[(size_t)(b * Tt + row) * Hh + g * Dd +
                                   cs * 8];
    int d = s >> 2, c2 = s & 3;
    kvV[it] = *(const short8*)&vt16[(((size_t)b * Gg + g) * Dd + d) * Tt +
                                    c2 * 8];
  }

  for (int kt = 0; kt < Tt; kt += 32) {
    __syncthreads();
#pragma unroll
    for (int it = 0; it < 3; it++) {
      int s = it * 256 + tid;
      int row = s / 24, cs = s - row * 24;
      *(short8*)&Ks[row * 200 + cs * 8] = kvK[it];
      int d = s >> 2, c2 = s & 3;
      *(short8*)&Vt[d * VTS + c2 * 8] = kvV[it];
    }
    __syncthreads();

    if (kt + 32 < Tt) {
#pragma unroll
      for (int it = 0; it < 3; it++) {
        int s = it * 256 + tid;
        int row = s / 24, cs = s - row * 24;
        kvK[it] = *(const short8*)&k16[(size_t)(b * Tt + kt + 32 + row) * Hh +
                                       g * Dd + cs * 8];
        int d = s >> 2, c2 = s & 3;
        kvV[it] = *(const short8*)&vt16[(((size_t)b * Gg + g) * Dd + d) * Tt +
                                        kt + 32 + c2 * 8];
      }
    }

    floatx4 st[2][2];
#pragma unroll
    for (int mt = 0; mt < 2; mt++)
#pragma unroll
      for (int jj = 0; jj < 2; jj++) st[mt][jj] = (floatx4)0.f;
#pragma unroll
    for (int ks = 0; ks < 6; ks++) {
      short8 k0 = *(const short8*)&Ks[lm * 200 + ks * 32 + quad * 8];
      short8 k1 = *(const short8*)&Ks[(16 + lm) * 200 + ks * 32 + quad * 8];
      st[0][0] = __builtin_amdgcn_mfma_f32_16x16x32_bf16(k0, qf[0][ks], st[0][0], 0, 0, 0);
      st[0][1] = __builtin_amdgcn_mfma_f32_16x16x32_bf16(k1, qf[0][ks], st[0][1], 0, 0, 0);
      st[1][0] = __builtin_amdgcn_mfma_f32_16x16x32_bf16(k0, qf[1][ks], st[1][0], 0, 0, 0);
      st[1][1] = __builtin_amdgcn_mfma_f32_16x16x32_bf16(k1, qf[1][ks], st[1][1], 0, 0, 0);
    }

    short8 ptf[2];
#pragma unroll
    for (int mt = 0; mt < 2; mt++) {
      float smax = st[mt][0][0];
#pragma unroll
      for (int r = 1; r < 4; r++) smax = fmaxf(smax, st[mt][0][r]);
#pragma unroll
      for (int r = 0; r < 4; r++) smax = fmaxf(smax, st[mt][1][r]);
      smax = fmaxf(smax, __shfl_xor(smax, 16));
      smax = fmaxf(smax, __shfl_xor(smax, 32));
      float mnew = fmaxf(mr[mt], smax);
      float alpha = __expf(mr[mt] - mnew);
      mr[mt] = mnew;
      float p[2][4];
      float sum = 0.f;
#pragma unroll
      for (int jj = 0; jj < 2; jj++)
#pragma unroll
        for (int r = 0; r < 4; r++) {
          p[jj][r] = __expf(st[mt][jj][r] - mnew);
          sum += p[jj][r];
        }
      sum += __shfl_xor(sum, 16);
      sum += __shfl_xor(sum, 32);
      lr[mt] = lr[mt] * alpha + sum;

      int pk00 = (int)pack_bf16(p[0][0], p[0][1]);
      int pk01 = (int)pack_bf16(p[0][2], p[0][3]);
      int pk10 = (int)pack_bf16(p[1][0], p[1][1]);
      int pk11 = (int)pack_bf16(p[1][2], p[1][3]);
      int srcA = ((quad & 1) << 5) + lm;
      int srcB = srcA + 16;
      int a0 = __shfl(pk00, srcA), a1 = __shfl(pk01, srcA);
      int a2 = __shfl(pk00, srcB), a3 = __shfl(pk01, srcB);
      int b0 = __shfl(pk10, srcA), b1 = __shfl(pk11, srcA);
      int b2 = __shfl(pk10, srcB), b3 = __shfl(pk11, srcB);
      bool hi = quad >= 2;
      union { int u[4]; short8 v; } pu;
      pu.u[0] = hi ? b0 : a0;
      pu.u[1] = hi ? b1 : a1;
      pu.u[2] = hi ? b2 : a2;
      pu.u[3] = hi ? b3 : a3;
      ptf[mt] = pu.v;

#pragma unroll
      for (int n = 0; n < 12; n++)
#pragma unroll
        for (int r = 0; r < 4; r++) Oa[mt][n][r] *= alpha;
    }

#pragma unroll
    for (int n = 0; n < 12; n++) {
      short8 vf = *(const short8*)&Vt[(n * 16 + lm) * VTS + quad * 8];
      Oa[0][n] = __builtin_amdgcn_mfma_f32_16x16x32_bf16(vf, ptf[0], Oa[0][n], 0, 0, 0);
      Oa[1][n] = __builtin_amdgcn_mfma_f32_16x16x32_bf16(vf, ptf[1], Oa[1][n], 0, 0, 0);
    }
  }

#pragma unroll
  for (int mt = 0; mt < 2; mt++) {
    float inv = 1.f / lr[mt];
    int tok = b * Tt + q0 + w * 32 + mt * 16 + lm;
#pragma unroll
    for (int n = 0; n < 12; n++) {
      short4 sv;
      sv.x = bf16s(Oa[mt][n][0] * inv);
      sv.y = bf16s(Oa[mt][n][1] * inv);
      sv.z = bf16s(Oa[mt][n][2] * inv);
      sv.w = bf16s(Oa[mt][n][3] * inv);
      *(short4*)&o16[(size_t)tok * Hh + g * Dd + n * 16 + quad * 4] = sv;
    }
  }
}

// ---------------------------------------------------------------------------
// 5) Pool, two-stage; stage1 reads bf16 h
// ---------------------------------------------------------------------------
__global__ __launch_bounds__(256) void pool_stage1(
    const __hip_bfloat16* __restrict__ h16, float* __restrict__ ppart,
    int b0) {
  int idx = blockIdx.x * 256 + threadIdx.x;
  int seg = blockIdx.y;
  int bl = idx / Hh, c = idx % Hh;
  float s = 0.f, ss = 0.f;
  const __hip_bfloat16* hp = &h16[((size_t)bl * Tt + seg * 128) * Hh + c];
  for (int t = 0; t < 128; t++) {
    float v = __bfloat162float(hp[(size_t)t * Hh]);
    s += v; ss += v * v;
  }
  float* o = &ppart[(((size_t)(b0 + bl) * 8 + seg) * 2) * Hh + c];
  o[0] = s;
  o[Hh] = ss;
}

__global__ __launch_bounds__(256) void pool_stage2(
    const float* __restrict__ ppart, float* __restrict__ pool) {
  int idx = blockIdx.x * 256 + threadIdx.x;
  int b = idx / Hh, c = idx % Hh;
  float s = 0.f, ss = 0.f;
#pragma unroll
  for (int seg = 0; seg < 8; seg++) {
    const float* o = &ppart[(((size_t)b * 8 + seg) * 2) * Hh + c];
    s += o[0]; ss += o[Hh];
  }
  float mu = s * (1.f / Tt);
  float var = ss * (1.f / Tt) - mu * mu;
  pool[(size_t)b * 1536 + c] = mu;
  pool[(size_t)b * 1536 + 768 + c] = sqrtf(fmaxf(var, 0.f));
}

// ---------------------------------------------------------------------------
// 6) Final projection, split-K two-stage (unchanged)
// ---------------------------------------------------------------------------
__global__ __launch_bounds__(256) void final_partial(
    const float* __restrict__ pool, const float* __restrict__ pw,
    float* __restrict__ part) {
  const int n = blockIdx.x * 256 + threadIdx.x;
  const int bg = blockIdx.y * 4;
  const int ks = blockIdx.z, k0 = ks * 192;
  __shared__ float ms[4][192];
  for (int e = threadIdx.x; e < 4 * 192; e += 256) {
    int bb = e / 192, kk = e % 192;
    ms[bb][kk] = pool[(size_t)(bg + bb) * 1536 + k0 + kk];
  }
  __syncthreads();
  float a0 = 0.f, a1 = 0.f, a2 = 0.f, a3 = 0.f;
  for (int kk = 0; kk < 192; kk++) {
    float wv = pw[(size_t)(k0 + kk) * Hh + n];
    a0 = fmaf(ms[0][kk], wv, a0);
    a1 = fmaf(ms[1][kk], wv, a1);
    a2 = fmaf(ms[2][kk], wv, a2);
    a3 = fmaf(ms[3][kk], wv, a3);
  }
  part[((size_t)ks * Bb + bg + 0) * Hh + n] = a0;
  part[((size_t)ks * Bb + bg + 1) * Hh + n] = a1;
  part[((size_t)ks * Bb + bg + 2) * Hh + n] = a2;
  part[((size_t)ks * Bb + bg + 3) * Hh + n] = a3;
}

__global__ __launch_bounds__(256) void final_stage2(
    const float* __restrict__ part, const float* __restrict__ pb,
    const float* __restrict__ g, const float* __restrict__ bt,
    float* __restrict__ out) {
  __shared__ float red[8];
  const int b = blockIdx.x;
  float v[3], s = 0.f, ss = 0.f;
#pragma unroll
  for (int jj = 0; jj < 3; jj++) {
    int n = threadIdx.x + jj * 256;
    float a = pb[n];
#pragma unroll
    for (int ks = 0; ks < 8; ks++) a += part[((size_t)ks * Bb + b) * Hh + n];
    v[jj] = a; s += a; ss += a * a;
  }
  float2 r = block_reduce2(s, ss, red);
  float mu = r.x * (1.f / Hh);
  float var = r.y * (1.f / Hh) - mu * mu;
  float rs = rsqrtf(var + EPS);
#pragma unroll
  for (int jj = 0; jj < 3; jj++) {
    int n = threadIdx.x + jj * 256;
    float o = (v[jj] - mu) * rs * g[n] + bt[n];
    out[(size_t)b * Hh + n] = o > 0.f ? o : 0.f;
  }
}

// ---------------------------------------------------------------------------
extern "C" void kernel_launch(void* const* d_in, const int* in_sizes, int n_in,
                              void* d_out, int out_size, void* d_ws,
                              size_t ws_size, hipStream_t stream) {
  (void)in_sizes; (void)n_in; (void)out_size;
  const float* x = (const float*)d_in[0];
  const float* cw[3][4];
  for (int j = 0; j < 3; j++)
    for (int p2 = 0; p2 < 4; p2++) cw[j][p2] = (const float*)d_in[1 + j * 4 + p2];
  const float* conv_ln_g = (const float*)d_in[13];
  const float* conv_ln_b = (const float*)d_in[14];
  const float* wq = (const float*)d_in[15];
  const float* wk = (const float*)d_in[16];
  const float* wv = (const float*)d_in[17];
  const float* wp = (const float*)d_in[18];
  const float* bp = (const float*)d_in[19];
  const float* lng = (const float*)d_in[20];
  const float* lnb = (const float*)d_in[21];
  const float* proj_w = (const float*)d_in[22];
  const float* proj_b = (const float*)d_in[23];
  const float* proj_ln_g = (const float*)d_in[24];
  const float* proj_ln_b = (const float*)d_in[25];
  float* out = (float*)d_out;

  // --- workspace: 8 B per token-channel element -----------------------------
  // chunk buffers: h16(2) | q16(2) | k16(2) | vt16(2).
  // unions: yraw (conv raw, 4 B/elem) = q16||k16 (contiguous);
  //         y16 (proj out) = k16 (dead after attn).
  const size_t perb = (size_t)Tt * Hh;
  const size_t fixedB = 8ull * Hh * Hh * 2 + 3ull * 512 * WKMAX * 2 +
                        (size_t)Bb * Tt * Ff * 2 + (size_t)Bb * 2 * Hh * 4 +
                        (size_t)Bb * 8 * 2 * Hh * 4 + 8ull * Bb * Hh * 4;
  int chunk = Bb;
  while (chunk > 1 && 8ull * perb * chunk + fixedB > ws_size) chunk >>= 1;

  const size_t crow = perb * (size_t)chunk;
  char* p = (char*)d_ws;
  __hip_bfloat16* h16 = (__hip_bfloat16*)p;  p += crow * 2;
  short* q16 = (short*)p;            p += crow * 2;
  short* k16 = (short*)p;            p += crow * 2;   // contiguous after q16
  short* v16t = (short*)p;           p += crow * 2;
  short* yraw16 = q16;               // conv raw spans q16||k16 (4 B/elem)
  short* y16 = k16;                  // proj output reuses k16
  __hip_bfloat16* wt = (__hip_bfloat16*)p;   p += 8ull * Hh * Hh * 2;
  __hip_bfloat16* wcv = (__hip_bfloat16*)p;  p += 3ull * 512 * WKMAX * 2;
  short* x16 = (short*)p;            p += (size_t)Bb * Tt * Ff * 2;
  float* pool = (float*)p;           p += (size_t)Bb * 2 * Hh * 4;
  float* ppart = (float*)p;          p += (size_t)Bb * 8 * 2 * Hh * 4;
  float* fpart = (float*)p;

  // one-time casts
  wt_cast_kernel<<<dim3(24, 24, 8), 256, 0, stream>>>(wq, wk, wv, wp, wt);
  wcv_cast_kernel<<<(3 * 512 * WKMAX + 255) / 256, 256, 0, stream>>>(
      cw[0][0], cw[0][2], cw[1][0], cw[1][2], cw[2][0], cw[2][2], wcv);
  x_cast_kernel<<<(Bb * Tt * Ff / 8 + 255) / 256, 256, 0, stream>>>(
      x, x16, Bb * Tt * Ff / 8);

  const short* wts = (const short*)wt;

  for (int b0 = 0; b0 < Bb; b0 += chunk) {
    const int M = chunk * Tt;

    conv_gemm_kernel<<<dim3(Tt / 128, 4, chunk * 3), 256, 0, stream>>>(
        x16, (const short*)wcv, yraw16, b0);
    gate_ln_kernel<<<M, 256, 0, stream>>>(
        yraw16, h16, cw[0][1], cw[0][3], cw[1][1], cw[1][3], cw[2][1],
        cw[2][3], conv_ln_g, conv_ln_b);

    for (int i = 0; i < 2; i++) {
      const short* wqkv = wts + (size_t)(i * 4) * Hh * Hh;
      const short* wtp = wts + (size_t)(i * 4 + 3) * Hh * Hh;
      gemm_qkv<<<dim3(18, M / 128), 256, 0, stream>>>((const short*)h16, wqkv,
                                                      q16, k16, v16t);
      attn_mfma<<<dim3(chunk, Gg, Tt / 128), 256, 0, stream>>>(q16, k16, v16t,
                                                               q16);
      gemm_proj<<<dim3(6, M / 128), 256, 0, stream>>>(q16, wtp, y16);
      res_ln_kernel<<<M, 256, 0, stream>>>(h16, (const __hip_bfloat16*)y16,
                                           bp + (size_t)i * Hh,
                                           lng + (size_t)i * Hh,
                                           lnb + (size_t)i * Hh);
    }

    pool_stage1<<<dim3((chunk * Hh) / 256, 8), 256, 0, stream>>>(h16, ppart,
                                                                 b0);
  }

  pool_stage2<<<(Bb * Hh) / 256, 256, 0, stream>>>(ppart, pool);
  final_partial<<<dim3(3, 8, 8), 256, 0, stream>>>(pool, proj_w, fpart);
  final_stage2<<<Bb, 256, 0, stream>>>(fpart, proj_b, proj_ln_g, proj_ln_b,
                                       out);
}

// Round 10
// 1048.127 us; speedup vs baseline: 10.6854x; 1.0175x over previous
//
#include <hip/hip_runtime.h>
#include <hip/hip_bf16.h>

// ---------------------------------------------------------------------------
// TemporalExtractor round 10:
//   attn only: (1) LDS double-buffer -> 1 barrier per K-iter (was 2);
//   (2) softmax denominator via MFMA ones-row (13th V tile) -> removes the
//   per-iter sum shfl_xor chain; l extracted once at end via one __shfl;
//   (3) staging address math hoisted out of the K-loop (pointer increments).
//   Everything else identical to round 9.
// ---------------------------------------------------------------------------

constexpr int Bb = 32, Tt = 1024, Ff = 64, Hh = 768, Gg = 4, Dd = 192;
constexpr float EPS = 1e-5f;
constexpr int WKMAX = 448;  // padded conv-weight K stride (7*64)
constexpr int VTS = 40;     // Vt LDS row stride in shorts

typedef __attribute__((ext_vector_type(8))) short short8;   // 8 bf16 = 4 VGPRs
typedef __attribute__((ext_vector_type(4))) float floatx4;  // MFMA acc

__device__ __forceinline__ void async_copy16(const void* g, void* l) {
  __builtin_amdgcn_global_load_lds(
      (const __attribute__((address_space(1))) unsigned int*)g,
      (__attribute__((address_space(3))) unsigned int*)l, 16, 0, 0);
}

__device__ __forceinline__ short bf16s(float f) {
  __hip_bfloat16 h = __float2bfloat16(f);
  return *(short*)&h;
}

__device__ __forceinline__ unsigned int pack_bf16(float lo, float hi) {
  return (unsigned int)(unsigned short)bf16s(lo) |
         ((unsigned int)(unsigned short)bf16s(hi) << 16);
}

__device__ __forceinline__ float2 block_reduce2(float a, float b, float* tmp) {
  int lane = threadIdx.x & 63, wid = threadIdx.x >> 6;
#pragma unroll
  for (int off = 32; off > 0; off >>= 1) {
    a += __shfl_down(a, off);
    b += __shfl_down(b, off);
  }
  if (lane == 0) { tmp[wid] = a; tmp[4 + wid] = b; }
  __syncthreads();
  if (threadIdx.x == 0) {
    tmp[0] = tmp[0] + tmp[1] + tmp[2] + tmp[3];
    tmp[4] = tmp[4] + tmp[5] + tmp[6] + tmp[7];
  }
  __syncthreads();
  float2 r; r.x = tmp[0]; r.y = tmp[4];
  return r;
}

// ---------------------------------------------------------------------------
// 0a) Attn/proj weight transpose+cast (Q pre-scaled by 192^-0.5)
// ---------------------------------------------------------------------------
__global__ __launch_bounds__(256) void wt_cast_kernel(
    const float* __restrict__ wq, const float* __restrict__ wk,
    const float* __restrict__ wv, const float* __restrict__ wp,
    __hip_bfloat16* __restrict__ wt) {
  const int z = blockIdx.z;
  const int m = z & 3, i = z >> 2;
  const float* src =
      (m == 0 ? wq : m == 1 ? wk : m == 2 ? wv : wp) + (size_t)i * Hh * Hh;
  const float sc = (m == 0) ? 0.0721687836f : 1.f;
  __shared__ float tile[32][33];
  const int n0 = blockIdx.x * 32, k0 = blockIdx.y * 32;
  const int tx = threadIdx.x & 31, ty = threadIdx.x >> 5;
#pragma unroll
  for (int r = 0; r < 4; r++)
    tile[ty + 8 * r][tx] = src[(size_t)(k0 + ty + 8 * r) * Hh + n0 + tx];
  __syncthreads();
#pragma unroll
  for (int r = 0; r < 4; r++)
    wt[((size_t)z * Hh + n0 + ty + 8 * r) * Hh + k0 + tx] =
        __float2bfloat16(tile[tx][ty + 8 * r] * sc);
}

// ---------------------------------------------------------------------------
// 0b) Conv weight cast
// ---------------------------------------------------------------------------
__global__ __launch_bounds__(256) void wcv_cast_kernel(
    const float* __restrict__ wf3, const float* __restrict__ wg3,
    const float* __restrict__ wf5, const float* __restrict__ wg5,
    const float* __restrict__ wf7, const float* __restrict__ wg7,
    __hip_bfloat16* __restrict__ wcv) {
  int idx = blockIdx.x * 256 + threadIdx.x;
  if (idx >= 3 * 512 * WKMAX) return;
  int j = idx / (512 * WKMAX);
  int rem = idx - j * 512 * WKMAX;
  int n = rem / WKMAX, k = rem % WKMAX;
  int Kw = 3 + 2 * j;
  float v = 0.f;
  if (k < Kw * 64) {
    const float* src = (n < 256) ? (j == 0 ? wf3 : j == 1 ? wf5 : wf7)
                                 : (j == 0 ? wg3 : j == 1 ? wg5 : wg7);
    v = src[(size_t)k * 256 + (n & 255)];
  }
  wcv[idx] = __float2bfloat16(v);
}

// 0c) x cast fp32 -> bf16
__global__ __launch_bounds__(256) void x_cast_kernel(
    const float* __restrict__ x, short* __restrict__ x16, int n8) {
  int idx = blockIdx.x * 256 + threadIdx.x;
  if (idx >= n8) return;
  const float4 a = ((const float4*)x)[idx * 2];
  const float4 b = ((const float4*)x)[idx * 2 + 1];
  short8 o;
  o[0] = bf16s(a.x); o[1] = bf16s(a.y); o[2] = bf16s(a.z); o[3] = bf16s(a.w);
  o[4] = bf16s(b.x); o[5] = bf16s(b.y); o[6] = bf16s(b.z); o[7] = bf16s(b.w);
  ((short8*)x16)[idx] = o;
}

// ---------------------------------------------------------------------------
// 1) Conv as implicit GEMM (unchanged)
// ---------------------------------------------------------------------------
__global__ __launch_bounds__(256) void conv_gemm_kernel(
    const short* __restrict__ x16, const short* __restrict__ wcv,
    short* __restrict__ yraw, int b0) {
  __shared__ __align__(16) short Asl[128 * 72];
  __shared__ __align__(16) short Bsl[128 * 72];
  const int t0 = blockIdx.x * 128, n0 = blockIdx.y * 128;
  const int bl = blockIdx.z / 3, j = blockIdx.z % 3;
  const int Kw = 3 + 2 * j, pad = j + 1;
  const int bglob = b0 + bl;
  const short* wb = wcv + (size_t)j * 512 * WKMAX;
  const int tid = threadIdx.x;
  const int lane = tid & 63;
  const int w = tid >> 6, wm = w >> 1, wn = w & 1;
  const int lm = lane & 15, quad = lane >> 4;

  floatx4 acc[4][4];
#pragma unroll
  for (int i = 0; i < 4; i++)
#pragma unroll
    for (int jj = 0; jj < 4; jj++) acc[i][jj] = (floatx4)0.f;

  for (int kk = 0; kk < Kw; kk++) {
    __syncthreads();
#pragma unroll
    for (int it = 0; it < 4; it++) {
      int s = it * 256 + tid;
      int row = s >> 3, c8 = s & 7;
      int t = t0 + row + kk - pad;
      short8 av = (short8)0;
      if (t >= 0 && t < Tt)
        av = *(const short8*)&x16[((size_t)bglob * Tt + t) * Ff + c8 * 8];
      *(short8*)&Asl[row * 72 + c8 * 8] = av;
      short8 bv = *(const short8*)&wb[(size_t)(n0 + row) * WKMAX + kk * 64 +
                                      c8 * 8];
      *(short8*)&Bsl[row * 72 + c8 * 8] = bv;
    }
    __syncthreads();
#pragma unroll
    for (int ks = 0; ks < 2; ks++) {
      short8 a[4], b[4];
#pragma unroll
      for (int i = 0; i < 4; i++)
        a[i] = *(const short8*)&Asl[(wm * 64 + i * 16 + lm) * 72 + ks * 32 +
                                    quad * 8];
#pragma unroll
      for (int jj = 0; jj < 4; jj++)
        b[jj] = *(const short8*)&Bsl[(wn * 64 + jj * 16 + lm) * 72 + ks * 32 +
                                     quad * 8];
#pragma unroll
      for (int i = 0; i < 4; i++)
#pragma unroll
        for (int jj = 0; jj < 4; jj++)
          acc[i][jj] = __builtin_amdgcn_mfma_f32_16x16x32_bf16(a[i], b[jj],
                                                               acc[i][jj],
                                                               0, 0, 0);
    }
  }

  const int rbase = quad * 4;
#pragma unroll
  for (int i = 0; i < 4; i++)
#pragma unroll
    for (int jj = 0; jj < 4; jj++) {
      int mrow = t0 + wm * 64 + i * 16 + rbase;
      int ncol = n0 + wn * 64 + jj * 16 + lm;
#pragma unroll
      for (int r = 0; r < 4; r++)
        yraw[((size_t)bl * Tt + mrow + r) * 1536 + j * 512 + ncol] =
            bf16s(acc[i][jj][r]);
    }
}

// ---------------------------------------------------------------------------
// 2) Fused gate + LayerNorm (unchanged)
// ---------------------------------------------------------------------------
__global__ __launch_bounds__(256) void gate_ln_kernel(
    const short* __restrict__ yraw, __hip_bfloat16* __restrict__ h16,
    const float* __restrict__ bf3, const float* __restrict__ bg3,
    const float* __restrict__ bf5, const float* __restrict__ bg5,
    const float* __restrict__ bf7, const float* __restrict__ bg7,
    const float* __restrict__ g, const float* __restrict__ bt) {
  __shared__ float red[8];
  const size_t row = blockIdx.x;
  float v[3], s = 0.f, ss = 0.f;
#pragma unroll
  for (int jj = 0; jj < 3; jj++) {
    int c = threadIdx.x + jj * 256;
    int br = c >> 8, cc = c & 255;
    const float* bfp = br == 0 ? bf3 : br == 1 ? bf5 : bf7;
    const float* bgp = br == 0 ? bg3 : br == 1 ? bg5 : bg7;
    __hip_bfloat16 rf = *(const __hip_bfloat16*)&yraw[row * 1536 + br * 512 + cc];
    __hip_bfloat16 rg =
        *(const __hip_bfloat16*)&yraw[row * 1536 + br * 512 + 256 + cc];
    float f = __bfloat162float(rf) + bfp[cc];
    float gt = __bfloat162float(rg) + bgp[cc];
    float a = f > 0.f ? f : 0.f;
    float t = a * (1.f / (1.f + __expf(-gt)));
    v[jj] = t; s += t; ss += t * t;
  }
  float2 r = block_reduce2(s, ss, red);
  float mu = r.x * (1.f / Hh);
  float var = r.y * (1.f / Hh) - mu * mu;
  float rs = rsqrtf(var + EPS);
#pragma unroll
  for (int jj = 0; jj < 3; jj++) {
    int c = threadIdx.x + jj * 256;
    float o = (v[jj] - mu) * rs * g[c] + bt[c];
    h16[row * Hh + c] = __float2bfloat16(o);
  }
}

// residual LN: h16 = LN(h16 + y16 + bp)   (bf16 in/out, fp32 math)
__global__ __launch_bounds__(256) void res_ln_kernel(
    __hip_bfloat16* __restrict__ h16, const __hip_bfloat16* __restrict__ y,
    const float* __restrict__ bp, const float* __restrict__ g,
    const float* __restrict__ bt) {
  __shared__ float red[8];
  const size_t row = blockIdx.x;
  float v[3], s = 0.f, ss = 0.f;
#pragma unroll
  for (int jj = 0; jj < 3; jj++) {
    int c = threadIdx.x + jj * 256;
    float t = __bfloat162float(h16[row * Hh + c]) +
              __bfloat162float(y[row * Hh + c]) + bp[c];
    v[jj] = t; s += t; ss += t * t;
  }
  float2 r = block_reduce2(s, ss, red);
  float mu = r.x * (1.f / Hh);
  float var = r.y * (1.f / Hh) - mu * mu;
  float rs = rsqrtf(var + EPS);
#pragma unroll
  for (int jj = 0; jj < 3; jj++) {
    int c = threadIdx.x + jj * 256;
    float o = (v[jj] - mu) * rs * g[c] + bt[c];
    h16[row * Hh + c] = __float2bfloat16(o);
  }
}

// ---------------------------------------------------------------------------
// 3a) Fused QKV GEMM (unchanged)
// ---------------------------------------------------------------------------
__global__ __launch_bounds__(256) void gemm_qkv(
    const short* __restrict__ A, const short* __restrict__ Bt,
    short* __restrict__ q16, short* __restrict__ k16,
    short* __restrict__ vt16) {
  constexpr int K = 768;
  __shared__ __align__(16) short Asl[128 * 32];
  __shared__ __align__(16) short Bsl[128 * 32];
  const int n0 = blockIdx.x * 128, m0 = blockIdx.y * 128;
  const int lane = threadIdx.x & 63;
  const int w = threadIdx.x >> 6, wm = w >> 1, wn = w & 1;
  const int lm = lane & 15, quad = lane >> 4;

  floatx4 acc[4][4];
#pragma unroll
  for (int i = 0; i < 4; i++)
#pragma unroll
    for (int jj = 0; jj < 4; jj++) acc[i][jj] = (floatx4)0.f;

  for (int k0 = 0; k0 < K; k0 += 32) {
    __syncthreads();
#pragma unroll
    for (int half = 0; half < 2; half++) {
      int s = half * 256 + threadIdx.x;
      int m = s >> 2, ks = (s & 3) * 8;
      async_copy16(&A[(size_t)(m0 + m) * K + k0 + ks], &Asl[s * 8]);
      async_copy16(&Bt[(size_t)(n0 + m) * K + k0 + ks], &Bsl[s * 8]);
    }
    __syncthreads();

    short8 a[4], b[4];
#pragma unroll
    for (int i = 0; i < 4; i++)
      a[i] = *(const short8*)&Asl[(wm * 64 + i * 16 + lm) * 32 + quad * 8];
#pragma unroll
    for (int jj = 0; jj < 4; jj++)
      b[jj] = *(const short8*)&Bsl[(wn * 64 + jj * 16 + lm) * 32 + quad * 8];
#pragma unroll
    for (int i = 0; i < 4; i++)
#pragma unroll
      for (int jj = 0; jj < 4; jj++)
        acc[i][jj] = __builtin_amdgcn_mfma_f32_16x16x32_bf16(a[i], b[jj],
                                                             acc[i][jj],
                                                             0, 0, 0);
  }

  const int which = blockIdx.x / 6;  // 0:q 1:k 2:v
  const int rbase = quad * 4;
#pragma unroll
  for (int i = 0; i < 4; i++)
#pragma unroll
    for (int jj = 0; jj < 4; jj++) {
      int mrow = m0 + wm * 64 + i * 16 + rbase;
      int nl = n0 - which * Hh + wn * 64 + jj * 16 + lm;
      if (which == 0) {
#pragma unroll
        for (int r = 0; r < 4; r++)
          q16[(size_t)(mrow + r) * Hh + nl] = bf16s(acc[i][jj][r]);
      } else if (which == 1) {
#pragma unroll
        for (int r = 0; r < 4; r++)
          k16[(size_t)(mrow + r) * Hh + nl] = bf16s(acc[i][jj][r]);
      } else {
        int bL = mrow >> 10, t = mrow & 1023;
        int g = nl / Dd, d = nl % Dd;
        short4 sv;
        sv.x = bf16s(acc[i][jj][0]); sv.y = bf16s(acc[i][jj][1]);
        sv.z = bf16s(acc[i][jj][2]); sv.w = bf16s(acc[i][jj][3]);
        *(short4*)&vt16[(((size_t)bL * Gg + g) * Dd + d) * Tt + t] = sv;
      }
    }
}

// 3b) Proj GEMM: bf16 out [tok][768] (unchanged)
__global__ __launch_bounds__(256) void gemm_proj(
    const short* __restrict__ A, const short* __restrict__ Bt,
    short* __restrict__ C) {
  constexpr int K = 768, N = 768;
  __shared__ __align__(16) short Asl[128 * 32];
  __shared__ __align__(16) short Bsl[128 * 32];
  const int n0 = blockIdx.x * 128, m0 = blockIdx.y * 128;
  const int lane = threadIdx.x & 63;
  const int w = threadIdx.x >> 6, wm = w >> 1, wn = w & 1;
  const int lm = lane & 15, quad = lane >> 4;

  floatx4 acc[4][4];
#pragma unroll
  for (int i = 0; i < 4; i++)
#pragma unroll
    for (int jj = 0; jj < 4; jj++) acc[i][jj] = (floatx4)0.f;

  for (int k0 = 0; k0 < K; k0 += 32) {
    __syncthreads();
#pragma unroll
    for (int half = 0; half < 2; half++) {
      int s = half * 256 + threadIdx.x;
      int m = s >> 2, ks = (s & 3) * 8;
      async_copy16(&A[(size_t)(m0 + m) * K + k0 + ks], &Asl[s * 8]);
      async_copy16(&Bt[(size_t)(n0 + m) * K + k0 + ks], &Bsl[s * 8]);
    }
    __syncthreads();

    short8 a[4], b[4];
#pragma unroll
    for (int i = 0; i < 4; i++)
      a[i] = *(const short8*)&Asl[(wm * 64 + i * 16 + lm) * 32 + quad * 8];
#pragma unroll
    for (int jj = 0; jj < 4; jj++)
      b[jj] = *(const short8*)&Bsl[(wn * 64 + jj * 16 + lm) * 32 + quad * 8];
#pragma unroll
    for (int i = 0; i < 4; i++)
#pragma unroll
      for (int jj = 0; jj < 4; jj++)
        acc[i][jj] = __builtin_amdgcn_mfma_f32_16x16x32_bf16(a[i], b[jj],
                                                             acc[i][jj],
                                                             0, 0, 0);
  }

  const int rbase = quad * 4;
#pragma unroll
  for (int i = 0; i < 4; i++)
#pragma unroll
    for (int jj = 0; jj < 4; jj++) {
      int mrow = m0 + wm * 64 + i * 16 + rbase;
      int ncol = n0 + wn * 64 + jj * 16 + lm;
#pragma unroll
      for (int r = 0; r < 4; r++)
        C[(size_t)(mrow + r) * N + ncol] = bf16s(acc[i][jj][r]);
    }
}

// ---------------------------------------------------------------------------
// 4) MFMA flash attention: S^T formulation, LDS double-buffer (1 barrier/iter),
//    denominator via MFMA ones-row (13th V tile), hoisted staging addresses.
// ---------------------------------------------------------------------------
__global__ __launch_bounds__(256, 2) void attn_mfma(
    const short* __restrict__ q16, const short* __restrict__ k16,
    const short* __restrict__ vt16, short* __restrict__ o16) {
  const int b = blockIdx.x;
  const int g = blockIdx.y;
  const int q0 = blockIdx.z * 128;
  const int tid = threadIdx.x;
  const int w = tid >> 6, lane = tid & 63, lm = lane & 15, quad = lane >> 4;

  __shared__ __align__(16) short Ks[2][32 * 200];   // [kk][d]
  __shared__ __align__(16) short Vt[2][208 * VTS];  // [d][kk] + ones tile

  // ones tile: Vt rows 192..207; row 192 = 1.0 over kk (sum row), rest 0.
  // written once (staging only touches d<192), visible after first barrier.
  for (int e = tid; e < 2 * 16 * VTS; e += 256) {
    int buf = e / (16 * VTS);
    int r = e - buf * (16 * VTS);
    int row = r / VTS, c = r - row * VTS;
    Vt[buf][(192 + row) * VTS + c] =
        (row == 0 && c < 32) ? (short)0x3F80 : (short)0;
  }

  // Q fragments (B operands; layout index-identical to A)
  short8 qf[2][6];
#pragma unroll
  for (int mt = 0; mt < 2; mt++)
#pragma unroll
    for (int ks = 0; ks < 6; ks++) {
      int tok = b * Tt + q0 + w * 32 + mt * 16 + lm;
      qf[mt][ks] = *(const short8*)&q16[(size_t)tok * Hh + g * Dd + ks * 32 +
                                        quad * 8];
    }

  floatx4 Oa[2][13];  // [q-tile][d-tile]; tile 12 = row-sum (l) via ones-row
#pragma unroll
  for (int mt = 0; mt < 2; mt++)
#pragma unroll
    for (int n = 0; n < 13; n++) Oa[mt][n] = (floatx4)0.f;
  float mr[2] = {-1e30f, -1e30f};

  // hoisted per-thread staging geometry
  int krow[3], kcs[3], vrow[3], vcs[3];
  const short* kgp[3];
  const short* vgp[3];
#pragma unroll
  for (int it = 0; it < 3; it++) {
    int s = it * 256 + tid;
    krow[it] = s / 24; kcs[it] = s - krow[it] * 24;
    vrow[it] = s >> 2; vcs[it] = s & 3;
    kgp[it] = &k16[(size_t)(b * Tt + krow[it]) * Hh + g * Dd + kcs[it] * 8];
    vgp[it] = &vt16[(((size_t)b * Gg + g) * Dd + vrow[it]) * Tt + vcs[it] * 8];
  }

  short8 kvK[3], kvV[3];
#pragma unroll
  for (int it = 0; it < 3; it++) {  // tile 0
    kvK[it] = *(const short8*)kgp[it];
    kvV[it] = *(const short8*)vgp[it];
  }
#pragma unroll
  for (int it = 0; it < 3; it++) {  // write buf 0
    *(short8*)&Ks[0][krow[it] * 200 + kcs[it] * 8] = kvK[it];
    *(short8*)&Vt[0][vrow[it] * VTS + vcs[it] * 8] = kvV[it];
  }
#pragma unroll
  for (int it = 0; it < 3; it++) {  // prefetch tile 1
    kvK[it] = *(const short8*)(kgp[it] + (size_t)32 * Hh);
    kvV[it] = *(const short8*)(vgp[it] + 32);
  }
  __syncthreads();

  for (int i = 0; i < 32; i++) {
    const int ib = i & 1;
    if (i + 1 < 32) {  // write tile i+1 into the other buffer
      const int wb2 = ib ^ 1;
#pragma unroll
      for (int it = 0; it < 3; it++) {
        *(short8*)&Ks[wb2][krow[it] * 200 + kcs[it] * 8] = kvK[it];
        *(short8*)&Vt[wb2][vrow[it] * VTS + vcs[it] * 8] = kvV[it];
      }
    }
    if (i + 2 < 32) {  // prefetch tile i+2
      const size_t ko = (size_t)(i + 2) * 32 * Hh;
      const int vo = (i + 2) * 32;
#pragma unroll
      for (int it = 0; it < 3; it++) {
        kvK[it] = *(const short8*)(kgp[it] + ko);
        kvV[it] = *(const short8*)(vgp[it] + vo);
      }
    }

    // S^T = K Q^T (rows kk, cols q=lm)
    floatx4 st[2][2];
#pragma unroll
    for (int mt = 0; mt < 2; mt++)
#pragma unroll
      for (int jj = 0; jj < 2; jj++) st[mt][jj] = (floatx4)0.f;
#pragma unroll
    for (int ks = 0; ks < 6; ks++) {
      short8 k0 = *(const short8*)&Ks[ib][lm * 200 + ks * 32 + quad * 8];
      short8 k1 = *(const short8*)&Ks[ib][(16 + lm) * 200 + ks * 32 + quad * 8];
      st[0][0] = __builtin_amdgcn_mfma_f32_16x16x32_bf16(k0, qf[0][ks], st[0][0], 0, 0, 0);
      st[0][1] = __builtin_amdgcn_mfma_f32_16x16x32_bf16(k1, qf[0][ks], st[0][1], 0, 0, 0);
      st[1][0] = __builtin_amdgcn_mfma_f32_16x16x32_bf16(k0, qf[1][ks], st[1][0], 0, 0, 0);
      st[1][1] = __builtin_amdgcn_mfma_f32_16x16x32_bf16(k1, qf[1][ks], st[1][1], 0, 0, 0);
    }

    // online softmax (max only; sum handled by ones-row MFMA) + P^T build
    short8 ptf[2];
#pragma unroll
    for (int mt = 0; mt < 2; mt++) {
      float smax = st[mt][0][0];
#pragma unroll
      for (int r = 1; r < 4; r++) smax = fmaxf(smax, st[mt][0][r]);
#pragma unroll
      for (int r = 0; r < 4; r++) smax = fmaxf(smax, st[mt][1][r]);
      smax = fmaxf(smax, __shfl_xor(smax, 16));
      smax = fmaxf(smax, __shfl_xor(smax, 32));
      float mnew = fmaxf(mr[mt], smax);
      float alpha = __expf(mr[mt] - mnew);
      mr[mt] = mnew;
      float p[2][4];
#pragma unroll
      for (int jj = 0; jj < 2; jj++)
#pragma unroll
        for (int r = 0; r < 4; r++) p[jj][r] = __expf(st[mt][jj][r] - mnew);

      int pk00 = (int)pack_bf16(p[0][0], p[0][1]);
      int pk01 = (int)pack_bf16(p[0][2], p[0][3]);
      int pk10 = (int)pack_bf16(p[1][0], p[1][1]);
      int pk11 = (int)pack_bf16(p[1][2], p[1][3]);
      int srcA = ((quad & 1) << 5) + lm;
      int srcB = srcA + 16;
      int a0 = __shfl(pk00, srcA), a1 = __shfl(pk01, srcA);
      int a2 = __shfl(pk00, srcB), a3 = __shfl(pk01, srcB);
      int b0 = __shfl(pk10, srcA), b1 = __shfl(pk11, srcA);
      int b2 = __shfl(pk10, srcB), b3 = __shfl(pk11, srcB);
      bool hi = quad >= 2;
      union { int u[4]; short8 v; } pu;
      pu.u[0] = hi ? b0 : a0;
      pu.u[1] = hi ? b1 : a1;
      pu.u[2] = hi ? b2 : a2;
      pu.u[3] = hi ? b3 : a3;
      ptf[mt] = pu.v;

#pragma unroll
      for (int n = 0; n < 13; n++)
#pragma unroll
        for (int r = 0; r < 4; r++) Oa[mt][n][r] *= alpha;
    }

    // O^T += V'^T P^T  (tile 12 accumulates l via ones row)
#pragma unroll
    for (int n = 0; n < 13; n++) {
      short8 vf = *(const short8*)&Vt[ib][(n * 16 + lm) * VTS + quad * 8];
      Oa[0][n] = __builtin_amdgcn_mfma_f32_16x16x32_bf16(vf, ptf[0], Oa[0][n], 0, 0, 0);
      Oa[1][n] = __builtin_amdgcn_mfma_f32_16x16x32_bf16(vf, ptf[1], Oa[1][n], 0, 0, 0);
    }
    __syncthreads();
  }

  // epilogue: l = Oa[mt][12][0] of lane (quad=0, lm) -> broadcast; O /= l
#pragma unroll
  for (int mt = 0; mt < 2; mt++) {
    float lval = __shfl(Oa[mt][12][0], lm);
    float inv = 1.f / lval;
    int tok = b * Tt + q0 + w * 32 + mt * 16 + lm;
#pragma unroll
    for (int n = 0; n < 12; n++) {
      short4 sv;
      sv.x = bf16s(Oa[mt][n][0] * inv);
      sv.y = bf16s(Oa[mt][n][1] * inv);
      sv.z = bf16s(Oa[mt][n][2] * inv);
      sv.w = bf16s(Oa[mt][n][3] * inv);
      *(short4*)&o16[(size_t)tok * Hh + g * Dd + n * 16 + quad * 4] = sv;
    }
  }
}

// ---------------------------------------------------------------------------
// 5) Pool, two-stage (unchanged)
// ---------------------------------------------------------------------------
__global__ __launch_bounds__(256) void pool_stage1(
    const __hip_bfloat16* __restrict__ h16, float* __restrict__ ppart,
    int b0) {
  int idx = blockIdx.x * 256 + threadIdx.x;
  int seg = blockIdx.y;
  int bl = idx / Hh, c = idx % Hh;
  float s = 0.f, ss = 0.f;
  const __hip_bfloat16* hp = &h16[((size_t)bl * Tt + seg * 128) * Hh + c];
  for (int t = 0; t < 128; t++) {
    float v = __bfloat162float(hp[(size_t)t * Hh]);
    s += v; ss += v * v;
  }
  float* o = &ppart[(((size_t)(b0 + bl) * 8 + seg) * 2) * Hh + c];
  o[0] = s;
  o[Hh] = ss;
}

__global__ __launch_bounds__(256) void pool_stage2(
    const float* __restrict__ ppart, float* __restrict__ pool) {
  int idx = blockIdx.x * 256 + threadIdx.x;
  int b = idx / Hh, c = idx % Hh;
  float s = 0.f, ss = 0.f;
#pragma unroll
  for (int seg = 0; seg < 8; seg++) {
    const float* o = &ppart[(((size_t)b * 8 + seg) * 2) * Hh + c];
    s += o[0]; ss += o[Hh];
  }
  float mu = s * (1.f / Tt);
  float var = ss * (1.f / Tt) - mu * mu;
  pool[(size_t)b * 1536 + c] = mu;
  pool[(size_t)b * 1536 + 768 + c] = sqrtf(fmaxf(var, 0.f));
}

// ---------------------------------------------------------------------------
// 6) Final projection, split-K two-stage (unchanged)
// ---------------------------------------------------------------------------
__global__ __launch_bounds__(256) void final_partial(
    const float* __restrict__ pool, const float* __restrict__ pw,
    float* __restrict__ part) {
  const int n = blockIdx.x * 256 + threadIdx.x;
  const int bg = blockIdx.y * 4;
  const int ks = blockIdx.z, k0 = ks * 192;
  __shared__ float ms[4][192];
  for (int e = threadIdx.x; e < 4 * 192; e += 256) {
    int bb = e / 192, kk = e % 192;
    ms[bb][kk] = pool[(size_t)(bg + bb) * 1536 + k0 + kk];
  }
  __syncthreads();
  float a0 = 0.f, a1 = 0.f, a2 = 0.f, a3 = 0.f;
  for (int kk = 0; kk < 192; kk++) {
    float wv = pw[(size_t)(k0 + kk) * Hh + n];
    a0 = fmaf(ms[0][kk], wv, a0);
    a1 = fmaf(ms[1][kk], wv, a1);
    a2 = fmaf(ms[2][kk], wv, a2);
    a3 = fmaf(ms[3][kk], wv, a3);
  }
  part[((size_t)ks * Bb + bg + 0) * Hh + n] = a0;
  part[((size_t)ks * Bb + bg + 1) * Hh + n] = a1;
  part[((size_t)ks * Bb + bg + 2) * Hh + n] = a2;
  part[((size_t)ks * Bb + bg + 3) * Hh + n] = a3;
}

__global__ __launch_bounds__(256) void final_stage2(
    const float* __restrict__ part, const float* __restrict__ pb,
    const float* __restrict__ g, const float* __restrict__ bt,
    float* __restrict__ out) {
  __shared__ float red[8];
  const int b = blockIdx.x;
  float v[3], s = 0.f, ss = 0.f;
#pragma unroll
  for (int jj = 0; jj < 3; jj++) {
    int n = threadIdx.x + jj * 256;
    float a = pb[n];
#pragma unroll
    for (int ks = 0; ks < 8; ks++) a += part[((size_t)ks * Bb + b) * Hh + n];
    v[jj] = a; s += a; ss += a * a;
  }
  float2 r = block_reduce2(s, ss, red);
  float mu = r.x * (1.f / Hh);
  float var = r.y * (1.f / Hh) - mu * mu;
  float rs = rsqrtf(var + EPS);
#pragma unroll
  for (int jj = 0; jj < 3; jj++) {
    int n = threadIdx.x + jj * 256;
    float o = (v[jj] - mu) * rs * g[n] + bt[n];
    out[(size_t)b * Hh + n] = o > 0.f ? o : 0.f;
  }
}

// ---------------------------------------------------------------------------
extern "C" void kernel_launch(void* const* d_in, const int* in_sizes, int n_in,
                              void* d_out, int out_size, void* d_ws,
                              size_t ws_size, hipStream_t stream) {
  (void)in_sizes; (void)n_in; (void)out_size;
  const float* x = (const float*)d_in[0];
  const float* cw[3][4];
  for (int j = 0; j < 3; j++)
    for (int p2 = 0; p2 < 4; p2++) cw[j][p2] = (const float*)d_in[1 + j * 4 + p2];
  const float* conv_ln_g = (const float*)d_in[13];
  const float* conv_ln_b = (const float*)d_in[14];
  const float* wq = (const float*)d_in[15];
  const float* wk = (const float*)d_in[16];
  const float* wv = (const float*)d_in[17];
  const float* wp = (const float*)d_in[18];
  const float* bp = (const float*)d_in[19];
  const float* lng = (const float*)d_in[20];
  const float* lnb = (const float*)d_in[21];
  const float* proj_w = (const float*)d_in[22];
  const float* proj_b = (const float*)d_in[23];
  const float* proj_ln_g = (const float*)d_in[24];
  const float* proj_ln_b = (const float*)d_in[25];
  float* out = (float*)d_out;

  // --- workspace: 8 B per token-channel element -----------------------------
  const size_t perb = (size_t)Tt * Hh;
  const size_t fixedB = 8ull * Hh * Hh * 2 + 3ull * 512 * WKMAX * 2 +
                        (size_t)Bb * Tt * Ff * 2 + (size_t)Bb * 2 * Hh * 4 +
                        (size_t)Bb * 8 * 2 * Hh * 4 + 8ull * Bb * Hh * 4;
  int chunk = Bb;
  while (chunk > 1 && 8ull * perb * chunk + fixedB > ws_size) chunk >>= 1;

  const size_t crow = perb * (size_t)chunk;
  char* p = (char*)d_ws;
  __hip_bfloat16* h16 = (__hip_bfloat16*)p;  p += crow * 2;
  short* q16 = (short*)p;            p += crow * 2;
  short* k16 = (short*)p;            p += crow * 2;   // contiguous after q16
  short* v16t = (short*)p;           p += crow * 2;
  short* yraw16 = q16;               // conv raw spans q16||k16 (4 B/elem)
  short* y16 = k16;                  // proj output reuses k16
  __hip_bfloat16* wt = (__hip_bfloat16*)p;   p += 8ull * Hh * Hh * 2;
  __hip_bfloat16* wcv = (__hip_bfloat16*)p;  p += 3ull * 512 * WKMAX * 2;
  short* x16 = (short*)p;            p += (size_t)Bb * Tt * Ff * 2;
  float* pool = (float*)p;           p += (size_t)Bb * 2 * Hh * 4;
  float* ppart = (float*)p;          p += (size_t)Bb * 8 * 2 * Hh * 4;
  float* fpart = (float*)p;

  // one-time casts
  wt_cast_kernel<<<dim3(24, 24, 8), 256, 0, stream>>>(wq, wk, wv, wp, wt);
  wcv_cast_kernel<<<(3 * 512 * WKMAX + 255) / 256, 256, 0, stream>>>(
      cw[0][0], cw[0][2], cw[1][0], cw[1][2], cw[2][0], cw[2][2], wcv);
  x_cast_kernel<<<(Bb * Tt * Ff / 8 + 255) / 256, 256, 0, stream>>>(
      x, x16, Bb * Tt * Ff / 8);

  const short* wts = (const short*)wt;

  for (int b0 = 0; b0 < Bb; b0 += chunk) {
    const int M = chunk * Tt;

    conv_gemm_kernel<<<dim3(Tt / 128, 4, chunk * 3), 256, 0, stream>>>(
        x16, (const short*)wcv, yraw16, b0);
    gate_ln_kernel<<<M, 256, 0, stream>>>(
        yraw16, h16, cw[0][1], cw[0][3], cw[1][1], cw[1][3], cw[2][1],
        cw[2][3], conv_ln_g, conv_ln_b);

    for (int i = 0; i < 2; i++) {
      const short* wqkv = wts + (size_t)(i * 4) * Hh * Hh;
      const short* wtp = wts + (size_t)(i * 4 + 3) * Hh * Hh;
      gemm_qkv<<<dim3(18, M / 128), 256, 0, stream>>>((const short*)h16, wqkv,
                                                      q16, k16, v16t);
      attn_mfma<<<dim3(chunk, Gg, Tt / 128), 256, 0, stream>>>(q16, k16, v16t,
                                                               q16);
      gemm_proj<<<dim3(6, M / 128), 256, 0, stream>>>(q16, wtp, y16);
      res_ln_kernel<<<M, 256, 0, stream>>>(h16, (const __hip_bfloat16*)y16,
                                           bp + (size_t)i * Hh,
                                           lng + (size_t)i * Hh,
                                           lnb + (size_t)i * Hh);
    }

    pool_stage1<<<dim3((chunk * Hh) / 256, 8), 256, 0, stream>>>(h16, ppart,
                                                                 b0);
  }

  pool_stage2<<<(Bb * Hh) / 256, 256, 0, stream>>>(ppart, pool);
  final_partial<<<dim3(3, 8, 8), 256, 0, stream>>>(pool, proj_w, fpart);
  final_stage2<<<Bb, 256, 0, stream>>>(fpart, proj_b, proj_ln_g, proj_ln_b,
                                       out);
}